// Round 1
// baseline (3930.687 us; speedup 1.0000x reference)
//
#include <hip/hip_runtime.h>
#include <hip/hip_bf16.h>

typedef unsigned short u16;
typedef __bf16 bf16x8 __attribute__((ext_vector_type(8)));
typedef float f32x4 __attribute__((ext_vector_type(4)));

#define SEQ   1024
#define DM    1024
#define NHEADS 16
#define HDIM  64
#define VOC   32000
#define FFD   2816
#define NLAY  2

__device__ __forceinline__ u16 f2b(float f) {
    unsigned x = __builtin_bit_cast(unsigned, f);
    unsigned r = x + 0x7fffu + ((x >> 16) & 1u);
    return (u16)(r >> 16);
}
__device__ __forceinline__ float b2f(u16 u) {
    unsigned x = ((unsigned)u) << 16;
    return __builtin_bit_cast(float, x);
}

// ---------------- embedding gather ----------------
__global__ __launch_bounds__(256) void embed_kernel(const int* __restrict__ tok,
    const float* __restrict__ emb, float* __restrict__ h) {
    const int l = blockIdx.x;
    const int t = tok[l];
    ((float4*)(h + (size_t)l * DM))[threadIdx.x] =
        ((const float4*)(emb + (size_t)t * DM))[threadIdx.x];
}

// ---------------- rope tables ----------------
__global__ __launch_bounds__(256) void ropetab_kernel(float* __restrict__ cosb,
                                                      float* __restrict__ sinb) {
    const int idx = blockIdx.x * 256 + threadIdx.x;   // < SEQ*32
    const int l = idx >> 5, j = idx & 31;
    const float inv = __expf(-((float)j * (1.0f / 32.0f)) * 13.122363377404328f); // ln(500000)
    const float ang = (float)l * inv;
    cosb[idx] = cosf(ang);
    sinb[idx] = sinf(ang);
}

// ---------------- transfusion span ids ----------------
__global__ void span_kernel(const int* __restrict__ tok, int* __restrict__ span) {
    __shared__ int sb[SEQ], se[SEQ];
    const int t = threadIdx.x;
    const int v = tok[t];
    const int bo = (v == 31998) ? 1 : 0;
    const int eo = (v == 31999) ? 1 : 0;
    sb[t] = bo; se[t] = eo;
    __syncthreads();
    for (int o = 1; o < SEQ; o <<= 1) {
        int a = 0, b = 0;
        if (t >= o) { a = sb[t - o]; b = se[t - o]; }
        __syncthreads();
        sb[t] += a; se[t] += b;
        __syncthreads();
    }
    const int bc = sb[t];
    const int ec = se[t] - eo;           // exclusive eoi cumsum
    span[t] = (bc > ec) ? bc : 0;
}

// ---------------- rmsnorm (fp32 in -> bf16 out) ----------------
__global__ __launch_bounds__(256) void rmsnorm_kernel(const float* __restrict__ x,
    const float* __restrict__ w, u16* __restrict__ o) {
    const int row = blockIdx.x;
    const float4 xv = ((const float4*)(x + (size_t)row * DM))[threadIdx.x];
    float ss = xv.x * xv.x + xv.y * xv.y + xv.z * xv.z + xv.w * xv.w;
    for (int off = 32; off; off >>= 1) ss += __shfl_xor(ss, off);
    __shared__ float red[4];
    const int lane = threadIdx.x & 63, wvi = threadIdx.x >> 6;
    if (lane == 0) red[wvi] = ss;
    __syncthreads();
    const float tot = red[0] + red[1] + red[2] + red[3];
    const float sc = rsqrtf(tot * (1.0f / (float)DM) + 1e-5f);
    const float4 wv4 = ((const float4*)w)[threadIdx.x];
    ushort4 ov;
    ov.x = f2b(xv.x * sc * wv4.x);
    ov.y = f2b(xv.y * sc * wv4.y);
    ov.z = f2b(xv.z * sc * wv4.z);
    ov.w = f2b(xv.w * sc * wv4.w);
    ((ushort4*)(o + (size_t)row * DM))[threadIdx.x] = ov;
}

// ---------------- GEMM: C[M,N] = A[M,K](bf16) · B[N,K](fp32->bf16)^T (+res) ----------------
// 128x128 tile, BK=32, 256 thr = 4 waves (2x2), each wave 64x64 via 4x4 16x16x32 MFMA frags.
template <int RESID>
__global__ __launch_bounds__(256) void gemm_bt_kernel(const u16* __restrict__ A,
    const float* __restrict__ B, float* __restrict__ C, const float* __restrict__ res,
    int M, int N, int K) {
    __shared__ __align__(16) u16 sA[128 * 32];
    __shared__ __align__(16) u16 sB[128 * 32];
    const int tid = threadIdx.x;
    const int lane = tid & 63;
    const int wid = tid >> 6;
    const int wm = wid >> 1, wn = wid & 1;
    const int tm = blockIdx.y * 128, tn = blockIdx.x * 128;

    f32x4 acc[4][4] = {};
    const int fr = lane & 15;
    const int kc = (lane >> 4) * 8;

    for (int k0 = 0; k0 < K; k0 += 32) {
#pragma unroll
        for (int i = 0; i < 2; ++i) {       // stage A tile (bf16 -> bf16)
            const int off = (i * 256 + tid) * 8;
            const int r = off >> 5, c = off & 31;
            *(int4*)(&sA[off]) = *(const int4*)(&A[(size_t)(tm + r) * K + k0 + c]);
        }
#pragma unroll
        for (int i = 0; i < 2; ++i) {       // stage B tile (fp32 -> bf16)
            const int off = (i * 256 + tid) * 8;
            const int r = off >> 5, c = off & 31;
            const float* bp = &B[(size_t)(tn + r) * K + k0 + c];
            const float4 f0 = *(const float4*)(bp);
            const float4 f1 = *(const float4*)(bp + 4);
            ushort4 p0, p1;
            p0.x = f2b(f0.x); p0.y = f2b(f0.y); p0.z = f2b(f0.z); p0.w = f2b(f0.w);
            p1.x = f2b(f1.x); p1.y = f2b(f1.y); p1.z = f2b(f1.z); p1.w = f2b(f1.w);
            *(ushort4*)(&sB[off]) = p0;
            *(ushort4*)(&sB[off + 4]) = p1;
        }
        __syncthreads();
        bf16x8 af[4], bfv[4];
#pragma unroll
        for (int m = 0; m < 4; ++m)
            af[m] = *(const bf16x8*)(&sA[(wm * 64 + m * 16 + fr) * 32 + kc]);
#pragma unroll
        for (int n = 0; n < 4; ++n)
            bfv[n] = *(const bf16x8*)(&sB[(wn * 64 + n * 16 + fr) * 32 + kc]);
#pragma unroll
        for (int m = 0; m < 4; ++m)
#pragma unroll
            for (int n = 0; n < 4; ++n)
                acc[m][n] = __builtin_amdgcn_mfma_f32_16x16x32_bf16(af[m], bfv[n], acc[m][n], 0, 0, 0);
        __syncthreads();
    }

    const int cr = (lane >> 4) * 4;
    const int cc = lane & 15;
#pragma unroll
    for (int m = 0; m < 4; ++m) {
#pragma unroll
        for (int n = 0; n < 4; ++n) {
            const int row0 = tm + wm * 64 + m * 16 + cr;
            const int col = tn + wn * 64 + n * 16 + cc;
#pragma unroll
            for (int r = 0; r < 4; ++r) {
                const size_t idx = (size_t)(row0 + r) * N + col;
                float v = acc[m][n][r];
                if (RESID) v += res[idx];
                C[idx] = v;
            }
        }
    }
}

// ---------------- rope apply + bf16 cast (q,k rotated; v passthrough) ----------------
__global__ __launch_bounds__(256) void rope_kernel(const float* __restrict__ qf,
    const float* __restrict__ kf, const float* __restrict__ vf,
    const float* __restrict__ cosb, const float* __restrict__ sinb,
    u16* __restrict__ qb, u16* __restrict__ kb, u16* __restrict__ vb) {
    const int l = blockIdx.x;
    for (int p = threadIdx.x; p < DM / 2; p += 256) {
        const int j = p & 31;
        const float c = cosb[l * 32 + j], s = sinb[l * 32 + j];
        const size_t base = (size_t)l * DM + 2 * p;   // p = h*32 + j -> 2p = h*64 + 2j
        float e = qf[base], o = qf[base + 1];
        qb[base]     = f2b(e * c - o * s);
        qb[base + 1] = f2b(e * s + o * c);
        e = kf[base]; o = kf[base + 1];
        kb[base]     = f2b(e * c - o * s);
        kb[base + 1] = f2b(e * s + o * c);
        vb[base]     = f2b(vf[base]);
        vb[base + 1] = f2b(vf[base + 1]);
    }
}

// ---------------- attention: one block per (query,head) ----------------
__global__ __launch_bounds__(256) void attn_kernel(const u16* __restrict__ qb,
    const u16* __restrict__ kb, const u16* __restrict__ vb,
    const int* __restrict__ span, u16* __restrict__ ob) {
    const int qpos = blockIdx.x;
    const int head = blockIdx.y;
    const int tid = threadIdx.x, lane = tid & 63, wvi = tid >> 6;
    __shared__ float sc[SEQ];
    __shared__ float red1[4], red2[4];
    __shared__ float pvs[4][HDIM];

    const float qv = b2f(qb[(size_t)qpos * DM + head * HDIM + lane]);
    const int myspan = span[qpos];

    for (int it = 0; it < SEQ / 4; ++it) {
        const int key = it * 4 + wvi;
        float p = qv * b2f(kb[(size_t)key * DM + head * HDIM + lane]);
        p += __shfl_xor(p, 32); p += __shfl_xor(p, 16); p += __shfl_xor(p, 8);
        p += __shfl_xor(p, 4);  p += __shfl_xor(p, 2);  p += __shfl_xor(p, 1);
        if (lane == 0) {
            const bool allowed = (key <= qpos) || (myspan > 0 && span[key] == myspan);
            sc[key] = allowed ? p * 0.125f : -1e30f;
        }
    }
    __syncthreads();

    float m = -1e30f;
#pragma unroll
    for (int i = 0; i < 4; ++i) m = fmaxf(m, sc[tid + i * 256]);
    for (int o = 32; o; o >>= 1) m = fmaxf(m, __shfl_xor(m, o));
    if (lane == 0) red1[wvi] = m;
    __syncthreads();
    m = fmaxf(fmaxf(red1[0], red1[1]), fmaxf(red1[2], red1[3]));

    float s = 0.f;
#pragma unroll
    for (int i = 0; i < 4; ++i) {
        const float e = __expf(sc[tid + i * 256] - m);
        sc[tid + i * 256] = e;
        s += e;
    }
    for (int o = 32; o; o >>= 1) s += __shfl_xor(s, o);
    if (lane == 0) red2[wvi] = s;
    __syncthreads();
    const float inv = 1.f / (red2[0] + red2[1] + red2[2] + red2[3]);

    float acc = 0.f;
    for (int k = wvi; k < SEQ; k += 4)
        acc += sc[k] * b2f(vb[(size_t)k * DM + head * HDIM + lane]);
    pvs[wvi][lane] = acc;
    __syncthreads();
    if (tid < HDIM) {
        const float o = (pvs[0][tid] + pvs[1][tid] + pvs[2][tid] + pvs[3][tid]) * inv;
        ob[(size_t)qpos * DM + head * HDIM + tid] = f2b(o);
    }
}

// ---------------- silu(y1)*y3 -> bf16 ----------------
__global__ __launch_bounds__(256) void silu_kernel(const float* __restrict__ y1,
    const float* __restrict__ y3, u16* __restrict__ z) {
    const int i = blockIdx.x * 256 + threadIdx.x;   // over SEQ*FFD/4
    const float4 a = ((const float4*)y1)[i];
    const float4 b = ((const float4*)y3)[i];
    ushort4 o;
    o.x = f2b(a.x / (1.f + __expf(-a.x)) * b.x);
    o.y = f2b(a.y / (1.f + __expf(-a.y)) * b.y);
    o.z = f2b(a.z / (1.f + __expf(-a.z)) * b.z);
    o.w = f2b(a.w / (1.f + __expf(-a.w)) * b.w);
    ((ushort4*)z)[i] = o;
}

extern "C" void kernel_launch(void* const* d_in, const int* in_sizes, int n_in,
                              void* d_out, int out_size, void* d_ws, size_t ws_size,
                              hipStream_t stream) {
    (void)in_sizes; (void)n_in; (void)out_size; (void)ws_size;
    const int*   tokens   = (const int*)d_in[0];
    const float* tok_emb  = (const float*)d_in[1];
    const float* wq       = (const float*)d_in[2];
    const float* wk       = (const float*)d_in[3];
    const float* wvw      = (const float*)d_in[4];
    const float* wo       = (const float*)d_in[5];
    const float* w1       = (const float*)d_in[6];
    const float* w2       = (const float*)d_in[7];
    const float* w3       = (const float*)d_in[8];
    const float* attn_nw  = (const float*)d_in[9];
    const float* ffn_nw   = (const float*)d_in[10];
    const float* final_nw = (const float*)d_in[11];
    const float* w_out    = (const float*)d_in[12];
    float* logits = (float*)d_out;

    char* ws = (char*)d_ws;
    size_t off = 0;
    auto alloc = [&](size_t b) { size_t o = off; off += (b + 255) & ~(size_t)255; return o; };
    float* h    = (float*)(ws + alloc((size_t)SEQ * DM * 4));
    u16*   xn   = (u16*)  (ws + alloc((size_t)SEQ * DM * 2));
    float* qf   = (float*)(ws + alloc((size_t)SEQ * DM * 4));
    float* kf   = (float*)(ws + alloc((size_t)SEQ * DM * 4));
    float* vf   = (float*)(ws + alloc((size_t)SEQ * DM * 4));
    u16*   qb   = (u16*)  (ws + alloc((size_t)SEQ * DM * 2));
    u16*   kb   = (u16*)  (ws + alloc((size_t)SEQ * DM * 2));
    u16*   vb   = (u16*)  (ws + alloc((size_t)SEQ * DM * 2));
    u16*   ab   = (u16*)  (ws + alloc((size_t)SEQ * DM * 2));
    float* y1   = (float*)(ws + alloc((size_t)SEQ * FFD * 4));
    float* y3   = (float*)(ws + alloc((size_t)SEQ * FFD * 4));
    u16*   zb   = (u16*)  (ws + alloc((size_t)SEQ * FFD * 2));
    float* cosb = (float*)(ws + alloc((size_t)SEQ * 32 * 4));
    float* sinb = (float*)(ws + alloc((size_t)SEQ * 32 * 4));
    int*   span = (int*)  (ws + alloc((size_t)SEQ * 4));

    embed_kernel<<<SEQ, 256, 0, stream>>>(tokens, tok_emb, h);
    ropetab_kernel<<<(SEQ * 32) / 256, 256, 0, stream>>>(cosb, sinb);
    span_kernel<<<1, SEQ, 0, stream>>>(tokens, span);

    for (int l = 0; l < NLAY; ++l) {
        rmsnorm_kernel<<<SEQ, 256, 0, stream>>>(h, attn_nw + (size_t)l * DM, xn);
        gemm_bt_kernel<0><<<dim3(DM / 128, SEQ / 128), 256, 0, stream>>>(
            xn, wq + (size_t)l * DM * DM, qf, nullptr, SEQ, DM, DM);
        gemm_bt_kernel<0><<<dim3(DM / 128, SEQ / 128), 256, 0, stream>>>(
            xn, wk + (size_t)l * DM * DM, kf, nullptr, SEQ, DM, DM);
        gemm_bt_kernel<0><<<dim3(DM / 128, SEQ / 128), 256, 0, stream>>>(
            xn, wvw + (size_t)l * DM * DM, vf, nullptr, SEQ, DM, DM);
        rope_kernel<<<SEQ, 256, 0, stream>>>(qf, kf, vf, cosb, sinb, qb, kb, vb);
        attn_kernel<<<dim3(SEQ, NHEADS), 256, 0, stream>>>(qb, kb, vb, span, ab);
        gemm_bt_kernel<1><<<dim3(DM / 128, SEQ / 128), 256, 0, stream>>>(
            ab, wo + (size_t)l * DM * DM, h, h, SEQ, DM, DM);

        rmsnorm_kernel<<<SEQ, 256, 0, stream>>>(h, ffn_nw + (size_t)l * DM, xn);
        gemm_bt_kernel<0><<<dim3(FFD / 128, SEQ / 128), 256, 0, stream>>>(
            xn, w1 + (size_t)l * FFD * DM, y1, nullptr, SEQ, FFD, DM);
        gemm_bt_kernel<0><<<dim3(FFD / 128, SEQ / 128), 256, 0, stream>>>(
            xn, w3 + (size_t)l * FFD * DM, y3, nullptr, SEQ, FFD, DM);
        silu_kernel<<<(SEQ * FFD) / 1024, 256, 0, stream>>>(y1, y3, zb);
        gemm_bt_kernel<1><<<dim3(DM / 128, SEQ / 128), 256, 0, stream>>>(
            zb, w2 + (size_t)l * DM * FFD, h, h, SEQ, DM, FFD);
    }

    rmsnorm_kernel<<<SEQ, 256, 0, stream>>>(h, final_nw, xn);
    gemm_bt_kernel<0><<<dim3(VOC / 128, SEQ / 128), 256, 0, stream>>>(
        xn, w_out, logits, nullptr, SEQ, VOC, DM);
}

// Round 2
// 974.379 us; speedup vs baseline: 4.0340x; 4.0340x over previous
//
#include <hip/hip_runtime.h>
#include <hip/hip_bf16.h>

typedef unsigned short u16;
typedef __bf16 bf16x8 __attribute__((ext_vector_type(8)));
typedef u16 u16x8 __attribute__((ext_vector_type(8)));
typedef float f32x4 __attribute__((ext_vector_type(4)));

#define SEQ   1024
#define DM    1024
#define NHEADS 16
#define HDIM  64
#define VOC   32000
#define FFD   2816
#define NLAY  2

__device__ __forceinline__ u16 f2b(float f) {
    unsigned x = __builtin_bit_cast(unsigned, f);
    unsigned r = x + 0x7fffu + ((x >> 16) & 1u);
    return (u16)(r >> 16);
}
__device__ __forceinline__ float b2f(u16 u) {
    unsigned x = ((unsigned)u) << 16;
    return __builtin_bit_cast(float, x);
}
__device__ __forceinline__ float grpmax16(float v) {
    v = fmaxf(v, __shfl_xor(v, 1)); v = fmaxf(v, __shfl_xor(v, 2));
    v = fmaxf(v, __shfl_xor(v, 4)); v = fmaxf(v, __shfl_xor(v, 8));
    return v;
}
__device__ __forceinline__ float grpsum16(float v) {
    v += __shfl_xor(v, 1); v += __shfl_xor(v, 2);
    v += __shfl_xor(v, 4); v += __shfl_xor(v, 8);
    return v;
}

// ---------------- embedding gather ----------------
__global__ __launch_bounds__(256) void embed_kernel(const int* __restrict__ tok,
    const float* __restrict__ emb, float* __restrict__ h) {
    const int l = blockIdx.x;
    const int t = tok[l];
    ((float4*)(h + (size_t)l * DM))[threadIdx.x] =
        ((const float4*)(emb + (size_t)t * DM))[threadIdx.x];
}

// ---------------- rope tables ----------------
__global__ __launch_bounds__(256) void ropetab_kernel(float* __restrict__ cosb,
                                                      float* __restrict__ sinb) {
    const int idx = blockIdx.x * 256 + threadIdx.x;   // < SEQ*32
    const int l = idx >> 5, j = idx & 31;
    const float inv = __expf(-((float)j * (1.0f / 32.0f)) * 13.122363377404328f); // ln(500000)
    const float ang = (float)l * inv;
    cosb[idx] = cosf(ang);
    sinb[idx] = sinf(ang);
}

// ---------------- transfusion span ids ----------------
__global__ void span_kernel(const int* __restrict__ tok, int* __restrict__ span) {
    __shared__ int sb[SEQ], se[SEQ];
    const int t = threadIdx.x;
    const int v = tok[t];
    const int bo = (v == 31998) ? 1 : 0;
    const int eo = (v == 31999) ? 1 : 0;
    sb[t] = bo; se[t] = eo;
    __syncthreads();
    for (int o = 1; o < SEQ; o <<= 1) {
        int a = 0, b = 0;
        if (t >= o) { a = sb[t - o]; b = se[t - o]; }
        __syncthreads();
        sb[t] += a; se[t] += b;
        __syncthreads();
    }
    const int bc = sb[t];
    const int ec = se[t] - eo;           // exclusive eoi cumsum
    span[t] = (bc > ec) ? bc : 0;
}

// ---------------- rmsnorm (fp32 in -> bf16 out) ----------------
__global__ __launch_bounds__(256) void rmsnorm_kernel(const float* __restrict__ x,
    const float* __restrict__ w, u16* __restrict__ o) {
    const int row = blockIdx.x;
    const float4 xv = ((const float4*)(x + (size_t)row * DM))[threadIdx.x];
    float ss = xv.x * xv.x + xv.y * xv.y + xv.z * xv.z + xv.w * xv.w;
    for (int off = 32; off; off >>= 1) ss += __shfl_xor(ss, off);
    __shared__ float red[4];
    const int lane = threadIdx.x & 63, wvi = threadIdx.x >> 6;
    if (lane == 0) red[wvi] = ss;
    __syncthreads();
    const float tot = red[0] + red[1] + red[2] + red[3];
    const float sc = rsqrtf(tot * (1.0f / (float)DM) + 1e-5f);
    const float4 wv4 = ((const float4*)w)[threadIdx.x];
    ushort4 ov;
    ov.x = f2b(xv.x * sc * wv4.x);
    ov.y = f2b(xv.y * sc * wv4.y);
    ov.z = f2b(xv.z * sc * wv4.z);
    ov.w = f2b(xv.w * sc * wv4.w);
    ((ushort4*)(o + (size_t)row * DM))[threadIdx.x] = ov;
}

// ---------------- GEMM: C[M,N] = A[M,K](bf16) · B[N,K](fp32->bf16)^T (+res) ----------------
template <int RESID>
__global__ __launch_bounds__(256) void gemm_bt_kernel(const u16* __restrict__ A,
    const float* __restrict__ B, float* __restrict__ C, const float* __restrict__ res,
    int M, int N, int K) {
    __shared__ __align__(16) u16 sA[128 * 32];
    __shared__ __align__(16) u16 sB[128 * 32];
    const int tid = threadIdx.x;
    const int lane = tid & 63;
    const int wid = tid >> 6;
    const int wm = wid >> 1, wn = wid & 1;
    const int tm = blockIdx.y * 128, tn = blockIdx.x * 128;

    f32x4 acc[4][4] = {};
    const int fr = lane & 15;
    const int kc = (lane >> 4) * 8;

    for (int k0 = 0; k0 < K; k0 += 32) {
#pragma unroll
        for (int i = 0; i < 2; ++i) {       // stage A tile (bf16 -> bf16)
            const int off = (i * 256 + tid) * 8;
            const int r = off >> 5, c = off & 31;
            *(int4*)(&sA[off]) = *(const int4*)(&A[(size_t)(tm + r) * K + k0 + c]);
        }
#pragma unroll
        for (int i = 0; i < 2; ++i) {       // stage B tile (fp32 -> bf16)
            const int off = (i * 256 + tid) * 8;
            const int r = off >> 5, c = off & 31;
            const float* bp = &B[(size_t)(tn + r) * K + k0 + c];
            const float4 f0 = *(const float4*)(bp);
            const float4 f1 = *(const float4*)(bp + 4);
            ushort4 p0, p1;
            p0.x = f2b(f0.x); p0.y = f2b(f0.y); p0.z = f2b(f0.z); p0.w = f2b(f0.w);
            p1.x = f2b(f1.x); p1.y = f2b(f1.y); p1.z = f2b(f1.z); p1.w = f2b(f1.w);
            *(ushort4*)(&sB[off]) = p0;
            *(ushort4*)(&sB[off + 4]) = p1;
        }
        __syncthreads();
        bf16x8 af[4], bfv[4];
#pragma unroll
        for (int m = 0; m < 4; ++m)
            af[m] = *(const bf16x8*)(&sA[(wm * 64 + m * 16 + fr) * 32 + kc]);
#pragma unroll
        for (int n = 0; n < 4; ++n)
            bfv[n] = *(const bf16x8*)(&sB[(wn * 64 + n * 16 + fr) * 32 + kc]);
#pragma unroll
        for (int m = 0; m < 4; ++m)
#pragma unroll
            for (int n = 0; n < 4; ++n)
                acc[m][n] = __builtin_amdgcn_mfma_f32_16x16x32_bf16(af[m], bfv[n], acc[m][n], 0, 0, 0);
        __syncthreads();
    }

    const int cr = (lane >> 4) * 4;
    const int cc = lane & 15;
#pragma unroll
    for (int m = 0; m < 4; ++m) {
#pragma unroll
        for (int n = 0; n < 4; ++n) {
            const int row0 = tm + wm * 64 + m * 16 + cr;
            const int col = tn + wn * 64 + n * 16 + cc;
#pragma unroll
            for (int r = 0; r < 4; ++r) {
                const size_t idx = (size_t)(row0 + r) * N + col;
                float v = acc[m][n][r];
                if (RESID) v += res[idx];
                C[idx] = v;
            }
        }
    }
}

// ---------------- rope apply + bf16 cast (q,k rotated; v passthrough) ----------------
__global__ __launch_bounds__(256) void rope_kernel(const float* __restrict__ qf,
    const float* __restrict__ kf, const float* __restrict__ vf,
    const float* __restrict__ cosb, const float* __restrict__ sinb,
    u16* __restrict__ qb, u16* __restrict__ kb, u16* __restrict__ vb) {
    const int l = blockIdx.x;
    for (int p = threadIdx.x; p < DM / 2; p += 256) {
        const int j = p & 31;
        const float c = cosb[l * 32 + j], s = sinb[l * 32 + j];
        const size_t base = (size_t)l * DM + 2 * p;   // p = h*32 + j -> 2p = h*64 + 2j
        float e = qf[base], o = qf[base + 1];
        qb[base]     = f2b(e * c - o * s);
        qb[base + 1] = f2b(e * s + o * c);
        e = kf[base]; o = kf[base + 1];
        kb[base]     = f2b(e * c - o * s);
        kb[base + 1] = f2b(e * s + o * c);
        vb[base]     = f2b(vf[base]);
        vb[base + 1] = f2b(vf[base + 1]);
    }
}

// ---------------- flash attention: block = (64 q-rows, 1 head), 4 waves ----------------
// Wave w owns q rows [qbase + w*16, +16). Online softmax over 64-key blocks.
__global__ __launch_bounds__(256) void fattn_kernel(const u16* __restrict__ qb,
    const u16* __restrict__ kb, const u16* __restrict__ vb,
    const int* __restrict__ span, u16* __restrict__ ob) {
    __shared__ __align__(16) u16 sK[64][72];   // K rows, padded
    __shared__ __align__(16) u16 sVT[64][72];  // V transposed: [d][key]
    __shared__ __align__(16) u16 sP[4][16][72];// per-wave P tile
    const int tid = threadIdx.x, lane = tid & 63, wq = tid >> 6;
    const int g = lane >> 4, fr = lane & 15;
    const int head = blockIdx.y;
    const int qbase = blockIdx.x * 64;

    // Q fragments (A-frag: row = fr, k = g*8 + kf*32), resident all kernel
    bf16x8 qfr[2];
    {
        const u16* qp = qb + (size_t)(qbase + wq * 16 + fr) * DM + head * HDIM + g * 8;
        qfr[0] = *(const bf16x8*)(qp);
        qfr[1] = *(const bf16x8*)(qp + 32);
    }
    int sq[4];
#pragma unroll
    for (int r = 0; r < 4; ++r) sq[r] = span[qbase + wq * 16 + g * 4 + r];

    float m_old[4] = {-1e30f, -1e30f, -1e30f, -1e30f};
    float lsum[4] = {0.f, 0.f, 0.f, 0.f};
    f32x4 acc[4] = {};   // O accum: [nf] over d, rows via (g,r)

    for (int kb0 = 0; kb0 < SEQ; kb0 += 64) {
        __syncthreads();   // previous iter's LDS reads done
        {   // stage K tile: thread -> row tid>>2, cols (tid&3)*16..+15
            const int r = tid >> 2, c0 = (tid & 3) * 16;
            const u16* src = kb + (size_t)(kb0 + r) * DM + head * HDIM + c0;
            *(u16x8*)&sK[r][c0]     = *(const u16x8*)(src);
            *(u16x8*)&sK[r][c0 + 8] = *(const u16x8*)(src + 8);
        }
        {   // stage V transposed: thread -> key tid&63, d (tid>>6)*16..+15
            const int k = tid & 63, d0 = (tid >> 6) * 16;
            const u16* src = vb + (size_t)(kb0 + k) * DM + head * HDIM + d0;
            const u16x8 v0 = *(const u16x8*)(src);
            const u16x8 v1 = *(const u16x8*)(src + 8);
#pragma unroll
            for (int j = 0; j < 8; ++j) {
                sVT[d0 + j][k]     = v0[j];
                sVT[d0 + 8 + j][k] = v1[j];
            }
        }
        __syncthreads();

        // S = Q·K^T  (M=16, N=64, K=64)
        f32x4 accs[4] = {};
#pragma unroll
        for (int nf = 0; nf < 4; ++nf)
#pragma unroll
            for (int kf = 0; kf < 2; ++kf) {
                const bf16x8 kfv = *(const bf16x8*)&sK[nf * 16 + fr][g * 8 + kf * 32];
                accs[nf] = __builtin_amdgcn_mfma_f32_16x16x32_bf16(qfr[kf], kfv, accs[nf], 0, 0, 0);
            }

        // mask + scale
        int spk[4];
#pragma unroll
        for (int nf = 0; nf < 4; ++nf) spk[nf] = span[kb0 + nf * 16 + fr];
        float sv[4][4]; bool al[4][4];
#pragma unroll
        for (int nf = 0; nf < 4; ++nf) {
            const int key = kb0 + nf * 16 + fr;
#pragma unroll
            for (int r = 0; r < 4; ++r) {
                const int q = qbase + wq * 16 + g * 4 + r;
                al[nf][r] = (key <= q) || (sq[r] > 0 && spk[nf] == sq[r]);
                sv[nf][r] = al[nf][r] ? accs[nf][r] * 0.125f : -1e30f;
            }
        }
        // online softmax
        float alpha[4], ls[4];
#pragma unroll
        for (int r = 0; r < 4; ++r) {
            float mn = fmaxf(fmaxf(sv[0][r], sv[1][r]), fmaxf(sv[2][r], sv[3][r]));
            mn = grpmax16(mn);
            const float mnew = fmaxf(m_old[r], mn);
            alpha[r] = __expf(m_old[r] - mnew);
            m_old[r] = mnew;
            ls[r] = 0.f;
        }
        u16 pb[4][4];
#pragma unroll
        for (int nf = 0; nf < 4; ++nf)
#pragma unroll
            for (int r = 0; r < 4; ++r) {
                const float p = al[nf][r] ? __expf(sv[nf][r] - m_old[r]) : 0.f;
                ls[r] += p;
                pb[nf][r] = f2b(p);
            }
#pragma unroll
        for (int r = 0; r < 4; ++r) {
            lsum[r] = lsum[r] * alpha[r] + grpsum16(ls[r]);
#pragma unroll
            for (int nf = 0; nf < 4; ++nf) acc[nf][r] *= alpha[r];
        }
        // P -> LDS (per-wave region; same-wave RAW handled by lgkmcnt)
#pragma unroll
        for (int nf = 0; nf < 4; ++nf)
#pragma unroll
            for (int r = 0; r < 4; ++r)
                sP[wq][g * 4 + r][nf * 16 + fr] = pb[nf][r];

        // O += P·V  (M=16, N=64 d, K=64 keys)
#pragma unroll
        for (int nf = 0; nf < 4; ++nf)
#pragma unroll
            for (int kf = 0; kf < 2; ++kf) {
                const bf16x8 pa  = *(const bf16x8*)&sP[wq][fr][g * 8 + kf * 32];
                const bf16x8 vtb = *(const bf16x8*)&sVT[nf * 16 + fr][g * 8 + kf * 32];
                acc[nf] = __builtin_amdgcn_mfma_f32_16x16x32_bf16(pa, vtb, acc[nf], 0, 0, 0);
            }
    }

    // epilogue: O = acc / l
#pragma unroll
    for (int nf = 0; nf < 4; ++nf)
#pragma unroll
        for (int r = 0; r < 4; ++r) {
            const int q = qbase + wq * 16 + g * 4 + r;
            const int d = nf * 16 + fr;
            ob[(size_t)q * DM + head * HDIM + d] = f2b(acc[nf][r] / lsum[r]);
        }
}

// ---------------- silu(y1)*y3 -> bf16 ----------------
__global__ __launch_bounds__(256) void silu_kernel(const float* __restrict__ y1,
    const float* __restrict__ y3, u16* __restrict__ z) {
    const int i = blockIdx.x * 256 + threadIdx.x;   // over SEQ*FFD/4
    const float4 a = ((const float4*)y1)[i];
    const float4 b = ((const float4*)y3)[i];
    ushort4 o;
    o.x = f2b(a.x / (1.f + __expf(-a.x)) * b.x);
    o.y = f2b(a.y / (1.f + __expf(-a.y)) * b.y);
    o.z = f2b(a.z / (1.f + __expf(-a.z)) * b.z);
    o.w = f2b(a.w / (1.f + __expf(-a.w)) * b.w);
    ((ushort4*)z)[i] = o;
}

extern "C" void kernel_launch(void* const* d_in, const int* in_sizes, int n_in,
                              void* d_out, int out_size, void* d_ws, size_t ws_size,
                              hipStream_t stream) {
    (void)in_sizes; (void)n_in; (void)out_size; (void)ws_size;
    const int*   tokens   = (const int*)d_in[0];
    const float* tok_emb  = (const float*)d_in[1];
    const float* wq       = (const float*)d_in[2];
    const float* wk       = (const float*)d_in[3];
    const float* wvw      = (const float*)d_in[4];
    const float* wo       = (const float*)d_in[5];
    const float* w1       = (const float*)d_in[6];
    const float* w2       = (const float*)d_in[7];
    const float* w3       = (const float*)d_in[8];
    const float* attn_nw  = (const float*)d_in[9];
    const float* ffn_nw   = (const float*)d_in[10];
    const float* final_nw = (const float*)d_in[11];
    const float* w_out    = (const float*)d_in[12];
    float* logits = (float*)d_out;

    char* ws = (char*)d_ws;
    size_t off = 0;
    auto alloc = [&](size_t b) { size_t o = off; off += (b + 255) & ~(size_t)255; return o; };
    float* h    = (float*)(ws + alloc((size_t)SEQ * DM * 4));
    u16*   xn   = (u16*)  (ws + alloc((size_t)SEQ * DM * 2));
    float* qf   = (float*)(ws + alloc((size_t)SEQ * DM * 4));
    float* kf   = (float*)(ws + alloc((size_t)SEQ * DM * 4));
    float* vf   = (float*)(ws + alloc((size_t)SEQ * DM * 4));
    u16*   qb   = (u16*)  (ws + alloc((size_t)SEQ * DM * 2));
    u16*   kb   = (u16*)  (ws + alloc((size_t)SEQ * DM * 2));
    u16*   vb   = (u16*)  (ws + alloc((size_t)SEQ * DM * 2));
    u16*   ab   = (u16*)  (ws + alloc((size_t)SEQ * DM * 2));
    float* y1   = (float*)(ws + alloc((size_t)SEQ * FFD * 4));
    float* y3   = (float*)(ws + alloc((size_t)SEQ * FFD * 4));
    u16*   zb   = (u16*)  (ws + alloc((size_t)SEQ * FFD * 2));
    float* cosb = (float*)(ws + alloc((size_t)SEQ * 32 * 4));
    float* sinb = (float*)(ws + alloc((size_t)SEQ * 32 * 4));
    int*   span = (int*)  (ws + alloc((size_t)SEQ * 4));

    embed_kernel<<<SEQ, 256, 0, stream>>>(tokens, tok_emb, h);
    ropetab_kernel<<<(SEQ * 32) / 256, 256, 0, stream>>>(cosb, sinb);
    span_kernel<<<1, SEQ, 0, stream>>>(tokens, span);

    for (int l = 0; l < NLAY; ++l) {
        rmsnorm_kernel<<<SEQ, 256, 0, stream>>>(h, attn_nw + (size_t)l * DM, xn);
        gemm_bt_kernel<0><<<dim3(DM / 128, SEQ / 128), 256, 0, stream>>>(
            xn, wq + (size_t)l * DM * DM, qf, nullptr, SEQ, DM, DM);
        gemm_bt_kernel<0><<<dim3(DM / 128, SEQ / 128), 256, 0, stream>>>(
            xn, wk + (size_t)l * DM * DM, kf, nullptr, SEQ, DM, DM);
        gemm_bt_kernel<0><<<dim3(DM / 128, SEQ / 128), 256, 0, stream>>>(
            xn, wvw + (size_t)l * DM * DM, vf, nullptr, SEQ, DM, DM);
        rope_kernel<<<SEQ, 256, 0, stream>>>(qf, kf, vf, cosb, sinb, qb, kb, vb);
        fattn_kernel<<<dim3(SEQ / 64, NHEADS), 256, 0, stream>>>(qb, kb, vb, span, ab);
        gemm_bt_kernel<1><<<dim3(DM / 128, SEQ / 128), 256, 0, stream>>>(
            ab, wo + (size_t)l * DM * DM, h, h, SEQ, DM, DM);

        rmsnorm_kernel<<<SEQ, 256, 0, stream>>>(h, ffn_nw + (size_t)l * DM, xn);
        gemm_bt_kernel<0><<<dim3(FFD / 128, SEQ / 128), 256, 0, stream>>>(
            xn, w1 + (size_t)l * FFD * DM, y1, nullptr, SEQ, FFD, DM);
        gemm_bt_kernel<0><<<dim3(FFD / 128, SEQ / 128), 256, 0, stream>>>(
            xn, w3 + (size_t)l * FFD * DM, y3, nullptr, SEQ, FFD, DM);
        silu_kernel<<<(SEQ * FFD) / 1024, 256, 0, stream>>>(y1, y3, zb);
        gemm_bt_kernel<1><<<dim3(DM / 128, SEQ / 128), 256, 0, stream>>>(
            zb, w2 + (size_t)l * DM * FFD, h, h, SEQ, DM, FFD);
    }

    rmsnorm_kernel<<<SEQ, 256, 0, stream>>>(h, final_nw, xn);
    gemm_bt_kernel<0><<<dim3(VOC / 128, SEQ / 128), 256, 0, stream>>>(
        xn, w_out, logits, nullptr, SEQ, VOC, DM);
}

// Round 3
// 708.320 us; speedup vs baseline: 5.5493x; 1.3756x over previous
//
#include <hip/hip_runtime.h>
#include <hip/hip_bf16.h>

typedef unsigned short u16;
typedef __bf16 bf16x8 __attribute__((ext_vector_type(8)));
typedef u16 u16x8 __attribute__((ext_vector_type(8)));
typedef float f32x4 __attribute__((ext_vector_type(4)));

#define SEQ   1024
#define DM    1024
#define NHEADS 16
#define HDIM  64
#define VOC   32000
#define FFD   2816
#define NLAY  2
#define SAP   40   // padded LDS row stride (u16): 80 B, 16B-aligned, kills 8-way conflict

__device__ __forceinline__ u16 f2b(float f) {
    unsigned x = __builtin_bit_cast(unsigned, f);
    unsigned r = x + 0x7fffu + ((x >> 16) & 1u);
    return (u16)(r >> 16);
}
__device__ __forceinline__ float b2f(u16 u) {
    unsigned x = ((unsigned)u) << 16;
    return __builtin_bit_cast(float, x);
}
__device__ __forceinline__ float grpmax16(float v) {
    v = fmaxf(v, __shfl_xor(v, 1)); v = fmaxf(v, __shfl_xor(v, 2));
    v = fmaxf(v, __shfl_xor(v, 4)); v = fmaxf(v, __shfl_xor(v, 8));
    return v;
}
__device__ __forceinline__ float grpsum16(float v) {
    v += __shfl_xor(v, 1); v += __shfl_xor(v, 2);
    v += __shfl_xor(v, 4); v += __shfl_xor(v, 8);
    return v;
}

// ---------------- embedding gather ----------------
__global__ __launch_bounds__(256) void embed_kernel(const int* __restrict__ tok,
    const float* __restrict__ emb, float* __restrict__ h) {
    const int l = blockIdx.x;
    const int t = tok[l];
    ((float4*)(h + (size_t)l * DM))[threadIdx.x] =
        ((const float4*)(emb + (size_t)t * DM))[threadIdx.x];
}

// ---------------- rope tables ----------------
__global__ __launch_bounds__(256) void ropetab_kernel(float* __restrict__ cosb,
                                                      float* __restrict__ sinb) {
    const int idx = blockIdx.x * 256 + threadIdx.x;   // < SEQ*32
    const int l = idx >> 5, j = idx & 31;
    const float inv = __expf(-((float)j * (1.0f / 32.0f)) * 13.122363377404328f); // ln(500000)
    const float ang = (float)l * inv;
    cosb[idx] = cosf(ang);
    sinb[idx] = sinf(ang);
}

// ---------------- transfusion span ids ----------------
__global__ void span_kernel(const int* __restrict__ tok, int* __restrict__ span) {
    __shared__ int sb[SEQ], se[SEQ];
    const int t = threadIdx.x;
    const int v = tok[t];
    const int bo = (v == 31998) ? 1 : 0;
    const int eo = (v == 31999) ? 1 : 0;
    sb[t] = bo; se[t] = eo;
    __syncthreads();
    for (int o = 1; o < SEQ; o <<= 1) {
        int a = 0, b = 0;
        if (t >= o) { a = sb[t - o]; b = se[t - o]; }
        __syncthreads();
        sb[t] += a; se[t] += b;
        __syncthreads();
    }
    const int bc = sb[t];
    const int ec = se[t] - eo;           // exclusive eoi cumsum
    span[t] = (bc > ec) ? bc : 0;
}

// ---------------- rmsnorm (fp32 in -> bf16 out) ----------------
__global__ __launch_bounds__(256) void rmsnorm_kernel(const float* __restrict__ x,
    const float* __restrict__ w, u16* __restrict__ o) {
    const int row = blockIdx.x;
    const float4 xv = ((const float4*)(x + (size_t)row * DM))[threadIdx.x];
    float ss = xv.x * xv.x + xv.y * xv.y + xv.z * xv.z + xv.w * xv.w;
    for (int off = 32; off; off >>= 1) ss += __shfl_xor(ss, off);
    __shared__ float red[4];
    const int lane = threadIdx.x & 63, wvi = threadIdx.x >> 6;
    if (lane == 0) red[wvi] = ss;
    __syncthreads();
    const float tot = red[0] + red[1] + red[2] + red[3];
    const float sc = rsqrtf(tot * (1.0f / (float)DM) + 1e-5f);
    const float4 wv4 = ((const float4*)w)[threadIdx.x];
    ushort4 ov;
    ov.x = f2b(xv.x * sc * wv4.x);
    ov.y = f2b(xv.y * sc * wv4.y);
    ov.z = f2b(xv.z * sc * wv4.z);
    ov.w = f2b(xv.w * sc * wv4.w);
    ((ushort4*)(o + (size_t)row * DM))[threadIdx.x] = ov;
}

// ---- shared staging helpers (row-major [R][32] into padded-stride LDS) ----
__device__ __forceinline__ void stage_a_tile(u16* sA, const u16* A, int tm, int K,
                                             int k0, int tid, int iters) {
    for (int i = 0; i < iters; ++i) {
        const int off = (i * 256 + tid) * 8;
        const int r = off >> 5, c = off & 31;
        *(int4*)(&sA[r * SAP + c]) = *(const int4*)(&A[(size_t)(tm + r) * K + k0 + c]);
    }
}
__device__ __forceinline__ void stage_b_tile(u16* sB, const float* B, int tn, int K,
                                             int k0, int tid) {
#pragma unroll
    for (int i = 0; i < 2; ++i) {
        const int off = (i * 256 + tid) * 8;
        const int r = off >> 5, c = off & 31;
        const float* bp = &B[(size_t)(tn + r) * K + k0 + c];
        const float4 f0 = *(const float4*)(bp);
        const float4 f1 = *(const float4*)(bp + 4);
        ushort4 p0, p1;
        p0.x = f2b(f0.x); p0.y = f2b(f0.y); p0.z = f2b(f0.z); p0.w = f2b(f0.w);
        p1.x = f2b(f1.x); p1.y = f2b(f1.y); p1.z = f2b(f1.z); p1.w = f2b(f1.w);
        *(ushort4*)(&sB[r * SAP + c]) = p0;
        *(ushort4*)(&sB[r * SAP + c + 4]) = p1;
    }
}

// ---------------- GEMM: C[M,N] = A[M,K](bf16) · B[N,K](fp32->bf16)^T (+res) ----------------
// grid = (M/BM, N/128); blockIdx.x (M-tiles) fastest -> consecutive blocks share B panel.
template <int RESID, int BM>
__global__ __launch_bounds__(256) void gemm_bt_kernel(const u16* __restrict__ A,
    const float* __restrict__ B, float* __restrict__ C, const float* __restrict__ res,
    int M, int N, int K) {
    __shared__ __align__(16) u16 sA[BM * SAP];
    __shared__ __align__(16) u16 sB[128 * SAP];
    const int tid = threadIdx.x;
    const int lane = tid & 63;
    const int wid = tid >> 6;
    const int wm = wid >> 1, wn = wid & 1;
    const int tm = blockIdx.x * BM, tn = blockIdx.y * 128;
    constexpr int MF = BM / 32;

    f32x4 acc[MF][4] = {};
    const int fr = lane & 15;
    const int kc = (lane >> 4) * 8;

    for (int k0 = 0; k0 < K; k0 += 32) {
        stage_a_tile(sA, A, tm, K, k0, tid, BM / 64);
        stage_b_tile(sB, B, tn, K, k0, tid);
        __syncthreads();
        bf16x8 af[MF], bfv[4];
#pragma unroll
        for (int m = 0; m < MF; ++m)
            af[m] = *(const bf16x8*)(&sA[(wm * (BM / 2) + m * 16 + fr) * SAP + kc]);
#pragma unroll
        for (int n = 0; n < 4; ++n)
            bfv[n] = *(const bf16x8*)(&sB[(wn * 64 + n * 16 + fr) * SAP + kc]);
#pragma unroll
        for (int m = 0; m < MF; ++m)
#pragma unroll
            for (int n = 0; n < 4; ++n)
                acc[m][n] = __builtin_amdgcn_mfma_f32_16x16x32_bf16(af[m], bfv[n], acc[m][n], 0, 0, 0);
        __syncthreads();
    }

    const int cr = (lane >> 4) * 4;
    const int cc = lane & 15;
#pragma unroll
    for (int m = 0; m < MF; ++m) {
#pragma unroll
        for (int n = 0; n < 4; ++n) {
            const int row0 = tm + wm * (BM / 2) + m * 16 + cr;
            const int col = tn + wn * 64 + n * 16 + cc;
#pragma unroll
            for (int r = 0; r < 4; ++r) {
                const size_t idx = (size_t)(row0 + r) * N + col;
                float v = acc[m][n][r];
                if (RESID) v += res[idx];
                C[idx] = v;
            }
        }
    }
}

// ---------------- fused QKV GEMM + RoPE + bf16 cast ----------------
// grid = (8, 24): y selects {mat = y>>3, tn = (y&7)*128}; x = M-tile (fastest, shares B panel).
__global__ __launch_bounds__(256) void qkv_kernel(const u16* __restrict__ A,
    const float* __restrict__ Bq, const float* __restrict__ Bk, const float* __restrict__ Bv,
    const float* __restrict__ cosb, const float* __restrict__ sinb,
    u16* __restrict__ qb, u16* __restrict__ kb, u16* __restrict__ vb) {
    __shared__ __align__(16) u16 sA[128 * SAP];
    __shared__ __align__(16) u16 sB[128 * SAP];
    const int tid = threadIdx.x;
    const int lane = tid & 63;
    const int wid = tid >> 6;
    const int wm = wid >> 1, wn = wid & 1;
    const int tm = blockIdx.x * 128;
    const int mat = blockIdx.y >> 3;
    const int tn = (blockIdx.y & 7) * 128;
    const float* B = (mat == 0) ? Bq : (mat == 1) ? Bk : Bv;
    u16* out = (mat == 0) ? qb : (mat == 1) ? kb : vb;

    f32x4 acc[4][4] = {};
    const int fr = lane & 15;
    const int kc = (lane >> 4) * 8;

    for (int k0 = 0; k0 < DM; k0 += 32) {
        stage_a_tile(sA, A, tm, DM, k0, tid, 2);
        stage_b_tile(sB, B, tn, DM, k0, tid);
        __syncthreads();
        bf16x8 af[4], bfv[4];
#pragma unroll
        for (int m = 0; m < 4; ++m)
            af[m] = *(const bf16x8*)(&sA[(wm * 64 + m * 16 + fr) * SAP + kc]);
#pragma unroll
        for (int n = 0; n < 4; ++n)
            bfv[n] = *(const bf16x8*)(&sB[(wn * 64 + n * 16 + fr) * SAP + kc]);
#pragma unroll
        for (int m = 0; m < 4; ++m)
#pragma unroll
            for (int n = 0; n < 4; ++n)
                acc[m][n] = __builtin_amdgcn_mfma_f32_16x16x32_bf16(af[m], bfv[n], acc[m][n], 0, 0, 0);
        __syncthreads();
    }

    const int cr = (lane >> 4) * 4;
    const int cc = lane & 15;
    if (mat < 2) {
#pragma unroll
        for (int m = 0; m < 4; ++m) {
#pragma unroll
            for (int n = 0; n < 4; ++n) {
                const int row0 = tm + wm * 64 + m * 16 + cr;
                const int col = tn + wn * 64 + n * 16 + cc;
                const int j = (n * 16 + cc) >> 1;    // pair index within head
#pragma unroll
                for (int r = 0; r < 4; ++r) {
                    const int row = row0 + r;
                    const float c = cosb[row * 32 + j];
                    const float s = sinb[row * 32 + j];
                    const float v = acc[m][n][r];
                    const float p = __shfl_xor(v, 1);
                    const float o = (cc & 1) ? (p * s + v * c) : (v * c - p * s);
                    out[(size_t)row * DM + col] = f2b(o);
                }
            }
        }
    } else {
#pragma unroll
        for (int m = 0; m < 4; ++m)
#pragma unroll
            for (int n = 0; n < 4; ++n) {
                const int row0 = tm + wm * 64 + m * 16 + cr;
                const int col = tn + wn * 64 + n * 16 + cc;
#pragma unroll
                for (int r = 0; r < 4; ++r)
                    out[(size_t)(row0 + r) * DM + col] = f2b(acc[m][n][r]);
            }
    }
}

// ---------------- fused w1/w3 GEMM + SiLU·mul -> bf16 ----------------
// grid = (16, 22): BM=64 M-tiles fastest; each block computes both w1 and w3 tiles.
__global__ __launch_bounds__(256) void ffn13_kernel(const u16* __restrict__ A,
    const float* __restrict__ B1, const float* __restrict__ B3, u16* __restrict__ Z) {
    __shared__ __align__(16) u16 sA[64 * SAP];
    __shared__ __align__(16) u16 sB1[128 * SAP];
    __shared__ __align__(16) u16 sB3[128 * SAP];
    const int tid = threadIdx.x;
    const int lane = tid & 63;
    const int wid = tid >> 6;
    const int wm = wid >> 1, wn = wid & 1;
    const int tm = blockIdx.x * 64, tn = blockIdx.y * 128;

    f32x4 acc1[2][4] = {}, acc3[2][4] = {};
    const int fr = lane & 15;
    const int kc = (lane >> 4) * 8;

    for (int k0 = 0; k0 < DM; k0 += 32) {
        stage_a_tile(sA, A, tm, DM, k0, tid, 1);
        stage_b_tile(sB1, B1, tn, DM, k0, tid);
        stage_b_tile(sB3, B3, tn, DM, k0, tid);
        __syncthreads();
        bf16x8 af[2], b1v[4], b3v[4];
#pragma unroll
        for (int m = 0; m < 2; ++m)
            af[m] = *(const bf16x8*)(&sA[(wm * 32 + m * 16 + fr) * SAP + kc]);
#pragma unroll
        for (int n = 0; n < 4; ++n) {
            b1v[n] = *(const bf16x8*)(&sB1[(wn * 64 + n * 16 + fr) * SAP + kc]);
            b3v[n] = *(const bf16x8*)(&sB3[(wn * 64 + n * 16 + fr) * SAP + kc]);
        }
#pragma unroll
        for (int m = 0; m < 2; ++m)
#pragma unroll
            for (int n = 0; n < 4; ++n) {
                acc1[m][n] = __builtin_amdgcn_mfma_f32_16x16x32_bf16(af[m], b1v[n], acc1[m][n], 0, 0, 0);
                acc3[m][n] = __builtin_amdgcn_mfma_f32_16x16x32_bf16(af[m], b3v[n], acc3[m][n], 0, 0, 0);
            }
        __syncthreads();
    }

    const int cr = (lane >> 4) * 4;
    const int cc = lane & 15;
#pragma unroll
    for (int m = 0; m < 2; ++m) {
#pragma unroll
        for (int n = 0; n < 4; ++n) {
            const int row0 = tm + wm * 32 + m * 16 + cr;
            const int col = tn + wn * 64 + n * 16 + cc;
#pragma unroll
            for (int r = 0; r < 4; ++r) {
                const float a1 = acc1[m][n][r];
                const float a3 = acc3[m][n][r];
                const float z = a1 / (1.f + __expf(-a1)) * a3;
                Z[(size_t)(row0 + r) * FFD + col] = f2b(z);
            }
        }
    }
}

// ---------------- flash attention: block = (64 q-rows, 1 head), 4 waves ----------------
__global__ __launch_bounds__(256) void fattn_kernel(const u16* __restrict__ qb,
    const u16* __restrict__ kb, const u16* __restrict__ vb,
    const int* __restrict__ span, u16* __restrict__ ob) {
    __shared__ __align__(16) u16 sK[64][72];   // K rows, padded
    __shared__ __align__(16) u16 sVT[64][72];  // V transposed: [d][key]
    __shared__ __align__(16) u16 sP[4][16][72];// per-wave P tile
    const int tid = threadIdx.x, lane = tid & 63, wq = tid >> 6;
    const int g = lane >> 4, fr = lane & 15;
    const int head = blockIdx.y;
    const int qbase = blockIdx.x * 64;

    bf16x8 qfr[2];
    {
        const u16* qp = qb + (size_t)(qbase + wq * 16 + fr) * DM + head * HDIM + g * 8;
        qfr[0] = *(const bf16x8*)(qp);
        qfr[1] = *(const bf16x8*)(qp + 32);
    }
    int sq[4];
#pragma unroll
    for (int r = 0; r < 4; ++r) sq[r] = span[qbase + wq * 16 + g * 4 + r];

    float m_old[4] = {-1e30f, -1e30f, -1e30f, -1e30f};
    float lsum[4] = {0.f, 0.f, 0.f, 0.f};
    f32x4 acc[4] = {};

    for (int kb0 = 0; kb0 < SEQ; kb0 += 64) {
        __syncthreads();
        {
            const int r = tid >> 2, c0 = (tid & 3) * 16;
            const u16* src = kb + (size_t)(kb0 + r) * DM + head * HDIM + c0;
            *(u16x8*)&sK[r][c0]     = *(const u16x8*)(src);
            *(u16x8*)&sK[r][c0 + 8] = *(const u16x8*)(src + 8);
        }
        {
            const int k = tid & 63, d0 = (tid >> 6) * 16;
            const u16* src = vb + (size_t)(kb0 + k) * DM + head * HDIM + d0;
            const u16x8 v0 = *(const u16x8*)(src);
            const u16x8 v1 = *(const u16x8*)(src + 8);
#pragma unroll
            for (int j = 0; j < 8; ++j) {
                sVT[d0 + j][k]     = v0[j];
                sVT[d0 + 8 + j][k] = v1[j];
            }
        }
        __syncthreads();

        f32x4 accs[4] = {};
#pragma unroll
        for (int nf = 0; nf < 4; ++nf)
#pragma unroll
            for (int kf = 0; kf < 2; ++kf) {
                const bf16x8 kfv = *(const bf16x8*)&sK[nf * 16 + fr][g * 8 + kf * 32];
                accs[nf] = __builtin_amdgcn_mfma_f32_16x16x32_bf16(qfr[kf], kfv, accs[nf], 0, 0, 0);
            }

        int spk[4];
#pragma unroll
        for (int nf = 0; nf < 4; ++nf) spk[nf] = span[kb0 + nf * 16 + fr];
        float sv[4][4]; bool al[4][4];
#pragma unroll
        for (int nf = 0; nf < 4; ++nf) {
            const int key = kb0 + nf * 16 + fr;
#pragma unroll
            for (int r = 0; r < 4; ++r) {
                const int q = qbase + wq * 16 + g * 4 + r;
                al[nf][r] = (key <= q) || (sq[r] > 0 && spk[nf] == sq[r]);
                sv[nf][r] = al[nf][r] ? accs[nf][r] * 0.125f : -1e30f;
            }
        }
        float alpha[4], ls[4];
#pragma unroll
        for (int r = 0; r < 4; ++r) {
            float mn = fmaxf(fmaxf(sv[0][r], sv[1][r]), fmaxf(sv[2][r], sv[3][r]));
            mn = grpmax16(mn);
            const float mnew = fmaxf(m_old[r], mn);
            alpha[r] = __expf(m_old[r] - mnew);
            m_old[r] = mnew;
            ls[r] = 0.f;
        }
        u16 pb[4][4];
#pragma unroll
        for (int nf = 0; nf < 4; ++nf)
#pragma unroll
            for (int r = 0; r < 4; ++r) {
                const float p = al[nf][r] ? __expf(sv[nf][r] - m_old[r]) : 0.f;
                ls[r] += p;
                pb[nf][r] = f2b(p);
            }
#pragma unroll
        for (int r = 0; r < 4; ++r) {
            lsum[r] = lsum[r] * alpha[r] + grpsum16(ls[r]);
#pragma unroll
            for (int nf = 0; nf < 4; ++nf) acc[nf][r] *= alpha[r];
        }
#pragma unroll
        for (int nf = 0; nf < 4; ++nf)
#pragma unroll
            for (int r = 0; r < 4; ++r)
                sP[wq][g * 4 + r][nf * 16 + fr] = pb[nf][r];

#pragma unroll
        for (int nf = 0; nf < 4; ++nf)
#pragma unroll
            for (int kf = 0; kf < 2; ++kf) {
                const bf16x8 pa  = *(const bf16x8*)&sP[wq][fr][g * 8 + kf * 32];
                const bf16x8 vtb = *(const bf16x8*)&sVT[nf * 16 + fr][g * 8 + kf * 32];
                acc[nf] = __builtin_amdgcn_mfma_f32_16x16x32_bf16(pa, vtb, acc[nf], 0, 0, 0);
            }
    }

#pragma unroll
    for (int nf = 0; nf < 4; ++nf)
#pragma unroll
        for (int r = 0; r < 4; ++r) {
            const int q = qbase + wq * 16 + g * 4 + r;
            const int d = nf * 16 + fr;
            ob[(size_t)q * DM + head * HDIM + d] = f2b(acc[nf][r] / lsum[r]);
        }
}

extern "C" void kernel_launch(void* const* d_in, const int* in_sizes, int n_in,
                              void* d_out, int out_size, void* d_ws, size_t ws_size,
                              hipStream_t stream) {
    (void)in_sizes; (void)n_in; (void)out_size; (void)ws_size;
    const int*   tokens   = (const int*)d_in[0];
    const float* tok_emb  = (const float*)d_in[1];
    const float* wq       = (const float*)d_in[2];
    const float* wk       = (const float*)d_in[3];
    const float* wvw      = (const float*)d_in[4];
    const float* wo       = (const float*)d_in[5];
    const float* w1       = (const float*)d_in[6];
    const float* w2       = (const float*)d_in[7];
    const float* w3       = (const float*)d_in[8];
    const float* attn_nw  = (const float*)d_in[9];
    const float* ffn_nw   = (const float*)d_in[10];
    const float* final_nw = (const float*)d_in[11];
    const float* w_out    = (const float*)d_in[12];
    float* logits = (float*)d_out;

    char* ws = (char*)d_ws;
    size_t off = 0;
    auto alloc = [&](size_t b) { size_t o = off; off += (b + 255) & ~(size_t)255; return o; };
    float* h    = (float*)(ws + alloc((size_t)SEQ * DM * 4));
    u16*   xn   = (u16*)  (ws + alloc((size_t)SEQ * DM * 2));
    u16*   qb   = (u16*)  (ws + alloc((size_t)SEQ * DM * 2));
    u16*   kb   = (u16*)  (ws + alloc((size_t)SEQ * DM * 2));
    u16*   vb   = (u16*)  (ws + alloc((size_t)SEQ * DM * 2));
    u16*   ab   = (u16*)  (ws + alloc((size_t)SEQ * DM * 2));
    u16*   zb   = (u16*)  (ws + alloc((size_t)SEQ * FFD * 2));
    float* cosb = (float*)(ws + alloc((size_t)SEQ * 32 * 4));
    float* sinb = (float*)(ws + alloc((size_t)SEQ * 32 * 4));
    int*   span = (int*)  (ws + alloc((size_t)SEQ * 4));

    embed_kernel<<<SEQ, 256, 0, stream>>>(tokens, tok_emb, h);
    ropetab_kernel<<<(SEQ * 32) / 256, 256, 0, stream>>>(cosb, sinb);
    span_kernel<<<1, SEQ, 0, stream>>>(tokens, span);

    for (int l = 0; l < NLAY; ++l) {
        rmsnorm_kernel<<<SEQ, 256, 0, stream>>>(h, attn_nw + (size_t)l * DM, xn);
        qkv_kernel<<<dim3(SEQ / 128, 24), 256, 0, stream>>>(
            xn, wq + (size_t)l * DM * DM, wk + (size_t)l * DM * DM, wvw + (size_t)l * DM * DM,
            cosb, sinb, qb, kb, vb);
        fattn_kernel<<<dim3(SEQ / 64, NHEADS), 256, 0, stream>>>(qb, kb, vb, span, ab);
        gemm_bt_kernel<1, 64><<<dim3(SEQ / 64, DM / 128), 256, 0, stream>>>(
            ab, wo + (size_t)l * DM * DM, h, h, SEQ, DM, DM);

        rmsnorm_kernel<<<SEQ, 256, 0, stream>>>(h, ffn_nw + (size_t)l * DM, xn);
        ffn13_kernel<<<dim3(SEQ / 64, FFD / 128), 256, 0, stream>>>(
            xn, w1 + (size_t)l * FFD * DM, w3 + (size_t)l * FFD * DM, zb);
        gemm_bt_kernel<1, 64><<<dim3(SEQ / 64, DM / 128), 256, 0, stream>>>(
            zb, w2 + (size_t)l * DM * FFD, h, h, SEQ, DM, FFD);
    }

    rmsnorm_kernel<<<SEQ, 256, 0, stream>>>(h, final_nw, xn);
    gemm_bt_kernel<0, 128><<<dim3(SEQ / 128, VOC / 128), 256, 0, stream>>>(
        xn, w_out, logits, nullptr, SEQ, VOC, DM);
}

// Round 4
// 537.509 us; speedup vs baseline: 7.3128x; 1.3178x over previous
//
#include <hip/hip_runtime.h>
#include <hip/hip_bf16.h>
#include <stdint.h>

typedef unsigned short u16;
typedef __bf16 bf16x8 __attribute__((ext_vector_type(8)));
typedef u16 u16x8 __attribute__((ext_vector_type(8)));
typedef float f32x4 __attribute__((ext_vector_type(4)));

#define SEQ   1024
#define DM    1024
#define NHEADS 16
#define HDIM  64
#define VOC   32000
#define FFD   2816
#define NLAY  2

__device__ __forceinline__ u16 f2b(float f) {
    unsigned x = __builtin_bit_cast(unsigned, f);
    unsigned r = x + 0x7fffu + ((x >> 16) & 1u);
    return (u16)(r >> 16);
}
__device__ __forceinline__ float b2f(u16 u) {
    unsigned x = ((unsigned)u) << 16;
    return __builtin_bit_cast(float, x);
}
__device__ __forceinline__ float grpmax16(float v) {
    v = fmaxf(v, __shfl_xor(v, 1)); v = fmaxf(v, __shfl_xor(v, 2));
    v = fmaxf(v, __shfl_xor(v, 4)); v = fmaxf(v, __shfl_xor(v, 8));
    return v;
}
__device__ __forceinline__ float grpsum16(float v) {
    v += __shfl_xor(v, 1); v += __shfl_xor(v, 2);
    v += __shfl_xor(v, 4); v += __shfl_xor(v, 8);
    return v;
}

// async global->LDS, 16 bytes per lane. LDS dest is wave-uniform base + lane*16,
// so LDS layout must be linear in tid order (no padding).
__device__ __forceinline__ void gll16(const void* g, void* l) {
    __builtin_amdgcn_global_load_lds(
        (__attribute__((address_space(1))) void*)(uintptr_t)g,
        (__attribute__((address_space(3))) void*)(uint32_t)(uintptr_t)l,
        16, 0, 0);
}
// bijective XCD swizzle (8 XCDs): contiguous logical ranges per XCD.
__device__ __forceinline__ int xcd_swz(int bid, int nwg) {
    return (nwg % 8 == 0) ? (bid % 8) * (nwg / 8) + bid / 8 : bid;
}

// ---------------- fp32 -> bf16 weight conversion (grid-stride, BW-bound) ----------------
__global__ __launch_bounds__(256) void cvt_kernel(const float* __restrict__ s,
                                                  u16* __restrict__ d, int n8) {
    const int stride = gridDim.x * 256;
    for (int i = blockIdx.x * 256 + threadIdx.x; i < n8; i += stride) {
        const float4 a = ((const float4*)s)[2 * i];
        const float4 b = ((const float4*)s)[2 * i + 1];
        ushort4 p, q;
        p.x = f2b(a.x); p.y = f2b(a.y); p.z = f2b(a.z); p.w = f2b(a.w);
        q.x = f2b(b.x); q.y = f2b(b.y); q.z = f2b(b.z); q.w = f2b(b.w);
        ((ushort4*)d)[2 * i] = p;
        ((ushort4*)d)[2 * i + 1] = q;
    }
}

// ---------------- embedding gather ----------------
__global__ __launch_bounds__(256) void embed_kernel(const int* __restrict__ tok,
    const float* __restrict__ emb, float* __restrict__ h) {
    const int l = blockIdx.x;
    const int t = tok[l];
    ((float4*)(h + (size_t)l * DM))[threadIdx.x] =
        ((const float4*)(emb + (size_t)t * DM))[threadIdx.x];
}

// ---------------- rope tables ----------------
__global__ __launch_bounds__(256) void ropetab_kernel(float* __restrict__ cosb,
                                                      float* __restrict__ sinb) {
    const int idx = blockIdx.x * 256 + threadIdx.x;   // < SEQ*32
    const int l = idx >> 5, j = idx & 31;
    const float inv = __expf(-((float)j * (1.0f / 32.0f)) * 13.122363377404328f); // ln(500000)
    const float ang = (float)l * inv;
    cosb[idx] = cosf(ang);
    sinb[idx] = sinf(ang);
}

// ---------------- transfusion span ids ----------------
__global__ void span_kernel(const int* __restrict__ tok, int* __restrict__ span) {
    __shared__ int sb[SEQ], se[SEQ];
    const int t = threadIdx.x;
    const int v = tok[t];
    const int bo = (v == 31998) ? 1 : 0;
    const int eo = (v == 31999) ? 1 : 0;
    sb[t] = bo; se[t] = eo;
    __syncthreads();
    for (int o = 1; o < SEQ; o <<= 1) {
        int a = 0, b = 0;
        if (t >= o) { a = sb[t - o]; b = se[t - o]; }
        __syncthreads();
        sb[t] += a; se[t] += b;
        __syncthreads();
    }
    const int bc = sb[t];
    const int ec = se[t] - eo;           // exclusive eoi cumsum
    span[t] = (bc > ec) ? bc : 0;
}

// ---------------- rmsnorm (fp32 in -> bf16 out) ----------------
__global__ __launch_bounds__(256) void rmsnorm_kernel(const float* __restrict__ x,
    const float* __restrict__ w, u16* __restrict__ o) {
    const int row = blockIdx.x;
    const float4 xv = ((const float4*)(x + (size_t)row * DM))[threadIdx.x];
    float ss = xv.x * xv.x + xv.y * xv.y + xv.z * xv.z + xv.w * xv.w;
    for (int off = 32; off; off >>= 1) ss += __shfl_xor(ss, off);
    __shared__ float red[4];
    const int lane = threadIdx.x & 63, wvi = threadIdx.x >> 6;
    if (lane == 0) red[wvi] = ss;
    __syncthreads();
    const float tot = red[0] + red[1] + red[2] + red[3];
    const float sc = rsqrtf(tot * (1.0f / (float)DM) + 1e-5f);
    const float4 wv4 = ((const float4*)w)[threadIdx.x];
    ushort4 ov;
    ov.x = f2b(xv.x * sc * wv4.x);
    ov.y = f2b(xv.y * sc * wv4.y);
    ov.z = f2b(xv.z * sc * wv4.z);
    ov.w = f2b(xv.w * sc * wv4.w);
    ((ushort4*)(o + (size_t)row * DM))[threadIdx.x] = ov;
}

// ---------------- GEMM core: C[M,N] = A[M,K](bf16) . B[N,K](bf16)^T ----------------
// m97 structure: global_load_lds width=16 both operands, linear LDS [rows][32],
// BK=32, 4 waves 2x2, 2 barriers per K-step.
template <int BM, int BN>
__device__ __forceinline__ void gemm_core(const u16* __restrict__ A, const u16* __restrict__ B,
    int K, int tm, int tn, u16* sA, u16* sB, f32x4 (&acc)[BM / 32][BN / 32]) {
    const int tid = threadIdx.x, lane = tid & 63;
    const int wid = tid >> 6, wm = wid >> 1, wn = wid & 1;
    const int fr = lane & 15, g = lane >> 4;
    constexpr int MF = BM / 32, NF = BN / 32;
    constexpr int ACH = (BM * 4) / 256, BCH = (BN * 4) / 256;  // 16B chunks / thread

    for (int k0 = 0; k0 < K; k0 += 32) {
#pragma unroll
        for (int j = 0; j < ACH; ++j) {
            const int idx = j * 256 + tid, r = idx >> 2, c = (idx & 3) * 8;
            gll16(&A[(size_t)(tm + r) * K + k0 + c], &sA[idx * 8]);
        }
#pragma unroll
        for (int j = 0; j < BCH; ++j) {
            const int idx = j * 256 + tid, r = idx >> 2, c = (idx & 3) * 8;
            gll16(&B[(size_t)(tn + r) * K + k0 + c], &sB[idx * 8]);
        }
        __syncthreads();   // compiler drains vmcnt before barrier -> tiles ready
        bf16x8 af[MF], bfv[NF];
#pragma unroll
        for (int m = 0; m < MF; ++m)
            af[m] = *(const bf16x8*)&sA[(wm * (BM / 2) + m * 16 + fr) * 32 + g * 8];
#pragma unroll
        for (int n = 0; n < NF; ++n)
            bfv[n] = *(const bf16x8*)&sB[(wn * (BN / 2) + n * 16 + fr) * 32 + g * 8];
#pragma unroll
        for (int m = 0; m < MF; ++m)
#pragma unroll
            for (int n = 0; n < NF; ++n)
                acc[m][n] = __builtin_amdgcn_mfma_f32_16x16x32_bf16(af[m], bfv[n], acc[m][n], 0, 0, 0);
        __syncthreads();   // frag reads done before next stage overwrites
    }
}

// ---------------- generic GEMM, fp32 out (+optional residual) ----------------
// grid = (M/BM, N/BN); logical M-tile fastest + XCD swizzle -> B-panel L2 reuse.
template <int RESID, int BM, int BN>
__global__ __launch_bounds__(256) void gemm_nt_kernel(const u16* __restrict__ A,
    const u16* __restrict__ B, float* __restrict__ C, const float* __restrict__ res,
    int N, int K) {
    __shared__ __align__(16) u16 sA[BM * 32];
    __shared__ __align__(16) u16 sB[BN * 32];
    const int nwg = gridDim.x * gridDim.y;
    const int lid = xcd_swz(blockIdx.y * gridDim.x + blockIdx.x, nwg);
    const int tm = (lid % gridDim.x) * BM;
    const int tn = (lid / gridDim.x) * BN;
    constexpr int MF = BM / 32, NF = BN / 32;

    f32x4 acc[MF][NF] = {};
    gemm_core<BM, BN>(A, B, K, tm, tn, sA, sB, acc);

    const int lane = threadIdx.x & 63, wid = threadIdx.x >> 6;
    const int wm = wid >> 1, wn = wid & 1;
    const int cr = (lane >> 4) * 4, cc = lane & 15;
#pragma unroll
    for (int m = 0; m < MF; ++m)
#pragma unroll
        for (int n = 0; n < NF; ++n) {
            const int row0 = tm + wm * (BM / 2) + m * 16 + cr;
            const int col = tn + wn * (BN / 2) + n * 16 + cc;
#pragma unroll
            for (int r = 0; r < 4; ++r) {
                const size_t idx = (size_t)(row0 + r) * N + col;
                float v = acc[m][n][r];
                if (RESID) v += res[idx];
                C[idx] = v;
            }
        }
}

// ---------------- fused QKV GEMM + RoPE + bf16 cast (BM=64, BN=128) ----------------
// grid = (16, 24): y -> {mat = y>>3, tn = (y&7)*128}; logical M-tile fastest.
__global__ __launch_bounds__(256) void qkv_kernel(const u16* __restrict__ A,
    const u16* __restrict__ Bq, const u16* __restrict__ Bk, const u16* __restrict__ Bv,
    const float* __restrict__ cosb, const float* __restrict__ sinb,
    u16* __restrict__ qb, u16* __restrict__ kb, u16* __restrict__ vb) {
    __shared__ __align__(16) u16 sA[64 * 32];
    __shared__ __align__(16) u16 sB[128 * 32];
    const int lid = xcd_swz(blockIdx.y * gridDim.x + blockIdx.x, 16 * 24);
    const int tm = (lid % 16) * 64;
    const int yy = lid / 16;
    const int mat = yy >> 3;
    const int tn = (yy & 7) * 128;
    const u16* B = (mat == 0) ? Bq : (mat == 1) ? Bk : Bv;
    u16* out = (mat == 0) ? qb : (mat == 1) ? kb : vb;

    f32x4 acc[2][4] = {};
    gemm_core<64, 128>(A, B, DM, tm, tn, sA, sB, acc);

    const int lane = threadIdx.x & 63, wid = threadIdx.x >> 6;
    const int wm = wid >> 1, wn = wid & 1;
    const int cr = (lane >> 4) * 4, cc = lane & 15;
    if (mat < 2) {
#pragma unroll
        for (int m = 0; m < 2; ++m)
#pragma unroll
            for (int n = 0; n < 4; ++n) {
                const int row0 = tm + wm * 32 + m * 16 + cr;
                const int col = tn + wn * 64 + n * 16 + cc;
                const int j = (n * 16 + cc) >> 1;    // rope pair index within head
#pragma unroll
                for (int r = 0; r < 4; ++r) {
                    const int row = row0 + r;
                    const float c = cosb[row * 32 + j];
                    const float s = sinb[row * 32 + j];
                    const float v = acc[m][n][r];
                    const float p = __shfl_xor(v, 1);
                    const float o = (cc & 1) ? (p * s + v * c) : (v * c - p * s);
                    out[(size_t)row * DM + col] = f2b(o);
                }
            }
    } else {
#pragma unroll
        for (int m = 0; m < 2; ++m)
#pragma unroll
            for (int n = 0; n < 4; ++n) {
                const int row0 = tm + wm * 32 + m * 16 + cr;
                const int col = tn + wn * 64 + n * 16 + cc;
#pragma unroll
                for (int r = 0; r < 4; ++r)
                    out[(size_t)(row0 + r) * DM + col] = f2b(acc[m][n][r]);
            }
    }
}

// ---------------- fused w1/w3 GEMM + SiLU*mul -> bf16 (BM=64, BN=128) ----------------
__global__ __launch_bounds__(256) void ffn13_kernel(const u16* __restrict__ A,
    const u16* __restrict__ B1, const u16* __restrict__ B3, u16* __restrict__ Z) {
    __shared__ __align__(16) u16 sA[64 * 32];
    __shared__ __align__(16) u16 sB1[128 * 32];
    __shared__ __align__(16) u16 sB3[128 * 32];
    const int lid = xcd_swz(blockIdx.y * gridDim.x + blockIdx.x, 16 * 22);
    const int tm = (lid % 16) * 64;
    const int tn = (lid / 16) * 128;
    const int tid = threadIdx.x, lane = tid & 63;
    const int wid = tid >> 6, wm = wid >> 1, wn = wid & 1;
    const int fr = lane & 15, g = lane >> 4;

    f32x4 acc1[2][4] = {}, acc3[2][4] = {};
    for (int k0 = 0; k0 < DM; k0 += 32) {
        {
            const int r = tid >> 2, c = (tid & 3) * 8;
            gll16(&A[(size_t)(tm + r) * DM + k0 + c], &sA[tid * 8]);
        }
#pragma unroll
        for (int j = 0; j < 2; ++j) {
            const int idx = j * 256 + tid, r = idx >> 2, c = (idx & 3) * 8;
            gll16(&B1[(size_t)(tn + r) * DM + k0 + c], &sB1[idx * 8]);
            gll16(&B3[(size_t)(tn + r) * DM + k0 + c], &sB3[idx * 8]);
        }
        __syncthreads();
        bf16x8 af[2], b1v[4], b3v[4];
#pragma unroll
        for (int m = 0; m < 2; ++m)
            af[m] = *(const bf16x8*)&sA[(wm * 32 + m * 16 + fr) * 32 + g * 8];
#pragma unroll
        for (int n = 0; n < 4; ++n) {
            b1v[n] = *(const bf16x8*)&sB1[(wn * 64 + n * 16 + fr) * 32 + g * 8];
            b3v[n] = *(const bf16x8*)&sB3[(wn * 64 + n * 16 + fr) * 32 + g * 8];
        }
#pragma unroll
        for (int m = 0; m < 2; ++m)
#pragma unroll
            for (int n = 0; n < 4; ++n) {
                acc1[m][n] = __builtin_amdgcn_mfma_f32_16x16x32_bf16(af[m], b1v[n], acc1[m][n], 0, 0, 0);
                acc3[m][n] = __builtin_amdgcn_mfma_f32_16x16x32_bf16(af[m], b3v[n], acc3[m][n], 0, 0, 0);
            }
        __syncthreads();
    }

    const int cr = (lane >> 4) * 4, cc = lane & 15;
#pragma unroll
    for (int m = 0; m < 2; ++m)
#pragma unroll
        for (int n = 0; n < 4; ++n) {
            const int row0 = tm + wm * 32 + m * 16 + cr;
            const int col = tn + wn * 64 + n * 16 + cc;
#pragma unroll
            for (int r = 0; r < 4; ++r) {
                const float a1 = acc1[m][n][r];
                const float a3 = acc3[m][n][r];
                const float z = a1 / (1.f + __expf(-a1)) * a3;
                Z[(size_t)(row0 + r) * FFD + col] = f2b(z);
            }
        }
}

// ---------------- flash attention: block = (64 q-rows, 1 head), 4 waves ----------------
__global__ __launch_bounds__(256) void fattn_kernel(const u16* __restrict__ qb,
    const u16* __restrict__ kb, const u16* __restrict__ vb,
    const int* __restrict__ span, u16* __restrict__ ob) {
    __shared__ __align__(16) u16 sK[64][72];   // K rows, padded
    __shared__ __align__(16) u16 sVT[64][72];  // V transposed: [d][key]
    __shared__ __align__(16) u16 sP[4][16][72];// per-wave P tile
    const int tid = threadIdx.x, lane = tid & 63, wq = tid >> 6;
    const int g = lane >> 4, fr = lane & 15;
    const int head = blockIdx.y;
    const int qbase = blockIdx.x * 64;

    bf16x8 qfr[2];
    {
        const u16* qp = qb + (size_t)(qbase + wq * 16 + fr) * DM + head * HDIM + g * 8;
        qfr[0] = *(const bf16x8*)(qp);
        qfr[1] = *(const bf16x8*)(qp + 32);
    }
    int sq[4];
#pragma unroll
    for (int r = 0; r < 4; ++r) sq[r] = span[qbase + wq * 16 + g * 4 + r];

    float m_old[4] = {-1e30f, -1e30f, -1e30f, -1e30f};
    float lsum[4] = {0.f, 0.f, 0.f, 0.f};
    f32x4 acc[4] = {};

    for (int kb0 = 0; kb0 < SEQ; kb0 += 64) {
        __syncthreads();
        {
            const int r = tid >> 2, c0 = (tid & 3) * 16;
            const u16* src = kb + (size_t)(kb0 + r) * DM + head * HDIM + c0;
            *(u16x8*)&sK[r][c0]     = *(const u16x8*)(src);
            *(u16x8*)&sK[r][c0 + 8] = *(const u16x8*)(src + 8);
        }
        {
            const int k = tid & 63, d0 = (tid >> 6) * 16;
            const u16* src = vb + (size_t)(kb0 + k) * DM + head * HDIM + d0;
            const u16x8 v0 = *(const u16x8*)(src);
            const u16x8 v1 = *(const u16x8*)(src + 8);
#pragma unroll
            for (int j = 0; j < 8; ++j) {
                sVT[d0 + j][k]     = v0[j];
                sVT[d0 + 8 + j][k] = v1[j];
            }
        }
        __syncthreads();

        f32x4 accs[4] = {};
#pragma unroll
        for (int nf = 0; nf < 4; ++nf)
#pragma unroll
            for (int kf = 0; kf < 2; ++kf) {
                const bf16x8 kfv = *(const bf16x8*)&sK[nf * 16 + fr][g * 8 + kf * 32];
                accs[nf] = __builtin_amdgcn_mfma_f32_16x16x32_bf16(qfr[kf], kfv, accs[nf], 0, 0, 0);
            }

        int spk[4];
#pragma unroll
        for (int nf = 0; nf < 4; ++nf) spk[nf] = span[kb0 + nf * 16 + fr];
        float sv[4][4]; bool al[4][4];
#pragma unroll
        for (int nf = 0; nf < 4; ++nf) {
            const int key = kb0 + nf * 16 + fr;
#pragma unroll
            for (int r = 0; r < 4; ++r) {
                const int q = qbase + wq * 16 + g * 4 + r;
                al[nf][r] = (key <= q) || (sq[r] > 0 && spk[nf] == sq[r]);
                sv[nf][r] = al[nf][r] ? accs[nf][r] * 0.125f : -1e30f;
            }
        }
        float alpha[4], ls[4];
#pragma unroll
        for (int r = 0; r < 4; ++r) {
            float mn = fmaxf(fmaxf(sv[0][r], sv[1][r]), fmaxf(sv[2][r], sv[3][r]));
            mn = grpmax16(mn);
            const float mnew = fmaxf(m_old[r], mn);
            alpha[r] = __expf(m_old[r] - mnew);
            m_old[r] = mnew;
            ls[r] = 0.f;
        }
        u16 pb[4][4];
#pragma unroll
        for (int nf = 0; nf < 4; ++nf)
#pragma unroll
            for (int r = 0; r < 4; ++r) {
                const float p = al[nf][r] ? __expf(sv[nf][r] - m_old[r]) : 0.f;
                ls[r] += p;
                pb[nf][r] = f2b(p);
            }
#pragma unroll
        for (int r = 0; r < 4; ++r) {
            lsum[r] = lsum[r] * alpha[r] + grpsum16(ls[r]);
#pragma unroll
            for (int nf = 0; nf < 4; ++nf) acc[nf][r] *= alpha[r];
        }
#pragma unroll
        for (int nf = 0; nf < 4; ++nf)
#pragma unroll
            for (int r = 0; r < 4; ++r)
                sP[wq][g * 4 + r][nf * 16 + fr] = pb[nf][r];

#pragma unroll
        for (int nf = 0; nf < 4; ++nf)
#pragma unroll
            for (int kf = 0; kf < 2; ++kf) {
                const bf16x8 pa  = *(const bf16x8*)&sP[wq][fr][g * 8 + kf * 32];
                const bf16x8 vtb = *(const bf16x8*)&sVT[nf * 16 + fr][g * 8 + kf * 32];
                acc[nf] = __builtin_amdgcn_mfma_f32_16x16x32_bf16(pa, vtb, acc[nf], 0, 0, 0);
            }
    }

#pragma unroll
    for (int nf = 0; nf < 4; ++nf)
#pragma unroll
        for (int r = 0; r < 4; ++r) {
            const int q = qbase + wq * 16 + g * 4 + r;
            const int d = nf * 16 + fr;
            ob[(size_t)q * DM + head * HDIM + d] = f2b(acc[nf][r] / lsum[r]);
        }
}

extern "C" void kernel_launch(void* const* d_in, const int* in_sizes, int n_in,
                              void* d_out, int out_size, void* d_ws, size_t ws_size,
                              hipStream_t stream) {
    (void)in_sizes; (void)n_in; (void)out_size; (void)ws_size;
    const int*   tokens   = (const int*)d_in[0];
    const float* tok_emb  = (const float*)d_in[1];
    const float* wq       = (const float*)d_in[2];
    const float* wk       = (const float*)d_in[3];
    const float* wvw      = (const float*)d_in[4];
    const float* wo       = (const float*)d_in[5];
    const float* w1       = (const float*)d_in[6];
    const float* w2       = (const float*)d_in[7];
    const float* w3       = (const float*)d_in[8];
    const float* attn_nw  = (const float*)d_in[9];
    const float* ffn_nw   = (const float*)d_in[10];
    const float* final_nw = (const float*)d_in[11];
    const float* w_out    = (const float*)d_in[12];
    float* logits = (float*)d_out;

    char* ws = (char*)d_ws;
    size_t off = 0;
    auto alloc = [&](size_t b) { size_t o = off; off += (b + 255) & ~(size_t)255; return o; };
    float* h    = (float*)(ws + alloc((size_t)SEQ * DM * 4));
    u16*   xn   = (u16*)  (ws + alloc((size_t)SEQ * DM * 2));
    u16*   qb   = (u16*)  (ws + alloc((size_t)SEQ * DM * 2));
    u16*   kb   = (u16*)  (ws + alloc((size_t)SEQ * DM * 2));
    u16*   vb   = (u16*)  (ws + alloc((size_t)SEQ * DM * 2));
    u16*   ab   = (u16*)  (ws + alloc((size_t)SEQ * DM * 2));
    u16*   zb   = (u16*)  (ws + alloc((size_t)SEQ * FFD * 2));
    float* cosb = (float*)(ws + alloc((size_t)SEQ * 32 * 4));
    float* sinb = (float*)(ws + alloc((size_t)SEQ * 32 * 4));
    int*   span = (int*)  (ws + alloc((size_t)SEQ * 4));
    // bf16 weight copies
    const size_t nQ = (size_t)NLAY * DM * DM;     // wq/wk/wv/wo each
    const size_t nF = (size_t)NLAY * FFD * DM;    // w1/w2/w3 each
    const size_t nO = (size_t)VOC * DM;           // w_out
    u16* wqb = (u16*)(ws + alloc(nQ * 2));
    u16* wkb = (u16*)(ws + alloc(nQ * 2));
    u16* wvb = (u16*)(ws + alloc(nQ * 2));
    u16* wob = (u16*)(ws + alloc(nQ * 2));
    u16* w1b = (u16*)(ws + alloc(nF * 2));
    u16* w2b = (u16*)(ws + alloc(nF * 2));
    u16* w3b = (u16*)(ws + alloc(nF * 2));
    u16* woub = (u16*)(ws + alloc(nO * 2));

    auto cvt = [&](const float* s, u16* d, size_t n) {
        const int n8 = (int)(n / 8);
        const int blocks = (n8 + 255) / 256 < 2048 ? (n8 + 255) / 256 : 2048;
        cvt_kernel<<<blocks, 256, 0, stream>>>(s, d, n8);
    };
    cvt(wq, wqb, nQ); cvt(wk, wkb, nQ); cvt(wvw, wvb, nQ); cvt(wo, wob, nQ);
    cvt(w1, w1b, nF); cvt(w2, w2b, nF); cvt(w3, w3b, nF);
    cvt(w_out, woub, nO);

    embed_kernel<<<SEQ, 256, 0, stream>>>(tokens, tok_emb, h);
    ropetab_kernel<<<(SEQ * 32) / 256, 256, 0, stream>>>(cosb, sinb);
    span_kernel<<<1, SEQ, 0, stream>>>(tokens, span);

    for (int l = 0; l < NLAY; ++l) {
        rmsnorm_kernel<<<SEQ, 256, 0, stream>>>(h, attn_nw + (size_t)l * DM, xn);
        qkv_kernel<<<dim3(16, 24), 256, 0, stream>>>(
            xn, wqb + (size_t)l * DM * DM, wkb + (size_t)l * DM * DM, wvb + (size_t)l * DM * DM,
            cosb, sinb, qb, kb, vb);
        fattn_kernel<<<dim3(SEQ / 64, NHEADS), 256, 0, stream>>>(qb, kb, vb, span, ab);
        gemm_nt_kernel<1, 64, 64><<<dim3(16, 16), 256, 0, stream>>>(
            ab, wob + (size_t)l * DM * DM, h, h, DM, DM);

        rmsnorm_kernel<<<SEQ, 256, 0, stream>>>(h, ffn_nw + (size_t)l * DM, xn);
        ffn13_kernel<<<dim3(16, 22), 256, 0, stream>>>(
            xn, w1b + (size_t)l * FFD * DM, w3b + (size_t)l * FFD * DM, zb);
        gemm_nt_kernel<1, 64, 64><<<dim3(16, 16), 256, 0, stream>>>(
            zb, w2b + (size_t)l * DM * FFD, h, h, DM, FFD);
    }

    rmsnorm_kernel<<<SEQ, 256, 0, stream>>>(h, final_nw, xn);
    gemm_nt_kernel<0, 128, 128><<<dim3(SEQ / 128, VOC / 128), 256, 0, stream>>>(
        xn, woub, logits, nullptr, VOC, DM);
}

// Round 5
// 529.511 us; speedup vs baseline: 7.4232x; 1.0151x over previous
//
#include <hip/hip_runtime.h>
#include <hip/hip_bf16.h>
#include <stdint.h>

typedef unsigned short u16;
typedef __bf16 bf16x8 __attribute__((ext_vector_type(8)));
typedef u16 u16x8 __attribute__((ext_vector_type(8)));
typedef float f32x4 __attribute__((ext_vector_type(4)));

#define SEQ   1024
#define DM    1024
#define NHEADS 16
#define HDIM  64
#define VOC   32000
#define FFD   2816
#define NLAY  2

__device__ __forceinline__ u16 f2b(float f) {
    unsigned x = __builtin_bit_cast(unsigned, f);
    unsigned r = x + 0x7fffu + ((x >> 16) & 1u);
    return (u16)(r >> 16);
}
__device__ __forceinline__ float b2f(u16 u) {
    unsigned x = ((unsigned)u) << 16;
    return __builtin_bit_cast(float, x);
}
__device__ __forceinline__ float grpmax16(float v) {
    v = fmaxf(v, __shfl_xor(v, 1)); v = fmaxf(v, __shfl_xor(v, 2));
    v = fmaxf(v, __shfl_xor(v, 4)); v = fmaxf(v, __shfl_xor(v, 8));
    return v;
}
__device__ __forceinline__ float grpsum16(float v) {
    v += __shfl_xor(v, 1); v += __shfl_xor(v, 2);
    v += __shfl_xor(v, 4); v += __shfl_xor(v, 8);
    return v;
}

// async global->LDS, 16 bytes per lane. LDS dest must be wave-uniform base + lane*16.
__device__ __forceinline__ void gll16(const void* g, void* l) {
    __builtin_amdgcn_global_load_lds(
        (__attribute__((address_space(1))) void*)(uintptr_t)g,
        (__attribute__((address_space(3))) void*)(uint32_t)(uintptr_t)l,
        16, 0, 0);
}
// bijective XCD swizzle for any nwg (m204): per-XCD contiguous logical chunks.
__device__ __forceinline__ int xcd_swz(int bid, int nwg) {
    const int q = nwg >> 3, r = nwg & 7;
    const int xcd = bid & 7, j = bid >> 3;
    const int start = (xcd < r) ? xcd * (q + 1) : r * (q + 1) + (xcd - r) * q;
    return start + j;
}

// ---------------- fp32 -> bf16 weight conversion (grid-stride, BW-bound) ----------------
__global__ __launch_bounds__(256) void cvt_kernel(const float* __restrict__ s,
                                                  u16* __restrict__ d, int n8) {
    const int stride = gridDim.x * 256;
    for (int i = blockIdx.x * 256 + threadIdx.x; i < n8; i += stride) {
        const float4 a = ((const float4*)s)[2 * i];
        const float4 b = ((const float4*)s)[2 * i + 1];
        ushort4 p, q;
        p.x = f2b(a.x); p.y = f2b(a.y); p.z = f2b(a.z); p.w = f2b(a.w);
        q.x = f2b(b.x); q.y = f2b(b.y); q.z = f2b(b.z); q.w = f2b(b.w);
        ((ushort4*)d)[2 * i] = p;
        ((ushort4*)d)[2 * i + 1] = q;
    }
}

// ---------------- embedding gather ----------------
__global__ __launch_bounds__(256) void embed_kernel(const int* __restrict__ tok,
    const float* __restrict__ emb, float* __restrict__ h) {
    const int l = blockIdx.x;
    const int t = tok[l];
    ((float4*)(h + (size_t)l * DM))[threadIdx.x] =
        ((const float4*)(emb + (size_t)t * DM))[threadIdx.x];
}

// ---------------- rope tables ----------------
__global__ __launch_bounds__(256) void ropetab_kernel(float* __restrict__ cosb,
                                                      float* __restrict__ sinb) {
    const int idx = blockIdx.x * 256 + threadIdx.x;   // < SEQ*32
    const int l = idx >> 5, j = idx & 31;
    const float inv = __expf(-((float)j * (1.0f / 32.0f)) * 13.122363377404328f); // ln(500000)
    const float ang = (float)l * inv;
    cosb[idx] = cosf(ang);
    sinb[idx] = sinf(ang);
}

// ---------------- transfusion span ids ----------------
__global__ void span_kernel(const int* __restrict__ tok, int* __restrict__ span) {
    __shared__ int sb[SEQ], se[SEQ];
    const int t = threadIdx.x;
    const int v = tok[t];
    const int bo = (v == 31998) ? 1 : 0;
    const int eo = (v == 31999) ? 1 : 0;
    sb[t] = bo; se[t] = eo;
    __syncthreads();
    for (int o = 1; o < SEQ; o <<= 1) {
        int a = 0, b = 0;
        if (t >= o) { a = sb[t - o]; b = se[t - o]; }
        __syncthreads();
        sb[t] += a; se[t] += b;
        __syncthreads();
    }
    const int bc = sb[t];
    const int ec = se[t] - eo;           // exclusive eoi cumsum
    span[t] = (bc > ec) ? bc : 0;
}

// ---------------- rmsnorm (fp32 in -> bf16 out) ----------------
__global__ __launch_bounds__(256) void rmsnorm_kernel(const float* __restrict__ x,
    const float* __restrict__ w, u16* __restrict__ o) {
    const int row = blockIdx.x;
    const float4 xv = ((const float4*)(x + (size_t)row * DM))[threadIdx.x];
    float ss = xv.x * xv.x + xv.y * xv.y + xv.z * xv.z + xv.w * xv.w;
    for (int off = 32; off; off >>= 1) ss += __shfl_xor(ss, off);
    __shared__ float red[4];
    const int lane = threadIdx.x & 63, wvi = threadIdx.x >> 6;
    if (lane == 0) red[wvi] = ss;
    __syncthreads();
    const float tot = red[0] + red[1] + red[2] + red[3];
    const float sc = rsqrtf(tot * (1.0f / (float)DM) + 1e-5f);
    const float4 wv4 = ((const float4*)w)[threadIdx.x];
    ushort4 ov;
    ov.x = f2b(xv.x * sc * wv4.x);
    ov.y = f2b(xv.y * sc * wv4.y);
    ov.z = f2b(xv.z * sc * wv4.z);
    ov.w = f2b(xv.w * sc * wv4.w);
    ((ushort4*)(o + (size_t)row * DM))[threadIdx.x] = ov;
}

// ======================= 128-wide GEMM core (BK=32, 4 waves 2x2) =======================
// LDS layout [row][32] u16, XOR-swizzled at 16B-granule level: granule' = g ^ (row&3).
// Stage pre-swizzles the GLOBAL source column so LDS dest stays linear (rule #21).
template <int BM, int BN>
__device__ __forceinline__ void gemm_core(const u16* __restrict__ A, const u16* __restrict__ B,
    int K, int tm, int tn, u16* sA, u16* sB, f32x4 (&acc)[BM / 32][BN / 32]) {
    const int tid = threadIdx.x, lane = tid & 63;
    const int wid = tid >> 6, wm = wid >> 1, wn = wid & 1;
    const int fr = lane & 15, g = lane >> 4;
    constexpr int MF = BM / 32, NF = BN / 32;
    constexpr int ACH = (BM * 4) / 256, BCH = (BN * 4) / 256;  // 16B chunks / thread

    for (int k0 = 0; k0 < K; k0 += 32) {
#pragma unroll
        for (int j = 0; j < ACH; ++j) {
            const int idx = j * 256 + tid, r = idx >> 2;
            const int c = ((idx & 3) ^ (r & 3)) * 8;
            gll16(&A[(size_t)(tm + r) * K + k0 + c], &sA[idx * 8]);
        }
#pragma unroll
        for (int j = 0; j < BCH; ++j) {
            const int idx = j * 256 + tid, r = idx >> 2;
            const int c = ((idx & 3) ^ (r & 3)) * 8;
            gll16(&B[(size_t)(tn + r) * K + k0 + c], &sB[idx * 8]);
        }
        __syncthreads();   // drains vmcnt -> tiles ready
        bf16x8 af[MF], bfv[NF];
#pragma unroll
        for (int m = 0; m < MF; ++m) {
            const int row = wm * (BM / 2) + m * 16 + fr;
            af[m] = *(const bf16x8*)&sA[row * 32 + ((g ^ (row & 3)) * 8)];
        }
#pragma unroll
        for (int n = 0; n < NF; ++n) {
            const int row = wn * (BN / 2) + n * 16 + fr;
            bfv[n] = *(const bf16x8*)&sB[row * 32 + ((g ^ (row & 3)) * 8)];
        }
#pragma unroll
        for (int m = 0; m < MF; ++m)
#pragma unroll
            for (int n = 0; n < NF; ++n)
                acc[m][n] = __builtin_amdgcn_mfma_f32_16x16x32_bf16(af[m], bfv[n], acc[m][n], 0, 0, 0);
        __syncthreads();   // frag reads done before next stage overwrites
    }
}

// ---------------- generic GEMM, fp32 out (+optional residual) ----------------
template <int RESID, int BM, int BN>
__global__ __launch_bounds__(256) void gemm_nt_kernel(const u16* __restrict__ A,
    const u16* __restrict__ B, float* __restrict__ C, const float* __restrict__ res,
    int N, int K) {
    __shared__ __align__(16) u16 sA[BM * 32];
    __shared__ __align__(16) u16 sB[BN * 32];
    const int nwg = gridDim.x * gridDim.y;
    const int lid = xcd_swz(blockIdx.y * gridDim.x + blockIdx.x, nwg);
    const int tm = (lid % gridDim.x) * BM;
    const int tn = (lid / gridDim.x) * BN;
    constexpr int MF = BM / 32, NF = BN / 32;

    f32x4 acc[MF][NF] = {};
    gemm_core<BM, BN>(A, B, K, tm, tn, sA, sB, acc);

    const int lane = threadIdx.x & 63, wid = threadIdx.x >> 6;
    const int wm = wid >> 1, wn = wid & 1;
    const int cr = (lane >> 4) * 4, cc = lane & 15;
#pragma unroll
    for (int m = 0; m < MF; ++m)
#pragma unroll
        for (int n = 0; n < NF; ++n) {
            const int row0 = tm + wm * (BM / 2) + m * 16 + cr;
            const int col = tn + wn * (BN / 2) + n * 16 + cc;
#pragma unroll
            for (int r = 0; r < 4; ++r) {
                const size_t idx = (size_t)(row0 + r) * N + col;
                float v = acc[m][n][r];
                if (RESID) v += res[idx];
                C[idx] = v;
            }
        }
}

// ======================= 256x256 / BK=64 / 8-wave pipelined GEMM =======================
// Double-buffered LDS (128 KiB). 4 phases per K-tile: {stage 1 half-tile of t+1 into
// buf q || ds_read quadrant frags from buf p || setprio-wrapped 16 MFMA}. One
// __syncthreads (drain) per K-tile: publishes buf p AND closes all reads of buf q.
// Stages during tile t only write buf q=t+1's buffer -> race-free.
template <int RESID>
__global__ __launch_bounds__(512, 2) void gemm_big_kernel(const u16* __restrict__ A,
    const u16* __restrict__ B, float* __restrict__ C, const float* __restrict__ res,
    int N, int K) {
    __shared__ __align__(16) u16 sA[2][256 * 64];
    __shared__ __align__(16) u16 sB[2][256 * 64];
    const int nwg = gridDim.x * gridDim.y;
    const int lid = xcd_swz(blockIdx.y * gridDim.x + blockIdx.x, nwg);
    const int tm = (lid % gridDim.x) * 256;
    const int tn = (lid / gridDim.x) * 256;
    const int tid = threadIdx.x, lane = tid & 63, wid = tid >> 6;
    const int wm = wid >> 2, wn = wid & 3;       // 2 x 4 waves
    const int fr = lane & 15, g = lane >> 4;

    f32x4 acc[8][4] = {};

    // stage half h of K-tile t: h0/h1 = A rows 0-127/128-255; h2/h3 = B same.
    auto stage_half = [&](int b, int t, int h) {
        const int k0 = t * 64;
        const u16* src = (h < 2) ? A : B;
        const int tr = (h < 2) ? tm : tn;
        u16* dst = (h < 2) ? sA[b] : sB[b];
#pragma unroll
        for (int j = 0; j < 2; ++j) {
            const int idx = (h & 1) * 1024 + j * 512 + tid;   // 16B-chunk index
            const int r = idx >> 3, gr = idx & 7;
            const int gcol = (gr ^ (r & 7)) * 8;              // pre-swizzled source granule
            gll16(&src[(size_t)(tr + r) * K + k0 + gcol], &dst[idx * 8]);
        }
    };

    const int NT = K >> 6;
#pragma unroll
    for (int h = 0; h < 4; ++h) stage_half(0, 0, h);

    int p = 0;
    for (int t = 0; t < NT; ++t) {
        __syncthreads();           // vmcnt(0)+barrier: buf p staged, buf q reads closed
        bf16x8 bfv[4][2];
#pragma unroll
        for (int qd = 0; qd < 4; ++qd) {
            if (t + 1 < NT) stage_half(p ^ 1, t + 1, qd);
            if (qd == 0) {
#pragma unroll
                for (int n = 0; n < 4; ++n)
#pragma unroll
                    for (int ks = 0; ks < 2; ++ks) {
                        const int row = wn * 64 + n * 16 + fr;
                        const int gr = (g + ks * 4) ^ (row & 7);
                        bfv[n][ks] = *(const bf16x8*)&sB[p][row * 64 + gr * 8];
                    }
            }
            bf16x8 af[2][2];
#pragma unroll
            for (int i = 0; i < 2; ++i)
#pragma unroll
                for (int ks = 0; ks < 2; ++ks) {
                    const int row = wm * 128 + (qd * 2 + i) * 16 + fr;
                    const int gr = (g + ks * 4) ^ (row & 7);
                    af[i][ks] = *(const bf16x8*)&sA[p][row * 64 + gr * 8];
                }
            __builtin_amdgcn_s_setprio(1);
#pragma unroll
            for (int i = 0; i < 2; ++i)
#pragma unroll
                for (int n = 0; n < 4; ++n)
#pragma unroll
                    for (int ks = 0; ks < 2; ++ks)
                        acc[qd * 2 + i][n] = __builtin_amdgcn_mfma_f32_16x16x32_bf16(
                            af[i][ks], bfv[n][ks], acc[qd * 2 + i][n], 0, 0, 0);
            __builtin_amdgcn_s_setprio(0);
        }
        p ^= 1;
    }

    const int cr = (lane >> 4) * 4, cc = lane & 15;
#pragma unroll
    for (int m = 0; m < 8; ++m)
#pragma unroll
        for (int n = 0; n < 4; ++n) {
            const int row0 = tm + wm * 128 + m * 16 + cr;
            const int col = tn + wn * 64 + n * 16 + cc;
#pragma unroll
            for (int r = 0; r < 4; ++r) {
                const size_t idx = (size_t)(row0 + r) * N + col;
                float v = acc[m][n][r];
                if (RESID) v += res[idx];
                C[idx] = v;
            }
        }
}

// ---------------- fused QKV GEMM + RoPE + bf16 cast (BM=64, BN=128) ----------------
__global__ __launch_bounds__(256) void qkv_kernel(const u16* __restrict__ A,
    const u16* __restrict__ Bq, const u16* __restrict__ Bk, const u16* __restrict__ Bv,
    const float* __restrict__ cosb, const float* __restrict__ sinb,
    u16* __restrict__ qb, u16* __restrict__ kb, u16* __restrict__ vb) {
    __shared__ __align__(16) u16 sA[64 * 32];
    __shared__ __align__(16) u16 sB[128 * 32];
    const int lid = xcd_swz(blockIdx.y * gridDim.x + blockIdx.x, 16 * 24);
    const int tm = (lid % 16) * 64;
    const int yy = lid / 16;
    const int mat = yy >> 3;
    const int tn = (yy & 7) * 128;
    const u16* B = (mat == 0) ? Bq : (mat == 1) ? Bk : Bv;
    u16* out = (mat == 0) ? qb : (mat == 1) ? kb : vb;

    f32x4 acc[2][4] = {};
    gemm_core<64, 128>(A, B, DM, tm, tn, sA, sB, acc);

    const int lane = threadIdx.x & 63, wid = threadIdx.x >> 6;
    const int wm = wid >> 1, wn = wid & 1;
    const int cr = (lane >> 4) * 4, cc = lane & 15;
    if (mat < 2) {
#pragma unroll
        for (int m = 0; m < 2; ++m)
#pragma unroll
            for (int n = 0; n < 4; ++n) {
                const int row0 = tm + wm * 32 + m * 16 + cr;
                const int col = tn + wn * 64 + n * 16 + cc;
                const int j = (n * 16 + cc) >> 1;    // rope pair index within head
#pragma unroll
                for (int r = 0; r < 4; ++r) {
                    const int row = row0 + r;
                    const float c = cosb[row * 32 + j];
                    const float s = sinb[row * 32 + j];
                    const float v = acc[m][n][r];
                    const float pv = __shfl_xor(v, 1);
                    const float o = (cc & 1) ? (pv * s + v * c) : (v * c - pv * s);
                    out[(size_t)row * DM + col] = f2b(o);
                }
            }
    } else {
#pragma unroll
        for (int m = 0; m < 2; ++m)
#pragma unroll
            for (int n = 0; n < 4; ++n) {
                const int row0 = tm + wm * 32 + m * 16 + cr;
                const int col = tn + wn * 64 + n * 16 + cc;
#pragma unroll
                for (int r = 0; r < 4; ++r)
                    out[(size_t)(row0 + r) * DM + col] = f2b(acc[m][n][r]);
            }
    }
}

// ---------------- fused w1/w3 GEMM + SiLU*mul -> bf16 (BM=64, BN=128) ----------------
__global__ __launch_bounds__(256) void ffn13_kernel(const u16* __restrict__ A,
    const u16* __restrict__ B1, const u16* __restrict__ B3, u16* __restrict__ Z) {
    __shared__ __align__(16) u16 sA[64 * 32];
    __shared__ __align__(16) u16 sB1[128 * 32];
    __shared__ __align__(16) u16 sB3[128 * 32];
    const int lid = xcd_swz(blockIdx.y * gridDim.x + blockIdx.x, 16 * 22);
    const int tm = (lid % 16) * 64;
    const int tn = (lid / 16) * 128;
    const int tid = threadIdx.x, lane = tid & 63;
    const int wid = tid >> 6, wm = wid >> 1, wn = wid & 1;
    const int fr = lane & 15, g = lane >> 4;

    f32x4 acc1[2][4] = {}, acc3[2][4] = {};
    for (int k0 = 0; k0 < DM; k0 += 32) {
        {
            const int r = tid >> 2, c = (((tid & 3) ^ (r & 3))) * 8;
            gll16(&A[(size_t)(tm + r) * DM + k0 + c], &sA[tid * 8]);
        }
#pragma unroll
        for (int j = 0; j < 2; ++j) {
            const int idx = j * 256 + tid, r = idx >> 2;
            const int c = (((idx & 3) ^ (r & 3))) * 8;
            gll16(&B1[(size_t)(tn + r) * DM + k0 + c], &sB1[idx * 8]);
            gll16(&B3[(size_t)(tn + r) * DM + k0 + c], &sB3[idx * 8]);
        }
        __syncthreads();
        bf16x8 af[2], b1v[4], b3v[4];
#pragma unroll
        for (int m = 0; m < 2; ++m) {
            const int row = wm * 32 + m * 16 + fr;
            af[m] = *(const bf16x8*)&sA[row * 32 + ((g ^ (row & 3)) * 8)];
        }
#pragma unroll
        for (int n = 0; n < 4; ++n) {
            const int row = wn * 64 + n * 16 + fr;
            b1v[n] = *(const bf16x8*)&sB1[row * 32 + ((g ^ (row & 3)) * 8)];
            b3v[n] = *(const bf16x8*)&sB3[row * 32 + ((g ^ (row & 3)) * 8)];
        }
#pragma unroll
        for (int m = 0; m < 2; ++m)
#pragma unroll
            for (int n = 0; n < 4; ++n) {
                acc1[m][n] = __builtin_amdgcn_mfma_f32_16x16x32_bf16(af[m], b1v[n], acc1[m][n], 0, 0, 0);
                acc3[m][n] = __builtin_amdgcn_mfma_f32_16x16x32_bf16(af[m], b3v[n], acc3[m][n], 0, 0, 0);
            }
        __syncthreads();
    }

    const int cr = (lane >> 4) * 4, cc = lane & 15;
#pragma unroll
    for (int m = 0; m < 2; ++m)
#pragma unroll
        for (int n = 0; n < 4; ++n) {
            const int row0 = tm + wm * 32 + m * 16 + cr;
            const int col = tn + wn * 64 + n * 16 + cc;
#pragma unroll
            for (int r = 0; r < 4; ++r) {
                const float a1 = acc1[m][n][r];
                const float a3 = acc3[m][n][r];
                const float z = a1 / (1.f + __expf(-a1)) * a3;
                Z[(size_t)(row0 + r) * FFD + col] = f2b(z);
            }
        }
}

// ---------------- flash attention: block = (64 q-rows, 1 head), 4 waves ----------------
__global__ __launch_bounds__(256) void fattn_kernel(const u16* __restrict__ qb,
    const u16* __restrict__ kb, const u16* __restrict__ vb,
    const int* __restrict__ span, u16* __restrict__ ob) {
    __shared__ __align__(16) u16 sK[64][72];   // K rows, padded
    __shared__ __align__(16) u16 sVT[64][72];  // V transposed: [d][key]
    __shared__ __align__(16) u16 sP[4][16][72];// per-wave P tile
    const int tid = threadIdx.x, lane = tid & 63, wq = tid >> 6;
    const int g = lane >> 4, fr = lane & 15;
    const int head = blockIdx.y;
    const int qbase = blockIdx.x * 64;

    bf16x8 qfr[2];
    {
        const u16* qp = qb + (size_t)(qbase + wq * 16 + fr) * DM + head * HDIM + g * 8;
        qfr[0] = *(const bf16x8*)(qp);
        qfr[1] = *(const bf16x8*)(qp + 32);
    }
    int sq[4];
#pragma unroll
    for (int r = 0; r < 4; ++r) sq[r] = span[qbase + wq * 16 + g * 4 + r];

    float m_old[4] = {-1e30f, -1e30f, -1e30f, -1e30f};
    float lsum[4] = {0.f, 0.f, 0.f, 0.f};
    f32x4 acc[4] = {};

    for (int kb0 = 0; kb0 < SEQ; kb0 += 64) {
        __syncthreads();
        {
            const int r = tid >> 2, c0 = (tid & 3) * 16;
            const u16* src = kb + (size_t)(kb0 + r) * DM + head * HDIM + c0;
            *(u16x8*)&sK[r][c0]     = *(const u16x8*)(src);
            *(u16x8*)&sK[r][c0 + 8] = *(const u16x8*)(src + 8);
        }
        {
            const int k = tid & 63, d0 = (tid >> 6) * 16;
            const u16* src = vb + (size_t)(kb0 + k) * DM + head * HDIM + d0;
            const u16x8 v0 = *(const u16x8*)(src);
            const u16x8 v1 = *(const u16x8*)(src + 8);
#pragma unroll
            for (int j = 0; j < 8; ++j) {
                sVT[d0 + j][k]     = v0[j];
                sVT[d0 + 8 + j][k] = v1[j];
            }
        }
        __syncthreads();

        f32x4 accs[4] = {};
        __builtin_amdgcn_s_setprio(1);
#pragma unroll
        for (int nf = 0; nf < 4; ++nf)
#pragma unroll
            for (int kf = 0; kf < 2; ++kf) {
                const bf16x8 kfv = *(const bf16x8*)&sK[nf * 16 + fr][g * 8 + kf * 32];
                accs[nf] = __builtin_amdgcn_mfma_f32_16x16x32_bf16(qfr[kf], kfv, accs[nf], 0, 0, 0);
            }
        __builtin_amdgcn_s_setprio(0);

        int spk[4];
#pragma unroll
        for (int nf = 0; nf < 4; ++nf) spk[nf] = span[kb0 + nf * 16 + fr];
        float sv[4][4]; bool al[4][4];
#pragma unroll
        for (int nf = 0; nf < 4; ++nf) {
            const int key = kb0 + nf * 16 + fr;
#pragma unroll
            for (int r = 0; r < 4; ++r) {
                const int q = qbase + wq * 16 + g * 4 + r;
                al[nf][r] = (key <= q) || (sq[r] > 0 && spk[nf] == sq[r]);
                sv[nf][r] = al[nf][r] ? accs[nf][r] * 0.125f : -1e30f;
            }
        }
        float alpha[4], ls[4];
#pragma unroll
        for (int r = 0; r < 4; ++r) {
            float mn = fmaxf(fmaxf(sv[0][r], sv[1][r]), fmaxf(sv[2][r], sv[3][r]));
            mn = grpmax16(mn);
            const float mnew = fmaxf(m_old[r], mn);
            alpha[r] = __expf(m_old[r] - mnew);
            m_old[r] = mnew;
            ls[r] = 0.f;
        }
        u16 pb[4][4];
#pragma unroll
        for (int nf = 0; nf < 4; ++nf)
#pragma unroll
            for (int r = 0; r < 4; ++r) {
                const float p = al[nf][r] ? __expf(sv[nf][r] - m_old[r]) : 0.f;
                ls[r] += p;
                pb[nf][r] = f2b(p);
            }
#pragma unroll
        for (int r = 0; r < 4; ++r) {
            lsum[r] = lsum[r] * alpha[r] + grpsum16(ls[r]);
#pragma unroll
            for (int nf = 0; nf < 4; ++nf) acc[nf][r] *= alpha[r];
        }
#pragma unroll
        for (int nf = 0; nf < 4; ++nf)
#pragma unroll
            for (int r = 0; r < 4; ++r)
                sP[wq][g * 4 + r][nf * 16 + fr] = pb[nf][r];

        __builtin_amdgcn_s_setprio(1);
#pragma unroll
        for (int nf = 0; nf < 4; ++nf)
#pragma unroll
            for (int kf = 0; kf < 2; ++kf) {
                const bf16x8 pa  = *(const bf16x8*)&sP[wq][fr][g * 8 + kf * 32];
                const bf16x8 vtb = *(const bf16x8*)&sVT[nf * 16 + fr][g * 8 + kf * 32];
                acc[nf] = __builtin_amdgcn_mfma_f32_16x16x32_bf16(pa, vtb, acc[nf], 0, 0, 0);
            }
        __builtin_amdgcn_s_setprio(0);
    }

#pragma unroll
    for (int nf = 0; nf < 4; ++nf)
#pragma unroll
        for (int r = 0; r < 4; ++r) {
            const int q = qbase + wq * 16 + g * 4 + r;
            const int d = nf * 16 + fr;
            ob[(size_t)q * DM + head * HDIM + d] = f2b(acc[nf][r] / lsum[r]);
        }
}

extern "C" void kernel_launch(void* const* d_in, const int* in_sizes, int n_in,
                              void* d_out, int out_size, void* d_ws, size_t ws_size,
                              hipStream_t stream) {
    (void)in_sizes; (void)n_in; (void)out_size; (void)ws_size;
    const int*   tokens   = (const int*)d_in[0];
    const float* tok_emb  = (const float*)d_in[1];
    const float* wq       = (const float*)d_in[2];
    const float* wk       = (const float*)d_in[3];
    const float* wvw      = (const float*)d_in[4];
    const float* wo       = (const float*)d_in[5];
    const float* w1       = (const float*)d_in[6];
    const float* w2       = (const float*)d_in[7];
    const float* w3       = (const float*)d_in[8];
    const float* attn_nw  = (const float*)d_in[9];
    const float* ffn_nw   = (const float*)d_in[10];
    const float* final_nw = (const float*)d_in[11];
    const float* w_out    = (const float*)d_in[12];
    float* logits = (float*)d_out;

    char* ws = (char*)d_ws;
    size_t off = 0;
    auto alloc = [&](size_t b) { size_t o = off; off += (b + 255) & ~(size_t)255; return o; };
    float* h    = (float*)(ws + alloc((size_t)SEQ * DM * 4));
    u16*   xn   = (u16*)  (ws + alloc((size_t)SEQ * DM * 2));
    u16*   qb   = (u16*)  (ws + alloc((size_t)SEQ * DM * 2));
    u16*   kb   = (u16*)  (ws + alloc((size_t)SEQ * DM * 2));
    u16*   vb   = (u16*)  (ws + alloc((size_t)SEQ * DM * 2));
    u16*   ab   = (u16*)  (ws + alloc((size_t)SEQ * DM * 2));
    u16*   zb   = (u16*)  (ws + alloc((size_t)SEQ * FFD * 2));
    float* cosb = (float*)(ws + alloc((size_t)SEQ * 32 * 4));
    float* sinb = (float*)(ws + alloc((size_t)SEQ * 32 * 4));
    int*   span = (int*)  (ws + alloc((size_t)SEQ * 4));
    // bf16 weight copies
    const size_t nQ = (size_t)NLAY * DM * DM;     // wq/wk/wv/wo each
    const size_t nF = (size_t)NLAY * FFD * DM;    // w1/w2/w3 each
    const size_t nO = (size_t)VOC * DM;           // w_out
    u16* wqb = (u16*)(ws + alloc(nQ * 2));
    u16* wkb = (u16*)(ws + alloc(nQ * 2));
    u16* wvb = (u16*)(ws + alloc(nQ * 2));
    u16* wob = (u16*)(ws + alloc(nQ * 2));
    u16* w1b = (u16*)(ws + alloc(nF * 2));
    u16* w2b = (u16*)(ws + alloc(nF * 2));
    u16* w3b = (u16*)(ws + alloc(nF * 2));
    u16* woub = (u16*)(ws + alloc(nO * 2));

    auto cvt = [&](const float* s, u16* d, size_t n) {
        const int n8 = (int)(n / 8);
        const int blocks = (n8 + 255) / 256 < 2048 ? (n8 + 255) / 256 : 2048;
        cvt_kernel<<<blocks, 256, 0, stream>>>(s, d, n8);
    };
    cvt(wq, wqb, nQ); cvt(wk, wkb, nQ); cvt(wvw, wvb, nQ); cvt(wo, wob, nQ);
    cvt(w1, w1b, nF); cvt(w2, w2b, nF); cvt(w3, w3b, nF);
    cvt(w_out, woub, nO);

    embed_kernel<<<SEQ, 256, 0, stream>>>(tokens, tok_emb, h);
    ropetab_kernel<<<(SEQ * 32) / 256, 256, 0, stream>>>(cosb, sinb);
    span_kernel<<<1, SEQ, 0, stream>>>(tokens, span);

    for (int l = 0; l < NLAY; ++l) {
        rmsnorm_kernel<<<SEQ, 256, 0, stream>>>(h, attn_nw + (size_t)l * DM, xn);
        qkv_kernel<<<dim3(16, 24), 256, 0, stream>>>(
            xn, wqb + (size_t)l * DM * DM, wkb + (size_t)l * DM * DM, wvb + (size_t)l * DM * DM,
            cosb, sinb, qb, kb, vb);
        fattn_kernel<<<dim3(SEQ / 64, NHEADS), 256, 0, stream>>>(qb, kb, vb, span, ab);
        gemm_nt_kernel<1, 64, 64><<<dim3(16, 16), 256, 0, stream>>>(
            ab, wob + (size_t)l * DM * DM, h, h, DM, DM);

        rmsnorm_kernel<<<SEQ, 256, 0, stream>>>(h, ffn_nw + (size_t)l * DM, xn);
        ffn13_kernel<<<dim3(16, 22), 256, 0, stream>>>(
            xn, w1b + (size_t)l * FFD * DM, w3b + (size_t)l * FFD * DM, zb);
        gemm_nt_kernel<1, 64, 64><<<dim3(16, 16), 256, 0, stream>>>(
            zb, w2b + (size_t)l * DM * FFD, h, h, DM, FFD);
    }

    rmsnorm_kernel<<<SEQ, 256, 0, stream>>>(h, final_nw, xn);
    gemm_big_kernel<0><<<dim3(SEQ / 256, VOC / 256), 512, 0, stream>>>(
        xn, woub, logits, nullptr, VOC, DM);
}

// Round 7
// 426.180 us; speedup vs baseline: 9.2231x; 1.2425x over previous
//
#include <hip/hip_runtime.h>
#include <hip/hip_bf16.h>
#include <stdint.h>

typedef unsigned short u16;
typedef __bf16 bf16x8 __attribute__((ext_vector_type(8)));
typedef u16 u16x8 __attribute__((ext_vector_type(8)));
typedef float f32x4 __attribute__((ext_vector_type(4)));

#define SEQ   1024
#define DM    1024
#define NHEADS 16
#define HDIM  64
#define VOC   32000
#define FFD   2816
#define NLAY  2

__device__ __forceinline__ u16 f2b(float f) {
    unsigned x = __builtin_bit_cast(unsigned, f);
    unsigned r = x + 0x7fffu + ((x >> 16) & 1u);
    return (u16)(r >> 16);
}
__device__ __forceinline__ float b2f(u16 u) {
    unsigned x = ((unsigned)u) << 16;
    return __builtin_bit_cast(float, x);
}
__device__ __forceinline__ float grpmax16(float v) {
    v = fmaxf(v, __shfl_xor(v, 1)); v = fmaxf(v, __shfl_xor(v, 2));
    v = fmaxf(v, __shfl_xor(v, 4)); v = fmaxf(v, __shfl_xor(v, 8));
    return v;
}
__device__ __forceinline__ float grpsum16(float v) {
    v += __shfl_xor(v, 1); v += __shfl_xor(v, 2);
    v += __shfl_xor(v, 4); v += __shfl_xor(v, 8);
    return v;
}

// async global->LDS, 16 bytes per lane. LDS dest must be wave-uniform base + lane*16.
__device__ __forceinline__ void gll16(const void* g, void* l) {
    __builtin_amdgcn_global_load_lds(
        (__attribute__((address_space(1))) void*)(uintptr_t)g,
        (__attribute__((address_space(3))) void*)(uint32_t)(uintptr_t)l,
        16, 0, 0);
}
template <int N> __device__ __forceinline__ void vwait() {
    if constexpr (N == 0)       asm volatile("s_waitcnt vmcnt(0)" ::: "memory");
    else if constexpr (N == 4)  asm volatile("s_waitcnt vmcnt(4)" ::: "memory");
    else if constexpr (N == 8)  asm volatile("s_waitcnt vmcnt(8)" ::: "memory");
    else if constexpr (N == 10) asm volatile("s_waitcnt vmcnt(10)" ::: "memory");
    else if constexpr (N == 16) asm volatile("s_waitcnt vmcnt(16)" ::: "memory");
}
// bijective XCD swizzle for any nwg (m204): per-XCD contiguous logical chunks.
__device__ __forceinline__ int xcd_swz(int bid, int nwg) {
    const int q = nwg >> 3, r = nwg & 7;
    const int xcd = bid & 7, j = bid >> 3;
    const int start = (xcd < r) ? xcd * (q + 1) : r * (q + 1) + (xcd - r) * q;
    return start + j;
}

// ---------------- fp32 -> bf16 weight conversion (grid-stride, BW-bound) ----------------
__global__ __launch_bounds__(256) void cvt_kernel(const float* __restrict__ s,
                                                  u16* __restrict__ d, int n8) {
    const int stride = gridDim.x * 256;
    for (int i = blockIdx.x * 256 + threadIdx.x; i < n8; i += stride) {
        const float4 a = ((const float4*)s)[2 * i];
        const float4 b = ((const float4*)s)[2 * i + 1];
        ushort4 p, q;
        p.x = f2b(a.x); p.y = f2b(a.y); p.z = f2b(a.z); p.w = f2b(a.w);
        q.x = f2b(b.x); q.y = f2b(b.y); q.z = f2b(b.z); q.w = f2b(b.w);
        ((ushort4*)d)[2 * i] = p;
        ((ushort4*)d)[2 * i + 1] = q;
    }
}

// ---------------- embedding gather ----------------
__global__ __launch_bounds__(256) void embed_kernel(const int* __restrict__ tok,
    const float* __restrict__ emb, float* __restrict__ h) {
    const int l = blockIdx.x;
    const int t = tok[l];
    ((float4*)(h + (size_t)l * DM))[threadIdx.x] =
        ((const float4*)(emb + (size_t)t * DM))[threadIdx.x];
}

// ---------------- rope tables ----------------
__global__ __launch_bounds__(256) void ropetab_kernel(float* __restrict__ cosb,
                                                      float* __restrict__ sinb) {
    const int idx = blockIdx.x * 256 + threadIdx.x;   // < SEQ*32
    const int l = idx >> 5, j = idx & 31;
    const float inv = __expf(-((float)j * (1.0f / 32.0f)) * 13.122363377404328f); // ln(500000)
    const float ang = (float)l * inv;
    cosb[idx] = cosf(ang);
    sinb[idx] = sinf(ang);
}

// ---------------- transfusion span ids ----------------
__global__ void span_kernel(const int* __restrict__ tok, int* __restrict__ span) {
    __shared__ int sb[SEQ], se[SEQ];
    const int t = threadIdx.x;
    const int v = tok[t];
    const int bo = (v == 31998) ? 1 : 0;
    const int eo = (v == 31999) ? 1 : 0;
    sb[t] = bo; se[t] = eo;
    __syncthreads();
    for (int o = 1; o < SEQ; o <<= 1) {
        int a = 0, b = 0;
        if (t >= o) { a = sb[t - o]; b = se[t - o]; }
        __syncthreads();
        sb[t] += a; se[t] += b;
        __syncthreads();
    }
    const int bc = sb[t];
    const int ec = se[t] - eo;           // exclusive eoi cumsum
    span[t] = (bc > ec) ? bc : 0;
}

// ---------------- rmsnorm (fp32 in -> bf16 out) ----------------
__global__ __launch_bounds__(256) void rmsnorm_kernel(const float* __restrict__ x,
    const float* __restrict__ w, u16* __restrict__ o) {
    const int row = blockIdx.x;
    const float4 xv = ((const float4*)(x + (size_t)row * DM))[threadIdx.x];
    float ss = xv.x * xv.x + xv.y * xv.y + xv.z * xv.z + xv.w * xv.w;
    for (int off = 32; off; off >>= 1) ss += __shfl_xor(ss, off);
    __shared__ float red[4];
    const int lane = threadIdx.x & 63, wvi = threadIdx.x >> 6;
    if (lane == 0) red[wvi] = ss;
    __syncthreads();
    const float tot = red[0] + red[1] + red[2] + red[3];
    const float sc = rsqrtf(tot * (1.0f / (float)DM) + 1e-5f);
    const float4 wv4 = ((const float4*)w)[threadIdx.x];
    ushort4 ov;
    ov.x = f2b(xv.x * sc * wv4.x);
    ov.y = f2b(xv.y * sc * wv4.y);
    ov.z = f2b(xv.z * sc * wv4.z);
    ov.w = f2b(xv.w * sc * wv4.w);
    ((ushort4*)(o + (size_t)row * DM))[threadIdx.x] = ov;
}

// ======================= pipelined GEMM (BK=64, counted vmcnt) =======================
// LDS rows are 128B; granule swizzle gr' = gr ^ (row&7) is bank-conflict-free; swizzle
// baked into per-thread staging pointers (advance +64/tile).
// Per K-tile: {stage t+1 -> buf p^1} ; vwait<LOADS> (own tile-t loads done, t+1 loads
// stay in flight) ; s_barrier (all waves' tile-t resident) ; ds_read p + MFMA ;
// s_barrier (reads of p closed before iter t+1 writes p). No vmcnt(0) drain in loop.

// ---------------- generic pipelined GEMM, fp32 out (+optional residual) ----------------
template <int RESID, int BM, int BN>
__global__ __launch_bounds__(256) void gemm_p_kernel(const u16* __restrict__ A,
    const u16* __restrict__ B, float* __restrict__ C, const float* __restrict__ res,
    int N, int K) {
    constexpr int AL = BM / 32, BL = BN / 32, LOADS = AL + BL;
    constexpr int MF = BM / 32, NF = BN / 32;
    __shared__ __align__(16) u16 sA[2][BM * 64];
    __shared__ __align__(16) u16 sB[2][BN * 64];
    const int nwg = gridDim.x * gridDim.y;
    const int lid = xcd_swz(blockIdx.y * gridDim.x + blockIdx.x, nwg);
    const int tm = (lid % gridDim.x) * BM, tn = (lid / gridDim.x) * BN;
    const int tid = threadIdx.x, lane = tid & 63, wid = tid >> 6;
    const int wm = wid >> 1, wn = wid & 1, fr = lane & 15, g = lane >> 4;

    const u16* ap[AL]; const u16* bp[BL];
#pragma unroll
    for (int j = 0; j < AL; ++j) {
        const int idx = j * 256 + tid, r = idx >> 3, gr = (idx & 7) ^ (r & 7);
        ap[j] = A + (size_t)(tm + r) * K + gr * 8;
    }
#pragma unroll
    for (int j = 0; j < BL; ++j) {
        const int idx = j * 256 + tid, r = idx >> 3, gr = (idx & 7) ^ (r & 7);
        bp[j] = B + (size_t)(tn + r) * K + gr * 8;
    }

    f32x4 acc[MF][NF] = {};
    const int NT = K >> 6;
#pragma unroll
    for (int j = 0; j < AL; ++j) gll16(ap[j], &sA[0][(j * 256 + tid) * 8]);
#pragma unroll
    for (int j = 0; j < BL; ++j) gll16(bp[j], &sB[0][(j * 256 + tid) * 8]);

    int p = 0;
    for (int t = 0; t < NT; ++t) {
        if (t + 1 < NT) {
#pragma unroll
            for (int j = 0; j < AL; ++j) gll16(ap[j] + (t + 1) * 64, &sA[p ^ 1][(j * 256 + tid) * 8]);
#pragma unroll
            for (int j = 0; j < BL; ++j) gll16(bp[j] + (t + 1) * 64, &sB[p ^ 1][(j * 256 + tid) * 8]);
            vwait<LOADS>();
        } else {
            vwait<0>();
        }
        __builtin_amdgcn_s_barrier();          // all waves' tile-t data resident
        __builtin_amdgcn_sched_barrier(0);
        bf16x8 af[MF][2], bfv[NF][2];
#pragma unroll
        for (int m = 0; m < MF; ++m)
#pragma unroll
            for (int ks = 0; ks < 2; ++ks) {
                const int row = wm * (BM / 2) + m * 16 + fr;
                const int gr = (ks * 4 + g) ^ (row & 7);
                af[m][ks] = *(const bf16x8*)&sA[p][row * 64 + gr * 8];
            }
#pragma unroll
        for (int n = 0; n < NF; ++n)
#pragma unroll
            for (int ks = 0; ks < 2; ++ks) {
                const int row = wn * (BN / 2) + n * 16 + fr;
                const int gr = (ks * 4 + g) ^ (row & 7);
                bfv[n][ks] = *(const bf16x8*)&sB[p][row * 64 + gr * 8];
            }
        __builtin_amdgcn_s_setprio(1);
#pragma unroll
        for (int m = 0; m < MF; ++m)
#pragma unroll
            for (int n = 0; n < NF; ++n)
#pragma unroll
                for (int ks = 0; ks < 2; ++ks)
                    acc[m][n] = __builtin_amdgcn_mfma_f32_16x16x32_bf16(af[m][ks], bfv[n][ks], acc[m][n], 0, 0, 0);
        __builtin_amdgcn_s_setprio(0);
        __builtin_amdgcn_s_barrier();          // reads of buf p closed before next writes
        p ^= 1;
    }

    const int cr = (lane >> 4) * 4, cc = lane & 15;
#pragma unroll
    for (int m = 0; m < MF; ++m)
#pragma unroll
        for (int n = 0; n < NF; ++n) {
            const int row0 = tm + wm * (BM / 2) + m * 16 + cr;
            const int col = tn + wn * (BN / 2) + n * 16 + cc;
#pragma unroll
            for (int r = 0; r < 4; ++r) {
                const size_t idx = (size_t)(row0 + r) * N + col;
                float v = acc[m][n][r];
                if (RESID) v += res[idx];
                C[idx] = v;
            }
        }
}

// ======================= 256x256 / BK=64 / 8-wave counted-pipeline GEMM =======================
template <int RESID>
__global__ __launch_bounds__(512, 2) void gemm_big_kernel(const u16* __restrict__ A,
    const u16* __restrict__ B, float* __restrict__ C, const float* __restrict__ res,
    int N, int K) {
    __shared__ __align__(16) u16 sA[2][256 * 64];
    __shared__ __align__(16) u16 sB[2][256 * 64];
    const int nwg = gridDim.x * gridDim.y;
    const int lid = xcd_swz(blockIdx.y * gridDim.x + blockIdx.x, nwg);
    const int tm = (lid % gridDim.x) * 256;
    const int tn = (lid / gridDim.x) * 256;
    const int tid = threadIdx.x, lane = tid & 63, wid = tid >> 6;
    const int wm = wid >> 2, wn = wid & 3;       // 2 x 4 waves, per-wave 128x64
    const int fr = lane & 15, g = lane >> 4;

    const u16* ap[4]; const u16* bp[4];
#pragma unroll
    for (int j = 0; j < 4; ++j) {
        const int idx = j * 512 + tid, r = idx >> 3, gr = (idx & 7) ^ (r & 7);
        ap[j] = A + (size_t)(tm + r) * K + gr * 8;
        bp[j] = B + (size_t)(tn + r) * K + gr * 8;
    }

    f32x4 acc[8][4] = {};
    const int NT = K >> 6;
#pragma unroll
    for (int j = 0; j < 4; ++j) gll16(ap[j], &sA[0][(j * 512 + tid) * 8]);
#pragma unroll
    for (int j = 0; j < 4; ++j) gll16(bp[j], &sB[0][(j * 512 + tid) * 8]);

    int p = 0;
    for (int t = 0; t < NT; ++t) {
        if (t + 1 < NT) {
#pragma unroll
            for (int j = 0; j < 4; ++j) gll16(ap[j] + (t + 1) * 64, &sA[p ^ 1][(j * 512 + tid) * 8]);
#pragma unroll
            for (int j = 0; j < 4; ++j) gll16(bp[j] + (t + 1) * 64, &sB[p ^ 1][(j * 512 + tid) * 8]);
            vwait<8>();
        } else {
            vwait<0>();
        }
        __builtin_amdgcn_s_barrier();
        __builtin_amdgcn_sched_barrier(0);
        bf16x8 bfv[4][2];
#pragma unroll
        for (int n = 0; n < 4; ++n)
#pragma unroll
            for (int ks = 0; ks < 2; ++ks) {
                const int row = wn * 64 + n * 16 + fr;
                const int gr = (ks * 4 + g) ^ (row & 7);
                bfv[n][ks] = *(const bf16x8*)&sB[p][row * 64 + gr * 8];
            }
#pragma unroll
        for (int mq = 0; mq < 4; ++mq) {
            bf16x8 af[2][2];
#pragma unroll
            for (int i = 0; i < 2; ++i)
#pragma unroll
                for (int ks = 0; ks < 2; ++ks) {
                    const int row = wm * 128 + (mq * 2 + i) * 16 + fr;
                    const int gr = (ks * 4 + g) ^ (row & 7);
                    af[i][ks] = *(const bf16x8*)&sA[p][row * 64 + gr * 8];
                }
            __builtin_amdgcn_s_setprio(1);
#pragma unroll
            for (int i = 0; i < 2; ++i)
#pragma unroll
                for (int n = 0; n < 4; ++n)
#pragma unroll
                    for (int ks = 0; ks < 2; ++ks)
                        acc[mq * 2 + i][n] = __builtin_amdgcn_mfma_f32_16x16x32_bf16(
                            af[i][ks], bfv[n][ks], acc[mq * 2 + i][n], 0, 0, 0);
            __builtin_amdgcn_s_setprio(0);
        }
        __builtin_amdgcn_s_barrier();
        p ^= 1;
    }

    const int cr = (lane >> 4) * 4, cc = lane & 15;
#pragma unroll
    for (int m = 0; m < 8; ++m)
#pragma unroll
        for (int n = 0; n < 4; ++n) {
            const int row0 = tm + wm * 128 + m * 16 + cr;
            const int col = tn + wn * 64 + n * 16 + cc;
#pragma unroll
            for (int r = 0; r < 4; ++r) {
                const size_t idx = (size_t)(row0 + r) * N + col;
                float v = acc[m][n][r];
                if (RESID) v += res[idx];
                C[idx] = v;
            }
        }
}

// ---------------- fused QKV GEMM (128x128) + RoPE + bf16 cast ----------------
__global__ __launch_bounds__(256) void qkv_kernel(const u16* __restrict__ A,
    const u16* __restrict__ Bq, const u16* __restrict__ Bk, const u16* __restrict__ Bv,
    const float* __restrict__ cosb, const float* __restrict__ sinb,
    u16* __restrict__ qb, u16* __restrict__ kb, u16* __restrict__ vb) {
    __shared__ __align__(16) u16 sA[2][128 * 64];
    __shared__ __align__(16) u16 sB[2][128 * 64];
    const int lid = xcd_swz(blockIdx.y * gridDim.x + blockIdx.x, 8 * 24);
    const int tm = (lid % 8) * 128;
    const int yy = lid / 8;
    const int mat = yy >> 3;
    const int tn = (yy & 7) * 128;
    const u16* B = (mat == 0) ? Bq : (mat == 1) ? Bk : Bv;
    u16* out = (mat == 0) ? qb : (mat == 1) ? kb : vb;
    const int tid = threadIdx.x, lane = tid & 63, wid = tid >> 6;
    const int wm = wid >> 1, wn = wid & 1, fr = lane & 15, g = lane >> 4;

    const u16* ap[4]; const u16* bp[4];
#pragma unroll
    for (int j = 0; j < 4; ++j) {
        const int idx = j * 256 + tid, r = idx >> 3, gr = (idx & 7) ^ (r & 7);
        ap[j] = A + (size_t)(tm + r) * DM + gr * 8;
        bp[j] = B + (size_t)(tn + r) * DM + gr * 8;
    }

    f32x4 acc[4][4] = {};
#pragma unroll
    for (int j = 0; j < 4; ++j) gll16(ap[j], &sA[0][(j * 256 + tid) * 8]);
#pragma unroll
    for (int j = 0; j < 4; ++j) gll16(bp[j], &sB[0][(j * 256 + tid) * 8]);

    int p = 0;
    for (int t = 0; t < DM / 64; ++t) {
        if (t + 1 < DM / 64) {
#pragma unroll
            for (int j = 0; j < 4; ++j) gll16(ap[j] + (t + 1) * 64, &sA[p ^ 1][(j * 256 + tid) * 8]);
#pragma unroll
            for (int j = 0; j < 4; ++j) gll16(bp[j] + (t + 1) * 64, &sB[p ^ 1][(j * 256 + tid) * 8]);
            vwait<8>();
        } else {
            vwait<0>();
        }
        __builtin_amdgcn_s_barrier();
        __builtin_amdgcn_sched_barrier(0);
        bf16x8 af[4][2], bfv[4][2];
#pragma unroll
        for (int m = 0; m < 4; ++m)
#pragma unroll
            for (int ks = 0; ks < 2; ++ks) {
                const int row = wm * 64 + m * 16 + fr;
                const int gr = (ks * 4 + g) ^ (row & 7);
                af[m][ks] = *(const bf16x8*)&sA[p][row * 64 + gr * 8];
            }
#pragma unroll
        for (int n = 0; n < 4; ++n)
#pragma unroll
            for (int ks = 0; ks < 2; ++ks) {
                const int row = wn * 64 + n * 16 + fr;
                const int gr = (ks * 4 + g) ^ (row & 7);
                bfv[n][ks] = *(const bf16x8*)&sB[p][row * 64 + gr * 8];
            }
        __builtin_amdgcn_s_setprio(1);
#pragma unroll
        for (int m = 0; m < 4; ++m)
#pragma unroll
            for (int n = 0; n < 4; ++n)
#pragma unroll
                for (int ks = 0; ks < 2; ++ks)
                    acc[m][n] = __builtin_amdgcn_mfma_f32_16x16x32_bf16(af[m][ks], bfv[n][ks], acc[m][n], 0, 0, 0);
        __builtin_amdgcn_s_setprio(0);
        __builtin_amdgcn_s_barrier();
        p ^= 1;
    }

    const int cr = (lane >> 4) * 4, cc = lane & 15;
    if (mat < 2) {
#pragma unroll
        for (int m = 0; m < 4; ++m)
#pragma unroll
            for (int n = 0; n < 4; ++n) {
                const int row0 = tm + wm * 64 + m * 16 + cr;
                const int col = tn + wn * 64 + n * 16 + cc;
                const int j = (n * 16 + cc) >> 1;    // rope pair index within head
#pragma unroll
                for (int r = 0; r < 4; ++r) {
                    const int row = row0 + r;
                    const float c = cosb[row * 32 + j];
                    const float s = sinb[row * 32 + j];
                    const float v = acc[m][n][r];
                    const float pv = __shfl_xor(v, 1);
                    const float o = (cc & 1) ? (pv * s + v * c) : (v * c - pv * s);
                    out[(size_t)row * DM + col] = f2b(o);
                }
            }
    } else {
#pragma unroll
        for (int m = 0; m < 4; ++m)
#pragma unroll
            for (int n = 0; n < 4; ++n) {
                const int row0 = tm + wm * 64 + m * 16 + cr;
                const int col = tn + wn * 64 + n * 16 + cc;
#pragma unroll
                for (int r = 0; r < 4; ++r)
                    out[(size_t)(row0 + r) * DM + col] = f2b(acc[m][n][r]);
            }
    }
}

// ---------------- fused w1/w3 GEMM (64x128 dual-B) + SiLU*mul -> bf16 ----------------
__global__ __launch_bounds__(256) void ffn13_kernel(const u16* __restrict__ A,
    const u16* __restrict__ B1, const u16* __restrict__ B3, u16* __restrict__ Z) {
    __shared__ __align__(16) u16 sA[2][64 * 64];
    __shared__ __align__(16) u16 sB1[2][128 * 64];
    __shared__ __align__(16) u16 sB3[2][128 * 64];
    const int lid = xcd_swz(blockIdx.y * gridDim.x + blockIdx.x, 16 * 22);
    const int tm = (lid % 16) * 64;
    const int tn = (lid / 16) * 128;
    const int tid = threadIdx.x, lane = tid & 63, wid = tid >> 6;
    const int wm = wid >> 1, wn = wid & 1, fr = lane & 15, g = lane >> 4;

    const u16* ap[2]; const u16* b1p[4]; const u16* b3p[4];
#pragma unroll
    for (int j = 0; j < 2; ++j) {
        const int idx = j * 256 + tid, r = idx >> 3, gr = (idx & 7) ^ (r & 7);
        ap[j] = A + (size_t)(tm + r) * DM + gr * 8;
    }
#pragma unroll
    for (int j = 0; j < 4; ++j) {
        const int idx = j * 256 + tid, r = idx >> 3, gr = (idx & 7) ^ (r & 7);
        b1p[j] = B1 + (size_t)(tn + r) * DM + gr * 8;
        b3p[j] = B3 + (size_t)(tn + r) * DM + gr * 8;
    }

    f32x4 acc1[2][4] = {}, acc3[2][4] = {};
#pragma unroll
    for (int j = 0; j < 2; ++j) gll16(ap[j], &sA[0][(j * 256 + tid) * 8]);
#pragma unroll
    for (int j = 0; j < 4; ++j) gll16(b1p[j], &sB1[0][(j * 256 + tid) * 8]);
#pragma unroll
    for (int j = 0; j < 4; ++j) gll16(b3p[j], &sB3[0][(j * 256 + tid) * 8]);

    int p = 0;
    for (int t = 0; t < DM / 64; ++t) {
        if (t + 1 < DM / 64) {
#pragma unroll
            for (int j = 0; j < 2; ++j) gll16(ap[j] + (t + 1) * 64, &sA[p ^ 1][(j * 256 + tid) * 8]);
#pragma unroll
            for (int j = 0; j < 4; ++j) gll16(b1p[j] + (t + 1) * 64, &sB1[p ^ 1][(j * 256 + tid) * 8]);
#pragma unroll
            for (int j = 0; j < 4; ++j) gll16(b3p[j] + (t + 1) * 64, &sB3[p ^ 1][(j * 256 + tid) * 8]);
            vwait<10>();
        } else {
            vwait<0>();
        }
        __builtin_amdgcn_s_barrier();
        __builtin_amdgcn_sched_barrier(0);
        bf16x8 af[2][2], b1v[4][2], b3v[4][2];
#pragma unroll
        for (int m = 0; m < 2; ++m)
#pragma unroll
            for (int ks = 0; ks < 2; ++ks) {
                const int row = wm * 32 + m * 16 + fr;
                const int gr = (ks * 4 + g) ^ (row & 7);
                af[m][ks] = *(const bf16x8*)&sA[p][row * 64 + gr * 8];
            }
#pragma unroll
        for (int n = 0; n < 4; ++n)
#pragma unroll
            for (int ks = 0; ks < 2; ++ks) {
                const int row = wn * 64 + n * 16 + fr;
                const int gr = (ks * 4 + g) ^ (row & 7);
                b1v[n][ks] = *(const bf16x8*)&sB1[p][row * 64 + gr * 8];
                b3v[n][ks] = *(const bf16x8*)&sB3[p][row * 64 + gr * 8];
            }
        __builtin_amdgcn_s_setprio(1);
#pragma unroll
        for (int m = 0; m < 2; ++m)
#pragma unroll
            for (int n = 0; n < 4; ++n)
#pragma unroll
                for (int ks = 0; ks < 2; ++ks) {
                    acc1[m][n] = __builtin_amdgcn_mfma_f32_16x16x32_bf16(af[m][ks], b1v[n][ks], acc1[m][n], 0, 0, 0);
                    acc3[m][n] = __builtin_amdgcn_mfma_f32_16x16x32_bf16(af[m][ks], b3v[n][ks], acc3[m][n], 0, 0, 0);
                }
        __builtin_amdgcn_s_setprio(0);
        __builtin_amdgcn_s_barrier();
        p ^= 1;
    }

    const int cr = (lane >> 4) * 4, cc = lane & 15;
#pragma unroll
    for (int m = 0; m < 2; ++m)
#pragma unroll
        for (int n = 0; n < 4; ++n) {
            const int row0 = tm + wm * 32 + m * 16 + cr;
            const int col = tn + wn * 64 + n * 16 + cc;
#pragma unroll
            for (int r = 0; r < 4; ++r) {
                const float a1 = acc1[m][n][r];
                const float a3 = acc3[m][n][r];
                const float z = a1 / (1.f + __expf(-a1)) * a3;
                Z[(size_t)(row0 + r) * FFD + col] = f2b(z);
            }
        }
}

// ---------------- flash attention: block = (64 q-rows, 1 head), 4 waves ----------------
__global__ __launch_bounds__(256) void fattn_kernel(const u16* __restrict__ qb,
    const u16* __restrict__ kb, const u16* __restrict__ vb,
    const int* __restrict__ span, u16* __restrict__ ob) {
    __shared__ __align__(16) u16 sK[64][72];   // K rows, padded
    __shared__ __align__(16) u16 sVT[64][72];  // V transposed: [d][key]
    __shared__ __align__(16) u16 sP[4][16][72];// per-wave P tile
    const int tid = threadIdx.x, lane = tid & 63, wq = tid >> 6;
    const int g = lane >> 4, fr = lane & 15;
    const int head = blockIdx.y;
    const int qbase = blockIdx.x * 64;

    bf16x8 qfr[2];
    {
        const u16* qp = qb + (size_t)(qbase + wq * 16 + fr) * DM + head * HDIM + g * 8;
        qfr[0] = *(const bf16x8*)(qp);
        qfr[1] = *(const bf16x8*)(qp + 32);
    }
    int sq[4];
#pragma unroll
    for (int r = 0; r < 4; ++r) sq[r] = span[qbase + wq * 16 + g * 4 + r];

    float m_old[4] = {-1e30f, -1e30f, -1e30f, -1e30f};
    float lsum[4] = {0.f, 0.f, 0.f, 0.f};
    f32x4 acc[4] = {};

    for (int kb0 = 0; kb0 < SEQ; kb0 += 64) {
        __syncthreads();
        {
            const int r = tid >> 2, c0 = (tid & 3) * 16;
            const u16* src = kb + (size_t)(kb0 + r) * DM + head * HDIM + c0;
            *(u16x8*)&sK[r][c0]     = *(const u16x8*)(src);
            *(u16x8*)&sK[r][c0 + 8] = *(const u16x8*)(src + 8);
        }
        {
            const int k = tid & 63, d0 = (tid >> 6) * 16;
            const u16* src = vb + (size_t)(kb0 + k) * DM + head * HDIM + d0;
            const u16x8 v0 = *(const u16x8*)(src);
            const u16x8 v1 = *(const u16x8*)(src + 8);
#pragma unroll
            for (int j = 0; j < 8; ++j) {
                sVT[d0 + j][k]     = v0[j];
                sVT[d0 + 8 + j][k] = v1[j];
            }
        }
        __syncthreads();

        f32x4 accs[4] = {};
        __builtin_amdgcn_s_setprio(1);
#pragma unroll
        for (int nf = 0; nf < 4; ++nf)
#pragma unroll
            for (int kf = 0; kf < 2; ++kf) {
                const bf16x8 kfv = *(const bf16x8*)&sK[nf * 16 + fr][g * 8 + kf * 32];
                accs[nf] = __builtin_amdgcn_mfma_f32_16x16x32_bf16(qfr[kf], kfv, accs[nf], 0, 0, 0);
            }
        __builtin_amdgcn_s_setprio(0);

        int spk[4];
#pragma unroll
        for (int nf = 0; nf < 4; ++nf) spk[nf] = span[kb0 + nf * 16 + fr];
        float sv[4][4]; bool al[4][4];
#pragma unroll
        for (int nf = 0; nf < 4; ++nf) {
            const int key = kb0 + nf * 16 + fr;
#pragma unroll
            for (int r = 0; r < 4; ++r) {
                const int q = qbase + wq * 16 + g * 4 + r;
                al[nf][r] = (key <= q) || (sq[r] > 0 && spk[nf] == sq[r]);
                sv[nf][r] = al[nf][r] ? accs[nf][r] * 0.125f : -1e30f;
            }
        }
        float alpha[4], ls[4];
#pragma unroll
        for (int r = 0; r < 4; ++r) {
            float mn = fmaxf(fmaxf(sv[0][r], sv[1][r]), fmaxf(sv[2][r], sv[3][r]));
            mn = grpmax16(mn);
            const float mnew = fmaxf(m_old[r], mn);
            alpha[r] = __expf(m_old[r] - mnew);
            m_old[r] = mnew;
            ls[r] = 0.f;
        }
        u16 pb[4][4];
#pragma unroll
        for (int nf = 0; nf < 4; ++nf)
#pragma unroll
            for (int r = 0; r < 4; ++r) {
                const float p = al[nf][r] ? __expf(sv[nf][r] - m_old[r]) : 0.f;
                ls[r] += p;
                pb[nf][r] = f2b(p);
            }
#pragma unroll
        for (int r = 0; r < 4; ++r) {
            lsum[r] = lsum[r] * alpha[r] + grpsum16(ls[r]);
#pragma unroll
            for (int nf = 0; nf < 4; ++nf) acc[nf][r] *= alpha[r];
        }
#pragma unroll
        for (int nf = 0; nf < 4; ++nf)
#pragma unroll
            for (int r = 0; r < 4; ++r)
                sP[wq][g * 4 + r][nf * 16 + fr] = pb[nf][r];

        __builtin_amdgcn_s_setprio(1);
#pragma unroll
        for (int nf = 0; nf < 4; ++nf)
#pragma unroll
            for (int kf = 0; kf < 2; ++kf) {
                const bf16x8 pa  = *(const bf16x8*)&sP[wq][fr][g * 8 + kf * 32];
                const bf16x8 vtb = *(const bf16x8*)&sVT[nf * 16 + fr][g * 8 + kf * 32];
                acc[nf] = __builtin_amdgcn_mfma_f32_16x16x32_bf16(pa, vtb, acc[nf], 0, 0, 0);
            }
        __builtin_amdgcn_s_setprio(0);
    }

#pragma unroll
    for (int nf = 0; nf < 4; ++nf)
#pragma unroll
        for (int r = 0; r < 4; ++r) {
            const int q = qbase + wq * 16 + g * 4 + r;
            const int d = nf * 16 + fr;
            ob[(size_t)q * DM + head * HDIM + d] = f2b(acc[nf][r] / lsum[r]);
        }
}

extern "C" void kernel_launch(void* const* d_in, const int* in_sizes, int n_in,
                              void* d_out, int out_size, void* d_ws, size_t ws_size,
                              hipStream_t stream) {
    (void)in_sizes; (void)n_in; (void)out_size; (void)ws_size;
    const int*   tokens   = (const int*)d_in[0];
    const float* tok_emb  = (const float*)d_in[1];
    const float* wq       = (const float*)d_in[2];
    const float* wk       = (const float*)d_in[3];
    const float* wvw      = (const float*)d_in[4];
    const float* wo       = (const float*)d_in[5];
    const float* w1       = (const float*)d_in[6];
    const float* w2       = (const float*)d_in[7];
    const float* w3       = (const float*)d_in[8];
    const float* attn_nw  = (const float*)d_in[9];
    const float* ffn_nw   = (const float*)d_in[10];
    const float* final_nw = (const float*)d_in[11];
    const float* w_out    = (const float*)d_in[12];
    float* logits = (float*)d_out;

    char* ws = (char*)d_ws;
    size_t off = 0;
    auto alloc = [&](size_t b) { size_t o = off; off += (b + 255) & ~(size_t)255; return o; };
    float* h    = (float*)(ws + alloc((size_t)SEQ * DM * 4));
    u16*   xn   = (u16*)  (ws + alloc((size_t)SEQ * DM * 2));
    u16*   qb   = (u16*)  (ws + alloc((size_t)SEQ * DM * 2));
    u16*   kb   = (u16*)  (ws + alloc((size_t)SEQ * DM * 2));
    u16*   vb   = (u16*)  (ws + alloc((size_t)SEQ * DM * 2));
    u16*   ab   = (u16*)  (ws + alloc((size_t)SEQ * DM * 2));
    u16*   zb   = (u16*)  (ws + alloc((size_t)SEQ * FFD * 2));
    float* cosb = (float*)(ws + alloc((size_t)SEQ * 32 * 4));
    float* sinb = (float*)(ws + alloc((size_t)SEQ * 32 * 4));
    int*   span = (int*)  (ws + alloc((size_t)SEQ * 4));
    // bf16 weight copies
    const size_t nQ = (size_t)NLAY * DM * DM;     // wq/wk/wv/wo each
    const size_t nF = (size_t)NLAY * FFD * DM;    // w1/w2/w3 each
    const size_t nO = (size_t)VOC * DM;           // w_out
    u16* wqb = (u16*)(ws + alloc(nQ * 2));
    u16* wkb = (u16*)(ws + alloc(nQ * 2));
    u16* wvb = (u16*)(ws + alloc(nQ * 2));
    u16* wob = (u16*)(ws + alloc(nQ * 2));
    u16* w1b = (u16*)(ws + alloc(nF * 2));
    u16* w2b = (u16*)(ws + alloc(nF * 2));
    u16* w3b = (u16*)(ws + alloc(nF * 2));
    u16* woub = (u16*)(ws + alloc(nO * 2));

    auto cvt = [&](const float* s, u16* d, size_t n) {
        const int n8 = (int)(n / 8);
        const int blocks = (n8 + 255) / 256 < 2048 ? (n8 + 255) / 256 : 2048;
        cvt_kernel<<<blocks, 256, 0, stream>>>(s, d, n8);
    };
    cvt(wq, wqb, nQ); cvt(wk, wkb, nQ); cvt(wvw, wvb, nQ); cvt(wo, wob, nQ);
    cvt(w1, w1b, nF); cvt(w2, w2b, nF); cvt(w3, w3b, nF);
    cvt(w_out, woub, nO);

    embed_kernel<<<SEQ, 256, 0, stream>>>(tokens, tok_emb, h);
    ropetab_kernel<<<(SEQ * 32) / 256, 256, 0, stream>>>(cosb, sinb);
    span_kernel<<<1, SEQ, 0, stream>>>(tokens, span);

    for (int l = 0; l < NLAY; ++l) {
        rmsnorm_kernel<<<SEQ, 256, 0, stream>>>(h, attn_nw + (size_t)l * DM, xn);
        qkv_kernel<<<dim3(8, 24), 256, 0, stream>>>(
            xn, wqb + (size_t)l * DM * DM, wkb + (size_t)l * DM * DM, wvb + (size_t)l * DM * DM,
            cosb, sinb, qb, kb, vb);
        fattn_kernel<<<dim3(SEQ / 64, NHEADS), 256, 0, stream>>>(qb, kb, vb, span, ab);
        gemm_p_kernel<1, 64, 64><<<dim3(16, 16), 256, 0, stream>>>(
            ab, wob + (size_t)l * DM * DM, h, h, DM, DM);

        rmsnorm_kernel<<<SEQ, 256, 0, stream>>>(h, ffn_nw + (size_t)l * DM, xn);
        ffn13_kernel<<<dim3(16, 22), 256, 0, stream>>>(
            xn, w1b + (size_t)l * FFD * DM, w3b + (size_t)l * FFD * DM, zb);
        gemm_p_kernel<1, 64, 64><<<dim3(16, 16), 256, 0, stream>>>(
            zb, w2b + (size_t)l * DM * FFD, h, h, DM, FFD);
    }

    rmsnorm_kernel<<<SEQ, 256, 0, stream>>>(h, final_nw, xn);
    gemm_big_kernel<0><<<dim3(SEQ / 256, VOC / 256), 512, 0, stream>>>(
        xn, woub, logits, nullptr, VOC, DM);
}

// Round 8
// 384.751 us; speedup vs baseline: 10.2162x; 1.1077x over previous
//
#include <hip/hip_runtime.h>
#include <hip/hip_bf16.h>
#include <stdint.h>

typedef unsigned short u16;
typedef __bf16 bf16x8 __attribute__((ext_vector_type(8)));
typedef u16 u16x8 __attribute__((ext_vector_type(8)));
typedef float f32x4 __attribute__((ext_vector_type(4)));

#define SEQ   1024
#define DM    1024
#define NHEADS 16
#define HDIM  64
#define VOC   32000
#define FFD   2816
#define NLAY  2

__device__ __forceinline__ u16 f2b(float f) {
    unsigned x = __builtin_bit_cast(unsigned, f);
    unsigned r = x + 0x7fffu + ((x >> 16) & 1u);
    return (u16)(r >> 16);
}
__device__ __forceinline__ float b2f(u16 u) {
    unsigned x = ((unsigned)u) << 16;
    return __builtin_bit_cast(float, x);
}
__device__ __forceinline__ float grpmax16(float v) {
    v = fmaxf(v, __shfl_xor(v, 1)); v = fmaxf(v, __shfl_xor(v, 2));
    v = fmaxf(v, __shfl_xor(v, 4)); v = fmaxf(v, __shfl_xor(v, 8));
    return v;
}
__device__ __forceinline__ float grpsum16(float v) {
    v += __shfl_xor(v, 1); v += __shfl_xor(v, 2);
    v += __shfl_xor(v, 4); v += __shfl_xor(v, 8);
    return v;
}

// async global->LDS, 16 bytes per lane. LDS dest must be wave-uniform base + lane*16.
__device__ __forceinline__ void gll16(const void* g, void* l) {
    __builtin_amdgcn_global_load_lds(
        (__attribute__((address_space(1))) void*)(uintptr_t)g,
        (__attribute__((address_space(3))) void*)(uint32_t)(uintptr_t)l,
        16, 0, 0);
}
template <int N> __device__ __forceinline__ void vwait() {
    if constexpr (N == 0)       asm volatile("s_waitcnt vmcnt(0)" ::: "memory");
    else if constexpr (N == 4)  asm volatile("s_waitcnt vmcnt(4)" ::: "memory");
    else if constexpr (N == 8)  asm volatile("s_waitcnt vmcnt(8)" ::: "memory");
    else if constexpr (N == 10) asm volatile("s_waitcnt vmcnt(10)" ::: "memory");
    else if constexpr (N == 16) asm volatile("s_waitcnt vmcnt(16)" ::: "memory");
}
// bijective XCD swizzle for any nwg (m204): per-XCD contiguous logical chunks.
__device__ __forceinline__ int xcd_swz(int bid, int nwg) {
    const int q = nwg >> 3, r = nwg & 7;
    const int xcd = bid & 7, j = bid >> 3;
    const int start = (xcd < r) ? xcd * (q + 1) : r * (q + 1) + (xcd - r) * q;
    return start + j;
}

// ---------------- fp32 -> bf16 weight conversion, all weights in ONE launch ----------------
struct CvtArgs { const float* s[8]; u16* d[8]; int n8[8]; };
__global__ __launch_bounds__(256) void cvt_all_kernel(CvtArgs a) {
    const int stride = gridDim.x * 256;
    for (int g = 0; g < 8; ++g) {
        const float* __restrict__ s = a.s[g];
        u16* __restrict__ d = a.d[g];
        const int n8 = a.n8[g];
        for (int i = blockIdx.x * 256 + threadIdx.x; i < n8; i += stride) {
            const float4 x = ((const float4*)s)[2 * i];
            const float4 y = ((const float4*)s)[2 * i + 1];
            ushort4 p, q;
            p.x = f2b(x.x); p.y = f2b(x.y); p.z = f2b(x.z); p.w = f2b(x.w);
            q.x = f2b(y.x); q.y = f2b(y.y); q.z = f2b(y.z); q.w = f2b(y.w);
            ((ushort4*)d)[2 * i] = p;
            ((ushort4*)d)[2 * i + 1] = q;
        }
    }
}

// ---------------- embedding gather ----------------
__global__ __launch_bounds__(256) void embed_kernel(const int* __restrict__ tok,
    const float* __restrict__ emb, float* __restrict__ h) {
    const int l = blockIdx.x;
    const int t = tok[l];
    ((float4*)(h + (size_t)l * DM))[threadIdx.x] =
        ((const float4*)(emb + (size_t)t * DM))[threadIdx.x];
}

// ---------------- rope tables ----------------
__global__ __launch_bounds__(256) void ropetab_kernel(float* __restrict__ cosb,
                                                      float* __restrict__ sinb) {
    const int idx = blockIdx.x * 256 + threadIdx.x;   // < SEQ*32
    const int l = idx >> 5, j = idx & 31;
    const float inv = __expf(-((float)j * (1.0f / 32.0f)) * 13.122363377404328f); // ln(500000)
    const float ang = (float)l * inv;
    cosb[idx] = cosf(ang);
    sinb[idx] = sinf(ang);
}

// ---------------- transfusion span ids + per-64-token-tile span bitmask ----------------
__global__ void span_kernel(const int* __restrict__ tok, int* __restrict__ span,
                            int* __restrict__ tmask) {
    __shared__ int sb[SEQ], se[SEQ];
    __shared__ int tm[SEQ / 64];
    const int t = threadIdx.x;
    const int v = tok[t];
    const int bo = (v == 31998) ? 1 : 0;
    const int eo = (v == 31999) ? 1 : 0;
    sb[t] = bo; se[t] = eo;
    if (t < SEQ / 64) tm[t] = 0;
    __syncthreads();
    for (int o = 1; o < SEQ; o <<= 1) {
        int a = 0, b = 0;
        if (t >= o) { a = sb[t - o]; b = se[t - o]; }
        __syncthreads();
        sb[t] += a; se[t] += b;
        __syncthreads();
    }
    const int bc = sb[t];
    const int ec = se[t] - eo;           // exclusive eoi cumsum
    const int id = (bc > ec) ? bc : 0;
    span[t] = id;
    if (id > 0) atomicOr(&tm[t >> 6], 1 << ((id - 1) & 31));
    __syncthreads();
    if (t < SEQ / 64) tmask[t] = tm[t];
}

// ---------------- rmsnorm (fp32 in -> bf16 out) ----------------
__global__ __launch_bounds__(256) void rmsnorm_kernel(const float* __restrict__ x,
    const float* __restrict__ w, u16* __restrict__ o) {
    const int row = blockIdx.x;
    const float4 xv = ((const float4*)(x + (size_t)row * DM))[threadIdx.x];
    float ss = xv.x * xv.x + xv.y * xv.y + xv.z * xv.z + xv.w * xv.w;
    for (int off = 32; off; off >>= 1) ss += __shfl_xor(ss, off);
    __shared__ float red[4];
    const int lane = threadIdx.x & 63, wvi = threadIdx.x >> 6;
    if (lane == 0) red[wvi] = ss;
    __syncthreads();
    const float tot = red[0] + red[1] + red[2] + red[3];
    const float sc = rsqrtf(tot * (1.0f / (float)DM) + 1e-5f);
    const float4 wv4 = ((const float4*)w)[threadIdx.x];
    ushort4 ov;
    ov.x = f2b(xv.x * sc * wv4.x);
    ov.y = f2b(xv.y * sc * wv4.y);
    ov.z = f2b(xv.z * sc * wv4.z);
    ov.w = f2b(xv.w * sc * wv4.w);
    ((ushort4*)(o + (size_t)row * DM))[threadIdx.x] = ov;
}

// ======================= pipelined GEMM (BK=64, counted vmcnt) =======================
// LDS rows 128B; granule swizzle gr' = gr ^ (row&7) conflict-free; swizzle baked into
// per-thread staging pointers. Per K-tile: stage t+1 -> p^1 ; vwait<LOADS> ; s_barrier ;
// ds_read p + MFMA ; s_barrier. No vmcnt(0) drain in the main loop.

// ---------------- generic pipelined GEMM, fp32 out (+optional residual) ----------------
template <int RESID, int BM, int BN>
__global__ __launch_bounds__(256) void gemm_p_kernel(const u16* __restrict__ A,
    const u16* __restrict__ B, float* __restrict__ C, const float* __restrict__ res,
    int N, int K) {
    constexpr int AL = BM / 32, BL = BN / 32, LOADS = AL + BL;
    constexpr int MF = BM / 32, NF = BN / 32;
    __shared__ __align__(16) u16 sA[2][BM * 64];
    __shared__ __align__(16) u16 sB[2][BN * 64];
    const int nwg = gridDim.x * gridDim.y;
    const int lid = xcd_swz(blockIdx.y * gridDim.x + blockIdx.x, nwg);
    const int tm = (lid % gridDim.x) * BM, tn = (lid / gridDim.x) * BN;
    const int tid = threadIdx.x, lane = tid & 63, wid = tid >> 6;
    const int wm = wid >> 1, wn = wid & 1, fr = lane & 15, g = lane >> 4;

    const u16* ap[AL]; const u16* bp[BL];
#pragma unroll
    for (int j = 0; j < AL; ++j) {
        const int idx = j * 256 + tid, r = idx >> 3, gr = (idx & 7) ^ (r & 7);
        ap[j] = A + (size_t)(tm + r) * K + gr * 8;
    }
#pragma unroll
    for (int j = 0; j < BL; ++j) {
        const int idx = j * 256 + tid, r = idx >> 3, gr = (idx & 7) ^ (r & 7);
        bp[j] = B + (size_t)(tn + r) * K + gr * 8;
    }

    f32x4 acc[MF][NF] = {};
    const int NT = K >> 6;
#pragma unroll
    for (int j = 0; j < AL; ++j) gll16(ap[j], &sA[0][(j * 256 + tid) * 8]);
#pragma unroll
    for (int j = 0; j < BL; ++j) gll16(bp[j], &sB[0][(j * 256 + tid) * 8]);

    int p = 0;
    for (int t = 0; t < NT; ++t) {
        if (t + 1 < NT) {
#pragma unroll
            for (int j = 0; j < AL; ++j) gll16(ap[j] + (t + 1) * 64, &sA[p ^ 1][(j * 256 + tid) * 8]);
#pragma unroll
            for (int j = 0; j < BL; ++j) gll16(bp[j] + (t + 1) * 64, &sB[p ^ 1][(j * 256 + tid) * 8]);
            vwait<LOADS>();
        } else {
            vwait<0>();
        }
        __builtin_amdgcn_s_barrier();          // all waves' tile-t data resident
        __builtin_amdgcn_sched_barrier(0);
        bf16x8 af[MF][2], bfv[NF][2];
#pragma unroll
        for (int m = 0; m < MF; ++m)
#pragma unroll
            for (int ks = 0; ks < 2; ++ks) {
                const int row = wm * (BM / 2) + m * 16 + fr;
                const int gr = (ks * 4 + g) ^ (row & 7);
                af[m][ks] = *(const bf16x8*)&sA[p][row * 64 + gr * 8];
            }
#pragma unroll
        for (int n = 0; n < NF; ++n)
#pragma unroll
            for (int ks = 0; ks < 2; ++ks) {
                const int row = wn * (BN / 2) + n * 16 + fr;
                const int gr = (ks * 4 + g) ^ (row & 7);
                bfv[n][ks] = *(const bf16x8*)&sB[p][row * 64 + gr * 8];
            }
        __builtin_amdgcn_s_setprio(1);
#pragma unroll
        for (int m = 0; m < MF; ++m)
#pragma unroll
            for (int n = 0; n < NF; ++n)
#pragma unroll
                for (int ks = 0; ks < 2; ++ks)
                    acc[m][n] = __builtin_amdgcn_mfma_f32_16x16x32_bf16(af[m][ks], bfv[n][ks], acc[m][n], 0, 0, 0);
        __builtin_amdgcn_s_setprio(0);
        __builtin_amdgcn_s_barrier();          // reads of buf p closed before next writes
        p ^= 1;
    }

    const int cr = (lane >> 4) * 4, cc = lane & 15;
#pragma unroll
    for (int m = 0; m < MF; ++m)
#pragma unroll
        for (int n = 0; n < NF; ++n) {
            const int row0 = tm + wm * (BM / 2) + m * 16 + cr;
            const int col = tn + wn * (BN / 2) + n * 16 + cc;
#pragma unroll
            for (int r = 0; r < 4; ++r) {
                const size_t idx = (size_t)(row0 + r) * N + col;
                float v = acc[m][n][r];
                if (RESID) v += res[idx];
                C[idx] = v;
            }
        }
}

// ======================= 256x256 / BK=64 / 8-wave phase-interleaved GEMM =======================
// m201-style: per K-tile 4 quadrant phases {ds_read frags ; setprio MFMA ; s_barrier}.
// Phase barriers create wave role-split (read vs MFMA) so LDS and matrix pipe overlap.
template <int RESID>
__global__ __launch_bounds__(512, 2) void gemm_big_kernel(const u16* __restrict__ A,
    const u16* __restrict__ B, float* __restrict__ C, const float* __restrict__ res,
    int N, int K) {
    __shared__ __align__(16) u16 sA[2][256 * 64];
    __shared__ __align__(16) u16 sB[2][256 * 64];
    const int nwg = gridDim.x * gridDim.y;
    const int lid = xcd_swz(blockIdx.y * gridDim.x + blockIdx.x, nwg);
    const int tm = (lid % gridDim.x) * 256;
    const int tn = (lid / gridDim.x) * 256;
    const int tid = threadIdx.x, lane = tid & 63, wid = tid >> 6;
    const int wm = wid >> 2, wn = wid & 3;       // 2 x 4 waves, per-wave 128x64
    const int fr = lane & 15, g = lane >> 4;

    const u16* ap[4]; const u16* bp[4];
#pragma unroll
    for (int j = 0; j < 4; ++j) {
        const int idx = j * 512 + tid, r = idx >> 3, gr = (idx & 7) ^ (r & 7);
        ap[j] = A + (size_t)(tm + r) * K + gr * 8;
        bp[j] = B + (size_t)(tn + r) * K + gr * 8;
    }

    f32x4 acc[8][4] = {};
    const int NT = K >> 6;
#pragma unroll
    for (int j = 0; j < 4; ++j) gll16(ap[j], &sA[0][(j * 512 + tid) * 8]);
#pragma unroll
    for (int j = 0; j < 4; ++j) gll16(bp[j], &sB[0][(j * 512 + tid) * 8]);

    int p = 0;
    for (int t = 0; t < NT; ++t) {
        if (t + 1 < NT) {
#pragma unroll
            for (int j = 0; j < 4; ++j) gll16(ap[j] + (t + 1) * 64, &sA[p ^ 1][(j * 512 + tid) * 8]);
#pragma unroll
            for (int j = 0; j < 4; ++j) gll16(bp[j] + (t + 1) * 64, &sB[p ^ 1][(j * 512 + tid) * 8]);
            vwait<8>();
        } else {
            vwait<0>();
        }
        __builtin_amdgcn_s_barrier();            // tile-t resident for all waves
        __builtin_amdgcn_sched_barrier(0);
        bf16x8 bfv[4][2];
#pragma unroll
        for (int mq = 0; mq < 4; ++mq) {         // 4 phases per K-tile
            if (mq == 0) {
#pragma unroll
                for (int n = 0; n < 4; ++n)
#pragma unroll
                    for (int ks = 0; ks < 2; ++ks) {
                        const int row = wn * 64 + n * 16 + fr;
                        const int gr = (ks * 4 + g) ^ (row & 7);
                        bfv[n][ks] = *(const bf16x8*)&sB[p][row * 64 + gr * 8];
                    }
            }
            bf16x8 af[2][2];
#pragma unroll
            for (int i = 0; i < 2; ++i)
#pragma unroll
                for (int ks = 0; ks < 2; ++ks) {
                    const int row = wm * 128 + (mq * 2 + i) * 16 + fr;
                    const int gr = (ks * 4 + g) ^ (row & 7);
                    af[i][ks] = *(const bf16x8*)&sA[p][row * 64 + gr * 8];
                }
            __builtin_amdgcn_s_setprio(1);
#pragma unroll
            for (int i = 0; i < 2; ++i)
#pragma unroll
                for (int n = 0; n < 4; ++n)
#pragma unroll
                    for (int ks = 0; ks < 2; ++ks)
                        acc[mq * 2 + i][n] = __builtin_amdgcn_mfma_f32_16x16x32_bf16(
                            af[i][ks], bfv[n][ks], acc[mq * 2 + i][n], 0, 0, 0);
            __builtin_amdgcn_s_setprio(0);
            __builtin_amdgcn_s_barrier();        // phase boundary (last one closes WAR)
        }
        p ^= 1;
    }

    const int cr = (lane >> 4) * 4, cc = lane & 15;
#pragma unroll
    for (int m = 0; m < 8; ++m)
#pragma unroll
        for (int n = 0; n < 4; ++n) {
            const int row0 = tm + wm * 128 + m * 16 + cr;
            const int col = tn + wn * 64 + n * 16 + cc;
#pragma unroll
            for (int r = 0; r < 4; ++r) {
                const size_t idx = (size_t)(row0 + r) * N + col;
                float v = acc[m][n][r];
                if (RESID) v += res[idx];
                C[idx] = v;
            }
        }
}

// ---------------- fused QKV GEMM (128x128) + RoPE + bf16 cast ----------------
__global__ __launch_bounds__(256) void qkv_kernel(const u16* __restrict__ A,
    const u16* __restrict__ Bq, const u16* __restrict__ Bk, const u16* __restrict__ Bv,
    const float* __restrict__ cosb, const float* __restrict__ sinb,
    u16* __restrict__ qb, u16* __restrict__ kb, u16* __restrict__ vb) {
    __shared__ __align__(16) u16 sA[2][128 * 64];
    __shared__ __align__(16) u16 sB[2][128 * 64];
    const int lid = xcd_swz(blockIdx.y * gridDim.x + blockIdx.x, 8 * 24);
    const int tm = (lid % 8) * 128;
    const int yy = lid / 8;
    const int mat = yy >> 3;
    const int tn = (yy & 7) * 128;
    const u16* B = (mat == 0) ? Bq : (mat == 1) ? Bk : Bv;
    u16* out = (mat == 0) ? qb : (mat == 1) ? kb : vb;
    const int tid = threadIdx.x, lane = tid & 63, wid = tid >> 6;
    const int wm = wid >> 1, wn = wid & 1, fr = lane & 15, g = lane >> 4;

    const u16* ap[4]; const u16* bp[4];
#pragma unroll
    for (int j = 0; j < 4; ++j) {
        const int idx = j * 256 + tid, r = idx >> 3, gr = (idx & 7) ^ (r & 7);
        ap[j] = A + (size_t)(tm + r) * DM + gr * 8;
        bp[j] = B + (size_t)(tn + r) * DM + gr * 8;
    }

    f32x4 acc[4][4] = {};
#pragma unroll
    for (int j = 0; j < 4; ++j) gll16(ap[j], &sA[0][(j * 256 + tid) * 8]);
#pragma unroll
    for (int j = 0; j < 4; ++j) gll16(bp[j], &sB[0][(j * 256 + tid) * 8]);

    int p = 0;
    for (int t = 0; t < DM / 64; ++t) {
        if (t + 1 < DM / 64) {
#pragma unroll
            for (int j = 0; j < 4; ++j) gll16(ap[j] + (t + 1) * 64, &sA[p ^ 1][(j * 256 + tid) * 8]);
#pragma unroll
            for (int j = 0; j < 4; ++j) gll16(bp[j] + (t + 1) * 64, &sB[p ^ 1][(j * 256 + tid) * 8]);
            vwait<8>();
        } else {
            vwait<0>();
        }
        __builtin_amdgcn_s_barrier();
        __builtin_amdgcn_sched_barrier(0);
        bf16x8 af[4][2], bfv[4][2];
#pragma unroll
        for (int m = 0; m < 4; ++m)
#pragma unroll
            for (int ks = 0; ks < 2; ++ks) {
                const int row = wm * 64 + m * 16 + fr;
                const int gr = (ks * 4 + g) ^ (row & 7);
                af[m][ks] = *(const bf16x8*)&sA[p][row * 64 + gr * 8];
            }
#pragma unroll
        for (int n = 0; n < 4; ++n)
#pragma unroll
            for (int ks = 0; ks < 2; ++ks) {
                const int row = wn * 64 + n * 16 + fr;
                const int gr = (ks * 4 + g) ^ (row & 7);
                bfv[n][ks] = *(const bf16x8*)&sB[p][row * 64 + gr * 8];
            }
        __builtin_amdgcn_s_setprio(1);
#pragma unroll
        for (int m = 0; m < 4; ++m)
#pragma unroll
            for (int n = 0; n < 4; ++n)
#pragma unroll
                for (int ks = 0; ks < 2; ++ks)
                    acc[m][n] = __builtin_amdgcn_mfma_f32_16x16x32_bf16(af[m][ks], bfv[n][ks], acc[m][n], 0, 0, 0);
        __builtin_amdgcn_s_setprio(0);
        __builtin_amdgcn_s_barrier();
        p ^= 1;
    }

    const int cr = (lane >> 4) * 4, cc = lane & 15;
    if (mat < 2) {
#pragma unroll
        for (int m = 0; m < 4; ++m)
#pragma unroll
            for (int n = 0; n < 4; ++n) {
                const int row0 = tm + wm * 64 + m * 16 + cr;
                const int col = tn + wn * 64 + n * 16 + cc;
                const int j = (n * 16 + cc) >> 1;    // rope pair index within head
#pragma unroll
                for (int r = 0; r < 4; ++r) {
                    const int row = row0 + r;
                    const float c = cosb[row * 32 + j];
                    const float s = sinb[row * 32 + j];
                    const float v = acc[m][n][r];
                    const float pv = __shfl_xor(v, 1);
                    const float o = (cc & 1) ? (pv * s + v * c) : (v * c - pv * s);
                    out[(size_t)row * DM + col] = f2b(o);
                }
            }
    } else {
#pragma unroll
        for (int m = 0; m < 4; ++m)
#pragma unroll
            for (int n = 0; n < 4; ++n) {
                const int row0 = tm + wm * 64 + m * 16 + cr;
                const int col = tn + wn * 64 + n * 16 + cc;
#pragma unroll
                for (int r = 0; r < 4; ++r)
                    out[(size_t)(row0 + r) * DM + col] = f2b(acc[m][n][r]);
            }
    }
}

// ---------------- fused w1/w3 GEMM (64x128 dual-B) + SiLU*mul -> bf16 ----------------
__global__ __launch_bounds__(256) void ffn13_kernel(const u16* __restrict__ A,
    const u16* __restrict__ B1, const u16* __restrict__ B3, u16* __restrict__ Z) {
    __shared__ __align__(16) u16 sA[2][64 * 64];
    __shared__ __align__(16) u16 sB1[2][128 * 64];
    __shared__ __align__(16) u16 sB3[2][128 * 64];
    const int lid = xcd_swz(blockIdx.y * gridDim.x + blockIdx.x, 16 * 22);
    const int tm = (lid % 16) * 64;
    const int tn = (lid / 16) * 128;
    const int tid = threadIdx.x, lane = tid & 63, wid = tid >> 6;
    const int wm = wid >> 1, wn = wid & 1, fr = lane & 15, g = lane >> 4;

    const u16* ap[2]; const u16* b1p[4]; const u16* b3p[4];
#pragma unroll
    for (int j = 0; j < 2; ++j) {
        const int idx = j * 256 + tid, r = idx >> 3, gr = (idx & 7) ^ (r & 7);
        ap[j] = A + (size_t)(tm + r) * DM + gr * 8;
    }
#pragma unroll
    for (int j = 0; j < 4; ++j) {
        const int idx = j * 256 + tid, r = idx >> 3, gr = (idx & 7) ^ (r & 7);
        b1p[j] = B1 + (size_t)(tn + r) * DM + gr * 8;
        b3p[j] = B3 + (size_t)(tn + r) * DM + gr * 8;
    }

    f32x4 acc1[2][4] = {}, acc3[2][4] = {};
#pragma unroll
    for (int j = 0; j < 2; ++j) gll16(ap[j], &sA[0][(j * 256 + tid) * 8]);
#pragma unroll
    for (int j = 0; j < 4; ++j) gll16(b1p[j], &sB1[0][(j * 256 + tid) * 8]);
#pragma unroll
    for (int j = 0; j < 4; ++j) gll16(b3p[j], &sB3[0][(j * 256 + tid) * 8]);

    int p = 0;
    for (int t = 0; t < DM / 64; ++t) {
        if (t + 1 < DM / 64) {
#pragma unroll
            for (int j = 0; j < 2; ++j) gll16(ap[j] + (t + 1) * 64, &sA[p ^ 1][(j * 256 + tid) * 8]);
#pragma unroll
            for (int j = 0; j < 4; ++j) gll16(b1p[j] + (t + 1) * 64, &sB1[p ^ 1][(j * 256 + tid) * 8]);
#pragma unroll
            for (int j = 0; j < 4; ++j) gll16(b3p[j] + (t + 1) * 64, &sB3[p ^ 1][(j * 256 + tid) * 8]);
            vwait<10>();
        } else {
            vwait<0>();
        }
        __builtin_amdgcn_s_barrier();
        __builtin_amdgcn_sched_barrier(0);
        bf16x8 af[2][2], b1v[4][2], b3v[4][2];
#pragma unroll
        for (int m = 0; m < 2; ++m)
#pragma unroll
            for (int ks = 0; ks < 2; ++ks) {
                const int row = wm * 32 + m * 16 + fr;
                const int gr = (ks * 4 + g) ^ (row & 7);
                af[m][ks] = *(const bf16x8*)&sA[p][row * 64 + gr * 8];
            }
#pragma unroll
        for (int n = 0; n < 4; ++n)
#pragma unroll
            for (int ks = 0; ks < 2; ++ks) {
                const int row = wn * 64 + n * 16 + fr;
                const int gr = (ks * 4 + g) ^ (row & 7);
                b1v[n][ks] = *(const bf16x8*)&sB1[p][row * 64 + gr * 8];
                b3v[n][ks] = *(const bf16x8*)&sB3[p][row * 64 + gr * 8];
            }
        __builtin_amdgcn_s_setprio(1);
#pragma unroll
        for (int m = 0; m < 2; ++m)
#pragma unroll
            for (int n = 0; n < 4; ++n)
#pragma unroll
                for (int ks = 0; ks < 2; ++ks) {
                    acc1[m][n] = __builtin_amdgcn_mfma_f32_16x16x32_bf16(af[m][ks], b1v[n][ks], acc1[m][n], 0, 0, 0);
                    acc3[m][n] = __builtin_amdgcn_mfma_f32_16x16x32_bf16(af[m][ks], b3v[n][ks], acc3[m][n], 0, 0, 0);
                }
        __builtin_amdgcn_s_setprio(0);
        __builtin_amdgcn_s_barrier();
        p ^= 1;
    }

    const int cr = (lane >> 4) * 4, cc = lane & 15;
#pragma unroll
    for (int m = 0; m < 2; ++m)
#pragma unroll
        for (int n = 0; n < 4; ++n) {
            const int row0 = tm + wm * 32 + m * 16 + cr;
            const int col = tn + wn * 64 + n * 16 + cc;
#pragma unroll
            for (int r = 0; r < 4; ++r) {
                const float a1 = acc1[m][n][r];
                const float a3 = acc3[m][n][r];
                const float z = a1 / (1.f + __expf(-a1)) * a3;
                Z[(size_t)(row0 + r) * FFD + col] = f2b(z);
            }
        }
}

// ---------------- flash attention: block = (64 q-rows, 1 head), 4 waves ----------------
// KV-tile skip: tiles beyond the causal frontier processed only if span bitmasks overlap.
__global__ __launch_bounds__(256) void fattn_kernel(const u16* __restrict__ qb,
    const u16* __restrict__ kb, const u16* __restrict__ vb,
    const int* __restrict__ span, const int* __restrict__ tmask, u16* __restrict__ ob) {
    __shared__ __align__(16) u16 sK[64][72];   // K rows, padded
    __shared__ __align__(16) u16 sVT[64][72];  // V transposed: [d][key]
    __shared__ __align__(16) u16 sP[4][16][72];// per-wave P tile
    const int tid = threadIdx.x, lane = tid & 63, wq = tid >> 6;
    const int g = lane >> 4, fr = lane & 15;
    const int head = blockIdx.y;
    const int qbase = blockIdx.x * 64;
    const int qmask = tmask[blockIdx.x];

    bf16x8 qfr[2];
    {
        const u16* qp = qb + (size_t)(qbase + wq * 16 + fr) * DM + head * HDIM + g * 8;
        qfr[0] = *(const bf16x8*)(qp);
        qfr[1] = *(const bf16x8*)(qp + 32);
    }
    int sq[4];
#pragma unroll
    for (int r = 0; r < 4; ++r) sq[r] = span[qbase + wq * 16 + g * 4 + r];

    float m_old[4] = {-1e30f, -1e30f, -1e30f, -1e30f};
    float lsum[4] = {0.f, 0.f, 0.f, 0.f};
    f32x4 acc[4] = {};

    for (int kt = 0; kt < SEQ / 64; ++kt) {
        const int kb0 = kt * 64;
        if (kb0 > qbase && (qmask & tmask[kt]) == 0) continue;   // block-uniform skip
        __syncthreads();
        {
            const int r = tid >> 2, c0 = (tid & 3) * 16;
            const u16* src = kb + (size_t)(kb0 + r) * DM + head * HDIM + c0;
            *(u16x8*)&sK[r][c0]     = *(const u16x8*)(src);
            *(u16x8*)&sK[r][c0 + 8] = *(const u16x8*)(src + 8);
        }
        {
            const int k = tid & 63, d0 = (tid >> 6) * 16;
            const u16* src = vb + (size_t)(kb0 + k) * DM + head * HDIM + d0;
            const u16x8 v0 = *(const u16x8*)(src);
            const u16x8 v1 = *(const u16x8*)(src + 8);
#pragma unroll
            for (int j = 0; j < 8; ++j) {
                sVT[d0 + j][k]     = v0[j];
                sVT[d0 + 8 + j][k] = v1[j];
            }
        }
        __syncthreads();

        f32x4 accs[4] = {};
        __builtin_amdgcn_s_setprio(1);
#pragma unroll
        for (int nf = 0; nf < 4; ++nf)
#pragma unroll
            for (int kf = 0; kf < 2; ++kf) {
                const bf16x8 kfv = *(const bf16x8*)&sK[nf * 16 + fr][g * 8 + kf * 32];
                accs[nf] = __builtin_amdgcn_mfma_f32_16x16x32_bf16(qfr[kf], kfv, accs[nf], 0, 0, 0);
            }
        __builtin_amdgcn_s_setprio(0);

        float sv[4][4]; bool al[4][4];
        if (kb0 + 63 <= qbase) {             // fully-causal tile: all allowed
#pragma unroll
            for (int nf = 0; nf < 4; ++nf)
#pragma unroll
                for (int r = 0; r < 4; ++r) {
                    al[nf][r] = true;
                    sv[nf][r] = accs[nf][r] * 0.125f;
                }
        } else {
            int spk[4];
#pragma unroll
            for (int nf = 0; nf < 4; ++nf) spk[nf] = span[kb0 + nf * 16 + fr];
#pragma unroll
            for (int nf = 0; nf < 4; ++nf) {
                const int key = kb0 + nf * 16 + fr;
#pragma unroll
                for (int r = 0; r < 4; ++r) {
                    const int q = qbase + wq * 16 + g * 4 + r;
                    al[nf][r] = (key <= q) || (sq[r] > 0 && spk[nf] == sq[r]);
                    sv[nf][r] = al[nf][r] ? accs[nf][r] * 0.125f : -1e30f;
                }
            }
        }
        float alpha[4], ls[4];
#pragma unroll
        for (int r = 0; r < 4; ++r) {
            float mn = fmaxf(fmaxf(sv[0][r], sv[1][r]), fmaxf(sv[2][r], sv[3][r]));
            mn = grpmax16(mn);
            const float mnew = fmaxf(m_old[r], mn);
            alpha[r] = __expf(m_old[r] - mnew);
            m_old[r] = mnew;
            ls[r] = 0.f;
        }
        u16 pb[4][4];
#pragma unroll
        for (int nf = 0; nf < 4; ++nf)
#pragma unroll
            for (int r = 0; r < 4; ++r) {
                const float p = al[nf][r] ? __expf(sv[nf][r] - m_old[r]) : 0.f;
                ls[r] += p;
                pb[nf][r] = f2b(p);
            }
#pragma unroll
        for (int r = 0; r < 4; ++r) {
            lsum[r] = lsum[r] * alpha[r] + grpsum16(ls[r]);
#pragma unroll
            for (int nf = 0; nf < 4; ++nf) acc[nf][r] *= alpha[r];
        }
#pragma unroll
        for (int nf = 0; nf < 4; ++nf)
#pragma unroll
            for (int r = 0; r < 4; ++r)
                sP[wq][g * 4 + r][nf * 16 + fr] = pb[nf][r];

        __builtin_amdgcn_s_setprio(1);
#pragma unroll
        for (int nf = 0; nf < 4; ++nf)
#pragma unroll
            for (int kf = 0; kf < 2; ++kf) {
                const bf16x8 pa  = *(const bf16x8*)&sP[wq][fr][g * 8 + kf * 32];
                const bf16x8 vtb = *(const bf16x8*)&sVT[nf * 16 + fr][g * 8 + kf * 32];
                acc[nf] = __builtin_amdgcn_mfma_f32_16x16x32_bf16(pa, vtb, acc[nf], 0, 0, 0);
            }
        __builtin_amdgcn_s_setprio(0);
    }

#pragma unroll
    for (int nf = 0; nf < 4; ++nf)
#pragma unroll
        for (int r = 0; r < 4; ++r) {
            const int q = qbase + wq * 16 + g * 4 + r;
            const int d = nf * 16 + fr;
            ob[(size_t)q * DM + head * HDIM + d] = f2b(acc[nf][r] / lsum[r]);
        }
}

extern "C" void kernel_launch(void* const* d_in, const int* in_sizes, int n_in,
                              void* d_out, int out_size, void* d_ws, size_t ws_size,
                              hipStream_t stream) {
    (void)in_sizes; (void)n_in; (void)out_size; (void)ws_size;
    const int*   tokens   = (const int*)d_in[0];
    const float* tok_emb  = (const float*)d_in[1];
    const float* wq       = (const float*)d_in[2];
    const float* wk       = (const float*)d_in[3];
    const float* wvw      = (const float*)d_in[4];
    const float* wo       = (const float*)d_in[5];
    const float* w1       = (const float*)d_in[6];
    const float* w2       = (const float*)d_in[7];
    const float* w3       = (const float*)d_in[8];
    const float* attn_nw  = (const float*)d_in[9];
    const float* ffn_nw   = (const float*)d_in[10];
    const float* final_nw = (const float*)d_in[11];
    const float* w_out    = (const float*)d_in[12];
    float* logits = (float*)d_out;

    char* ws = (char*)d_ws;
    size_t off = 0;
    auto alloc = [&](size_t b) { size_t o = off; off += (b + 255) & ~(size_t)255; return o; };
    float* h    = (float*)(ws + alloc((size_t)SEQ * DM * 4));
    u16*   xn   = (u16*)  (ws + alloc((size_t)SEQ * DM * 2));
    u16*   qb   = (u16*)  (ws + alloc((size_t)SEQ * DM * 2));
    u16*   kb   = (u16*)  (ws + alloc((size_t)SEQ * DM * 2));
    u16*   vb   = (u16*)  (ws + alloc((size_t)SEQ * DM * 2));
    u16*   ab   = (u16*)  (ws + alloc((size_t)SEQ * DM * 2));
    u16*   zb   = (u16*)  (ws + alloc((size_t)SEQ * FFD * 2));
    float* cosb = (float*)(ws + alloc((size_t)SEQ * 32 * 4));
    float* sinb = (float*)(ws + alloc((size_t)SEQ * 32 * 4));
    int*   span = (int*)  (ws + alloc((size_t)SEQ * 4));
    int*   tmask= (int*)  (ws + alloc((size_t)(SEQ / 64) * 4));
    // bf16 weight copies
    const size_t nQ = (size_t)NLAY * DM * DM;     // wq/wk/wv/wo each
    const size_t nF = (size_t)NLAY * FFD * DM;    // w1/w2/w3 each
    const size_t nO = (size_t)VOC * DM;           // w_out
    u16* wqb = (u16*)(ws + alloc(nQ * 2));
    u16* wkb = (u16*)(ws + alloc(nQ * 2));
    u16* wvb = (u16*)(ws + alloc(nQ * 2));
    u16* wob = (u16*)(ws + alloc(nQ * 2));
    u16* w1b = (u16*)(ws + alloc(nF * 2));
    u16* w2b = (u16*)(ws + alloc(nF * 2));
    u16* w3b = (u16*)(ws + alloc(nF * 2));
    u16* woub = (u16*)(ws + alloc(nO * 2));

    CvtArgs ca;
    ca.s[0] = wq;  ca.d[0] = wqb;  ca.n8[0] = (int)(nQ / 8);
    ca.s[1] = wk;  ca.d[1] = wkb;  ca.n8[1] = (int)(nQ / 8);
    ca.s[2] = wvw; ca.d[2] = wvb;  ca.n8[2] = (int)(nQ / 8);
    ca.s[3] = wo;  ca.d[3] = wob;  ca.n8[3] = (int)(nQ / 8);
    ca.s[4] = w1;  ca.d[4] = w1b;  ca.n8[4] = (int)(nF / 8);
    ca.s[5] = w2;  ca.d[5] = w2b;  ca.n8[5] = (int)(nF / 8);
    ca.s[6] = w3;  ca.d[6] = w3b;  ca.n8[6] = (int)(nF / 8);
    ca.s[7] = w_out; ca.d[7] = woub; ca.n8[7] = (int)(nO / 8);
    cvt_all_kernel<<<2048, 256, 0, stream>>>(ca);

    embed_kernel<<<SEQ, 256, 0, stream>>>(tokens, tok_emb, h);
    ropetab_kernel<<<(SEQ * 32) / 256, 256, 0, stream>>>(cosb, sinb);
    span_kernel<<<1, SEQ, 0, stream>>>(tokens, span, tmask);

    for (int l = 0; l < NLAY; ++l) {
        rmsnorm_kernel<<<SEQ, 256, 0, stream>>>(h, attn_nw + (size_t)l * DM, xn);
        qkv_kernel<<<dim3(8, 24), 256, 0, stream>>>(
            xn, wqb + (size_t)l * DM * DM, wkb + (size_t)l * DM * DM, wvb + (size_t)l * DM * DM,
            cosb, sinb, qb, kb, vb);
        fattn_kernel<<<dim3(SEQ / 64, NHEADS), 256, 0, stream>>>(qb, kb, vb, span, tmask, ab);
        gemm_p_kernel<1, 64, 64><<<dim3(16, 16), 256, 0, stream>>>(
            ab, wob + (size_t)l * DM * DM, h, h, DM, DM);

        rmsnorm_kernel<<<SEQ, 256, 0, stream>>>(h, ffn_nw + (size_t)l * DM, xn);
        ffn13_kernel<<<dim3(16, 22), 256, 0, stream>>>(
            xn, w1b + (size_t)l * FFD * DM, w3b + (size_t)l * FFD * DM, zb);
        gemm_p_kernel<1, 64, 64><<<dim3(16, 16), 256, 0, stream>>>(
            zb, w2b + (size_t)l * DM * FFD, h, h, DM, FFD);
    }

    rmsnorm_kernel<<<SEQ, 256, 0, stream>>>(h, final_nw, xn);
    gemm_big_kernel<0><<<dim3(SEQ / 256, VOC / 256), 512, 0, stream>>>(
        xn, woub, logits, nullptr, VOC, DM);
}

// Round 9
// 382.384 us; speedup vs baseline: 10.2794x; 1.0062x over previous
//
#include <hip/hip_runtime.h>
#include <hip/hip_bf16.h>
#include <stdint.h>

typedef unsigned short u16;
typedef __bf16 bf16x8 __attribute__((ext_vector_type(8)));
typedef u16 u16x8 __attribute__((ext_vector_type(8)));
typedef float f32x4 __attribute__((ext_vector_type(4)));

#define SEQ   1024
#define DM    1024
#define NHEADS 16
#define HDIM  64
#define VOC   32000
#define FFD   2816
#define NLAY  2

__device__ __forceinline__ u16 f2b(float f) {
    unsigned x = __builtin_bit_cast(unsigned, f);
    unsigned r = x + 0x7fffu + ((x >> 16) & 1u);
    return (u16)(r >> 16);
}
__device__ __forceinline__ float b2f(u16 u) {
    unsigned x = ((unsigned)u) << 16;
    return __builtin_bit_cast(float, x);
}
__device__ __forceinline__ float grpmax16(float v) {
    v = fmaxf(v, __shfl_xor(v, 1)); v = fmaxf(v, __shfl_xor(v, 2));
    v = fmaxf(v, __shfl_xor(v, 4)); v = fmaxf(v, __shfl_xor(v, 8));
    return v;
}
__device__ __forceinline__ float grpsum16(float v) {
    v += __shfl_xor(v, 1); v += __shfl_xor(v, 2);
    v += __shfl_xor(v, 4); v += __shfl_xor(v, 8);
    return v;
}

// async global->LDS, 16 bytes per lane. LDS dest must be wave-uniform base + lane*16.
__device__ __forceinline__ void gll16(const void* g, void* l) {
    __builtin_amdgcn_global_load_lds(
        (__attribute__((address_space(1))) void*)(uintptr_t)g,
        (__attribute__((address_space(3))) void*)(uint32_t)(uintptr_t)l,
        16, 0, 0);
}
template <int N> __device__ __forceinline__ void vwait() {
    if constexpr (N == 0)       asm volatile("s_waitcnt vmcnt(0)" ::: "memory");
    else if constexpr (N == 4)  asm volatile("s_waitcnt vmcnt(4)" ::: "memory");
    else if constexpr (N == 8)  asm volatile("s_waitcnt vmcnt(8)" ::: "memory");
    else if constexpr (N == 10) asm volatile("s_waitcnt vmcnt(10)" ::: "memory");
    else if constexpr (N == 16) asm volatile("s_waitcnt vmcnt(16)" ::: "memory");
}
// bijective XCD swizzle for any nwg (m204): per-XCD contiguous logical chunks.
__device__ __forceinline__ int xcd_swz(int bid, int nwg) {
    const int q = nwg >> 3, r = nwg & 7;
    const int xcd = bid & 7, j = bid >> 3;
    const int start = (xcd < r) ? xcd * (q + 1) : r * (q + 1) + (xcd - r) * q;
    return start + j;
}

// ---------------- fp32 -> bf16 weight conversion: flat-balanced, ONE launch ----------------
// unit = 16 elements (64 B read, 32 B write per lane per iter). Flat index over all 8
// segments -> every thread busy every iteration regardless of segment sizes.
struct CvtArgs { const float* s[8]; u16* d[8]; int cum[9]; };
__global__ __launch_bounds__(256) void cvt_all_kernel(CvtArgs a) {
    const int stride = gridDim.x * 256;
    const int total = a.cum[8];
    for (int u = blockIdx.x * 256 + threadIdx.x; u < total; u += stride) {
        int g = 0;
#pragma unroll
        for (int k = 1; k < 8; ++k) g += (u >= a.cum[k]) ? 1 : 0;
        const int local = u - a.cum[g];
        const float4* sp = (const float4*)a.s[g] + (size_t)local * 4;
        const float4 x0 = sp[0], x1 = sp[1], x2 = sp[2], x3 = sp[3];
        ushort4 p0, p1, p2, p3;
        p0.x = f2b(x0.x); p0.y = f2b(x0.y); p0.z = f2b(x0.z); p0.w = f2b(x0.w);
        p1.x = f2b(x1.x); p1.y = f2b(x1.y); p1.z = f2b(x1.z); p1.w = f2b(x1.w);
        p2.x = f2b(x2.x); p2.y = f2b(x2.y); p2.z = f2b(x2.z); p2.w = f2b(x2.w);
        p3.x = f2b(x3.x); p3.y = f2b(x3.y); p3.z = f2b(x3.z); p3.w = f2b(x3.w);
        ushort4* dp = (ushort4*)a.d[g] + (size_t)local * 4;
        dp[0] = p0; dp[1] = p1; dp[2] = p2; dp[3] = p3;
    }
}

// ---------------- embedding gather ----------------
__global__ __launch_bounds__(256) void embed_kernel(const int* __restrict__ tok,
    const float* __restrict__ emb, float* __restrict__ h) {
    const int l = blockIdx.x;
    const int t = tok[l];
    ((float4*)(h + (size_t)l * DM))[threadIdx.x] =
        ((const float4*)(emb + (size_t)t * DM))[threadIdx.x];
}

// ---------------- rope tables ----------------
__global__ __launch_bounds__(256) void ropetab_kernel(float* __restrict__ cosb,
                                                      float* __restrict__ sinb) {
    const int idx = blockIdx.x * 256 + threadIdx.x;   // < SEQ*32
    const int l = idx >> 5, j = idx & 31;
    const float inv = __expf(-((float)j * (1.0f / 32.0f)) * 13.122363377404328f); // ln(500000)
    const float ang = (float)l * inv;
    cosb[idx] = cosf(ang);
    sinb[idx] = sinf(ang);
}

// ---------------- transfusion span ids + per-64-token-tile span bitmask ----------------
__global__ void span_kernel(const int* __restrict__ tok, int* __restrict__ span,
                            int* __restrict__ tmask) {
    __shared__ int sb[SEQ], se[SEQ];
    __shared__ int tm[SEQ / 64];
    const int t = threadIdx.x;
    const int v = tok[t];
    const int bo = (v == 31998) ? 1 : 0;
    const int eo = (v == 31999) ? 1 : 0;
    sb[t] = bo; se[t] = eo;
    if (t < SEQ / 64) tm[t] = 0;
    __syncthreads();
    for (int o = 1; o < SEQ; o <<= 1) {
        int a = 0, b = 0;
        if (t >= o) { a = sb[t - o]; b = se[t - o]; }
        __syncthreads();
        sb[t] += a; se[t] += b;
        __syncthreads();
    }
    const int bc = sb[t];
    const int ec = se[t] - eo;           // exclusive eoi cumsum
    const int id = (bc > ec) ? bc : 0;
    span[t] = id;
    if (id > 0) atomicOr(&tm[t >> 6], 1 << ((id - 1) & 31));
    __syncthreads();
    if (t < SEQ / 64) tmask[t] = tm[t];
}

// ---------------- rmsnorm (fp32 in -> bf16 out) ----------------
__global__ __launch_bounds__(256) void rmsnorm_kernel(const float* __restrict__ x,
    const float* __restrict__ w, u16* __restrict__ o) {
    const int row = blockIdx.x;
    const float4 xv = ((const float4*)(x + (size_t)row * DM))[threadIdx.x];
    float ss = xv.x * xv.x + xv.y * xv.y + xv.z * xv.z + xv.w * xv.w;
    for (int off = 32; off; off >>= 1) ss += __shfl_xor(ss, off);
    __shared__ float red[4];
    const int lane = threadIdx.x & 63, wvi = threadIdx.x >> 6;
    if (lane == 0) red[wvi] = ss;
    __syncthreads();
    const float tot = red[0] + red[1] + red[2] + red[3];
    const float sc = rsqrtf(tot * (1.0f / (float)DM) + 1e-5f);
    const float4 wv4 = ((const float4*)w)[threadIdx.x];
    ushort4 ov;
    ov.x = f2b(xv.x * sc * wv4.x);
    ov.y = f2b(xv.y * sc * wv4.y);
    ov.z = f2b(xv.z * sc * wv4.z);
    ov.w = f2b(xv.w * sc * wv4.w);
    ((ushort4*)(o + (size_t)row * DM))[threadIdx.x] = ov;
}

// ======================= pipelined GEMM (BK=64, counted vmcnt) =======================
// LDS rows 128B; granule swizzle gr' = gr ^ (row&7) conflict-free; swizzle baked into
// per-thread staging pointers. Per K-tile: stage t+1 -> p^1 ; vwait<LOADS> ; s_barrier ;
// ds_read p + MFMA ; s_barrier. No vmcnt(0) drain in the main loop.

// ---------------- generic pipelined GEMM, fp32 out (+optional residual) ----------------
template <int RESID, int BM, int BN>
__global__ __launch_bounds__(256) void gemm_p_kernel(const u16* __restrict__ A,
    const u16* __restrict__ B, float* __restrict__ C, const float* __restrict__ res,
    int N, int K) {
    constexpr int AL = BM / 32, BL = BN / 32, LOADS = AL + BL;
    constexpr int MF = BM / 32, NF = BN / 32;
    __shared__ __align__(16) u16 sA[2][BM * 64];
    __shared__ __align__(16) u16 sB[2][BN * 64];
    const int nwg = gridDim.x * gridDim.y;
    const int lid = xcd_swz(blockIdx.y * gridDim.x + blockIdx.x, nwg);
    const int tm = (lid % gridDim.x) * BM, tn = (lid / gridDim.x) * BN;
    const int tid = threadIdx.x, lane = tid & 63, wid = tid >> 6;
    const int wm = wid >> 1, wn = wid & 1, fr = lane & 15, g = lane >> 4;

    const u16* ap[AL]; const u16* bp[BL];
#pragma unroll
    for (int j = 0; j < AL; ++j) {
        const int idx = j * 256 + tid, r = idx >> 3, gr = (idx & 7) ^ (r & 7);
        ap[j] = A + (size_t)(tm + r) * K + gr * 8;
    }
#pragma unroll
    for (int j = 0; j < BL; ++j) {
        const int idx = j * 256 + tid, r = idx >> 3, gr = (idx & 7) ^ (r & 7);
        bp[j] = B + (size_t)(tn + r) * K + gr * 8;
    }

    f32x4 acc[MF][NF] = {};
    const int NT = K >> 6;
#pragma unroll
    for (int j = 0; j < AL; ++j) gll16(ap[j], &sA[0][(j * 256 + tid) * 8]);
#pragma unroll
    for (int j = 0; j < BL; ++j) gll16(bp[j], &sB[0][(j * 256 + tid) * 8]);

    int p = 0;
    for (int t = 0; t < NT; ++t) {
        if (t + 1 < NT) {
#pragma unroll
            for (int j = 0; j < AL; ++j) gll16(ap[j] + (t + 1) * 64, &sA[p ^ 1][(j * 256 + tid) * 8]);
#pragma unroll
            for (int j = 0; j < BL; ++j) gll16(bp[j] + (t + 1) * 64, &sB[p ^ 1][(j * 256 + tid) * 8]);
            vwait<LOADS>();
        } else {
            vwait<0>();
        }
        __builtin_amdgcn_s_barrier();          // all waves' tile-t data resident
        __builtin_amdgcn_sched_barrier(0);
        bf16x8 af[MF][2], bfv[NF][2];
#pragma unroll
        for (int m = 0; m < MF; ++m)
#pragma unroll
            for (int ks = 0; ks < 2; ++ks) {
                const int row = wm * (BM / 2) + m * 16 + fr;
                const int gr = (ks * 4 + g) ^ (row & 7);
                af[m][ks] = *(const bf16x8*)&sA[p][row * 64 + gr * 8];
            }
#pragma unroll
        for (int n = 0; n < NF; ++n)
#pragma unroll
            for (int ks = 0; ks < 2; ++ks) {
                const int row = wn * (BN / 2) + n * 16 + fr;
                const int gr = (ks * 4 + g) ^ (row & 7);
                bfv[n][ks] = *(const bf16x8*)&sB[p][row * 64 + gr * 8];
            }
        __builtin_amdgcn_s_setprio(1);
#pragma unroll
        for (int m = 0; m < MF; ++m)
#pragma unroll
            for (int n = 0; n < NF; ++n)
#pragma unroll
                for (int ks = 0; ks < 2; ++ks)
                    acc[m][n] = __builtin_amdgcn_mfma_f32_16x16x32_bf16(af[m][ks], bfv[n][ks], acc[m][n], 0, 0, 0);
        __builtin_amdgcn_s_setprio(0);
        __builtin_amdgcn_s_barrier();          // reads of buf p closed before next writes
        p ^= 1;
    }

    const int cr = (lane >> 4) * 4, cc = lane & 15;
#pragma unroll
    for (int m = 0; m < MF; ++m)
#pragma unroll
        for (int n = 0; n < NF; ++n) {
            const int row0 = tm + wm * (BM / 2) + m * 16 + cr;
            const int col = tn + wn * (BN / 2) + n * 16 + cc;
#pragma unroll
            for (int r = 0; r < 4; ++r) {
                const size_t idx = (size_t)(row0 + r) * N + col;
                float v = acc[m][n][r];
                if (RESID) v += res[idx];
                C[idx] = v;
            }
        }
}

// ======================= 256x256 / BK=64 / 8-wave phase-interleaved GEMM =======================
// m201-style: per K-tile 4 quadrant phases {ds_read frags ; setprio MFMA ; s_barrier}.
template <int RESID>
__global__ __launch_bounds__(512, 2) void gemm_big_kernel(const u16* __restrict__ A,
    const u16* __restrict__ B, float* __restrict__ C, const float* __restrict__ res,
    int N, int K) {
    __shared__ __align__(16) u16 sA[2][256 * 64];
    __shared__ __align__(16) u16 sB[2][256 * 64];
    const int nwg = gridDim.x * gridDim.y;
    const int lid = xcd_swz(blockIdx.y * gridDim.x + blockIdx.x, nwg);
    const int tm = (lid % gridDim.x) * 256;
    const int tn = (lid / gridDim.x) * 256;
    const int tid = threadIdx.x, lane = tid & 63, wid = tid >> 6;
    const int wm = wid >> 2, wn = wid & 3;       // 2 x 4 waves, per-wave 128x64
    const int fr = lane & 15, g = lane >> 4;

    const u16* ap[4]; const u16* bp[4];
#pragma unroll
    for (int j = 0; j < 4; ++j) {
        const int idx = j * 512 + tid, r = idx >> 3, gr = (idx & 7) ^ (r & 7);
        ap[j] = A + (size_t)(tm + r) * K + gr * 8;
        bp[j] = B + (size_t)(tn + r) * K + gr * 8;
    }

    f32x4 acc[8][4] = {};
    const int NT = K >> 6;
#pragma unroll
    for (int j = 0; j < 4; ++j) gll16(ap[j], &sA[0][(j * 512 + tid) * 8]);
#pragma unroll
    for (int j = 0; j < 4; ++j) gll16(bp[j], &sB[0][(j * 512 + tid) * 8]);

    int p = 0;
    for (int t = 0; t < NT; ++t) {
        if (t + 1 < NT) {
#pragma unroll
            for (int j = 0; j < 4; ++j) gll16(ap[j] + (t + 1) * 64, &sA[p ^ 1][(j * 512 + tid) * 8]);
#pragma unroll
            for (int j = 0; j < 4; ++j) gll16(bp[j] + (t + 1) * 64, &sB[p ^ 1][(j * 512 + tid) * 8]);
            vwait<8>();
        } else {
            vwait<0>();
        }
        __builtin_amdgcn_s_barrier();            // tile-t resident for all waves
        __builtin_amdgcn_sched_barrier(0);
        bf16x8 bfv[4][2];
#pragma unroll
        for (int mq = 0; mq < 4; ++mq) {         // 4 phases per K-tile
            if (mq == 0) {
#pragma unroll
                for (int n = 0; n < 4; ++n)
#pragma unroll
                    for (int ks = 0; ks < 2; ++ks) {
                        const int row = wn * 64 + n * 16 + fr;
                        const int gr = (ks * 4 + g) ^ (row & 7);
                        bfv[n][ks] = *(const bf16x8*)&sB[p][row * 64 + gr * 8];
                    }
            }
            bf16x8 af[2][2];
#pragma unroll
            for (int i = 0; i < 2; ++i)
#pragma unroll
                for (int ks = 0; ks < 2; ++ks) {
                    const int row = wm * 128 + (mq * 2 + i) * 16 + fr;
                    const int gr = (ks * 4 + g) ^ (row & 7);
                    af[i][ks] = *(const bf16x8*)&sA[p][row * 64 + gr * 8];
                }
            __builtin_amdgcn_s_setprio(1);
#pragma unroll
            for (int i = 0; i < 2; ++i)
#pragma unroll
                for (int n = 0; n < 4; ++n)
#pragma unroll
                    for (int ks = 0; ks < 2; ++ks)
                        acc[mq * 2 + i][n] = __builtin_amdgcn_mfma_f32_16x16x32_bf16(
                            af[i][ks], bfv[n][ks], acc[mq * 2 + i][n], 0, 0, 0);
            __builtin_amdgcn_s_setprio(0);
            __builtin_amdgcn_s_barrier();        // phase boundary (last one closes WAR)
        }
        p ^= 1;
    }

    const int cr = (lane >> 4) * 4, cc = lane & 15;
#pragma unroll
    for (int m = 0; m < 8; ++m)
#pragma unroll
        for (int n = 0; n < 4; ++n) {
            const int row0 = tm + wm * 128 + m * 16 + cr;
            const int col = tn + wn * 64 + n * 16 + cc;
#pragma unroll
            for (int r = 0; r < 4; ++r) {
                const size_t idx = (size_t)(row0 + r) * N + col;
                float v = acc[m][n][r];
                if (RESID) v += res[idx];
                C[idx] = v;
            }
        }
}

// ---------------- fused QKV GEMM (128x128) + RoPE + bf16 cast ----------------
__global__ __launch_bounds__(256) void qkv_kernel(const u16* __restrict__ A,
    const u16* __restrict__ Bq, const u16* __restrict__ Bk, const u16* __restrict__ Bv,
    const float* __restrict__ cosb, const float* __restrict__ sinb,
    u16* __restrict__ qb, u16* __restrict__ kb, u16* __restrict__ vb) {
    __shared__ __align__(16) u16 sA[2][128 * 64];
    __shared__ __align__(16) u16 sB[2][128 * 64];
    const int lid = xcd_swz(blockIdx.y * gridDim.x + blockIdx.x, 8 * 24);
    const int tm = (lid % 8) * 128;
    const int yy = lid / 8;
    const int mat = yy >> 3;
    const int tn = (yy & 7) * 128;
    const u16* B = (mat == 0) ? Bq : (mat == 1) ? Bk : Bv;
    u16* out = (mat == 0) ? qb : (mat == 1) ? kb : vb;
    const int tid = threadIdx.x, lane = tid & 63, wid = tid >> 6;
    const int wm = wid >> 1, wn = wid & 1, fr = lane & 15, g = lane >> 4;

    const u16* ap[4]; const u16* bp[4];
#pragma unroll
    for (int j = 0; j < 4; ++j) {
        const int idx = j * 256 + tid, r = idx >> 3, gr = (idx & 7) ^ (r & 7);
        ap[j] = A + (size_t)(tm + r) * DM + gr * 8;
        bp[j] = B + (size_t)(tn + r) * DM + gr * 8;
    }

    f32x4 acc[4][4] = {};
#pragma unroll
    for (int j = 0; j < 4; ++j) gll16(ap[j], &sA[0][(j * 256 + tid) * 8]);
#pragma unroll
    for (int j = 0; j < 4; ++j) gll16(bp[j], &sB[0][(j * 256 + tid) * 8]);

    int p = 0;
    for (int t = 0; t < DM / 64; ++t) {
        if (t + 1 < DM / 64) {
#pragma unroll
            for (int j = 0; j < 4; ++j) gll16(ap[j] + (t + 1) * 64, &sA[p ^ 1][(j * 256 + tid) * 8]);
#pragma unroll
            for (int j = 0; j < 4; ++j) gll16(bp[j] + (t + 1) * 64, &sB[p ^ 1][(j * 256 + tid) * 8]);
            vwait<8>();
        } else {
            vwait<0>();
        }
        __builtin_amdgcn_s_barrier();
        __builtin_amdgcn_sched_barrier(0);
        bf16x8 af[4][2], bfv[4][2];
#pragma unroll
        for (int m = 0; m < 4; ++m)
#pragma unroll
            for (int ks = 0; ks < 2; ++ks) {
                const int row = wm * 64 + m * 16 + fr;
                const int gr = (ks * 4 + g) ^ (row & 7);
                af[m][ks] = *(const bf16x8*)&sA[p][row * 64 + gr * 8];
            }
#pragma unroll
        for (int n = 0; n < 4; ++n)
#pragma unroll
            for (int ks = 0; ks < 2; ++ks) {
                const int row = wn * 64 + n * 16 + fr;
                const int gr = (ks * 4 + g) ^ (row & 7);
                bfv[n][ks] = *(const bf16x8*)&sB[p][row * 64 + gr * 8];
            }
        __builtin_amdgcn_s_setprio(1);
#pragma unroll
        for (int m = 0; m < 4; ++m)
#pragma unroll
            for (int n = 0; n < 4; ++n)
#pragma unroll
                for (int ks = 0; ks < 2; ++ks)
                    acc[m][n] = __builtin_amdgcn_mfma_f32_16x16x32_bf16(af[m][ks], bfv[n][ks], acc[m][n], 0, 0, 0);
        __builtin_amdgcn_s_setprio(0);
        __builtin_amdgcn_s_barrier();
        p ^= 1;
    }

    const int cr = (lane >> 4) * 4, cc = lane & 15;
    if (mat < 2) {
#pragma unroll
        for (int m = 0; m < 4; ++m)
#pragma unroll
            for (int n = 0; n < 4; ++n) {
                const int row0 = tm + wm * 64 + m * 16 + cr;
                const int col = tn + wn * 64 + n * 16 + cc;
                const int j = (n * 16 + cc) >> 1;    // rope pair index within head
#pragma unroll
                for (int r = 0; r < 4; ++r) {
                    const int row = row0 + r;
                    const float c = cosb[row * 32 + j];
                    const float s = sinb[row * 32 + j];
                    const float v = acc[m][n][r];
                    const float pv = __shfl_xor(v, 1);
                    const float o = (cc & 1) ? (pv * s + v * c) : (v * c - pv * s);
                    out[(size_t)row * DM + col] = f2b(o);
                }
            }
    } else {
#pragma unroll
        for (int m = 0; m < 4; ++m)
#pragma unroll
            for (int n = 0; n < 4; ++n) {
                const int row0 = tm + wm * 64 + m * 16 + cr;
                const int col = tn + wn * 64 + n * 16 + cc;
#pragma unroll
                for (int r = 0; r < 4; ++r)
                    out[(size_t)(row0 + r) * DM + col] = f2b(acc[m][n][r]);
            }
    }
}

// ---------------- fused w1/w3 GEMM (64x128 dual-B) + SiLU*mul -> bf16 ----------------
__global__ __launch_bounds__(256) void ffn13_kernel(const u16* __restrict__ A,
    const u16* __restrict__ B1, const u16* __restrict__ B3, u16* __restrict__ Z) {
    __shared__ __align__(16) u16 sA[2][64 * 64];
    __shared__ __align__(16) u16 sB1[2][128 * 64];
    __shared__ __align__(16) u16 sB3[2][128 * 64];
    const int lid = xcd_swz(blockIdx.y * gridDim.x + blockIdx.x, 16 * 22);
    const int tm = (lid % 16) * 64;
    const int tn = (lid / 16) * 128;
    const int tid = threadIdx.x, lane = tid & 63, wid = tid >> 6;
    const int wm = wid >> 1, wn = wid & 1, fr = lane & 15, g = lane >> 4;

    const u16* ap[2]; const u16* b1p[4]; const u16* b3p[4];
#pragma unroll
    for (int j = 0; j < 2; ++j) {
        const int idx = j * 256 + tid, r = idx >> 3, gr = (idx & 7) ^ (r & 7);
        ap[j] = A + (size_t)(tm + r) * DM + gr * 8;
    }
#pragma unroll
    for (int j = 0; j < 4; ++j) {
        const int idx = j * 256 + tid, r = idx >> 3, gr = (idx & 7) ^ (r & 7);
        b1p[j] = B1 + (size_t)(tn + r) * DM + gr * 8;
        b3p[j] = B3 + (size_t)(tn + r) * DM + gr * 8;
    }

    f32x4 acc1[2][4] = {}, acc3[2][4] = {};
#pragma unroll
    for (int j = 0; j < 2; ++j) gll16(ap[j], &sA[0][(j * 256 + tid) * 8]);
#pragma unroll
    for (int j = 0; j < 4; ++j) gll16(b1p[j], &sB1[0][(j * 256 + tid) * 8]);
#pragma unroll
    for (int j = 0; j < 4; ++j) gll16(b3p[j], &sB3[0][(j * 256 + tid) * 8]);

    int p = 0;
    for (int t = 0; t < DM / 64; ++t) {
        if (t + 1 < DM / 64) {
#pragma unroll
            for (int j = 0; j < 2; ++j) gll16(ap[j] + (t + 1) * 64, &sA[p ^ 1][(j * 256 + tid) * 8]);
#pragma unroll
            for (int j = 0; j < 4; ++j) gll16(b1p[j] + (t + 1) * 64, &sB1[p ^ 1][(j * 256 + tid) * 8]);
#pragma unroll
            for (int j = 0; j < 4; ++j) gll16(b3p[j] + (t + 1) * 64, &sB3[p ^ 1][(j * 256 + tid) * 8]);
            vwait<10>();
        } else {
            vwait<0>();
        }
        __builtin_amdgcn_s_barrier();
        __builtin_amdgcn_sched_barrier(0);
        bf16x8 af[2][2], b1v[4][2], b3v[4][2];
#pragma unroll
        for (int m = 0; m < 2; ++m)
#pragma unroll
            for (int ks = 0; ks < 2; ++ks) {
                const int row = wm * 32 + m * 16 + fr;
                const int gr = (ks * 4 + g) ^ (row & 7);
                af[m][ks] = *(const bf16x8*)&sA[p][row * 64 + gr * 8];
            }
#pragma unroll
        for (int n = 0; n < 4; ++n)
#pragma unroll
            for (int ks = 0; ks < 2; ++ks) {
                const int row = wn * 64 + n * 16 + fr;
                const int gr = (ks * 4 + g) ^ (row & 7);
                b1v[n][ks] = *(const bf16x8*)&sB1[p][row * 64 + gr * 8];
                b3v[n][ks] = *(const bf16x8*)&sB3[p][row * 64 + gr * 8];
            }
        __builtin_amdgcn_s_setprio(1);
#pragma unroll
        for (int m = 0; m < 2; ++m)
#pragma unroll
            for (int n = 0; n < 4; ++n)
#pragma unroll
                for (int ks = 0; ks < 2; ++ks) {
                    acc1[m][n] = __builtin_amdgcn_mfma_f32_16x16x32_bf16(af[m][ks], b1v[n][ks], acc1[m][n], 0, 0, 0);
                    acc3[m][n] = __builtin_amdgcn_mfma_f32_16x16x32_bf16(af[m][ks], b3v[n][ks], acc3[m][n], 0, 0, 0);
                }
        __builtin_amdgcn_s_setprio(0);
        __builtin_amdgcn_s_barrier();
        p ^= 1;
    }

    const int cr = (lane >> 4) * 4, cc = lane & 15;
#pragma unroll
    for (int m = 0; m < 2; ++m)
#pragma unroll
        for (int n = 0; n < 4; ++n) {
            const int row0 = tm + wm * 32 + m * 16 + cr;
            const int col = tn + wn * 64 + n * 16 + cc;
#pragma unroll
            for (int r = 0; r < 4; ++r) {
                const float a1 = acc1[m][n][r];
                const float a3 = acc3[m][n][r];
                const float z = a1 / (1.f + __expf(-a1)) * a3;
                Z[(size_t)(row0 + r) * FFD + col] = f2b(z);
            }
        }
}

// ---------------- flash attention: block = (64 q-rows, 1 head), 4 waves ----------------
// KV-tile skip: tiles beyond the causal frontier processed only if span bitmasks overlap.
__global__ __launch_bounds__(256) void fattn_kernel(const u16* __restrict__ qb,
    const u16* __restrict__ kb, const u16* __restrict__ vb,
    const int* __restrict__ span, const int* __restrict__ tmask, u16* __restrict__ ob) {
    __shared__ __align__(16) u16 sK[64][72];   // K rows, padded
    __shared__ __align__(16) u16 sVT[64][72];  // V transposed: [d][key]
    __shared__ __align__(16) u16 sP[4][16][72];// per-wave P tile
    const int tid = threadIdx.x, lane = tid & 63, wq = tid >> 6;
    const int g = lane >> 4, fr = lane & 15;
    const int head = blockIdx.y;
    const int qbase = blockIdx.x * 64;
    const int qmask = tmask[blockIdx.x];

    bf16x8 qfr[2];
    {
        const u16* qp = qb + (size_t)(qbase + wq * 16 + fr) * DM + head * HDIM + g * 8;
        qfr[0] = *(const bf16x8*)(qp);
        qfr[1] = *(const bf16x8*)(qp + 32);
    }
    int sq[4];
#pragma unroll
    for (int r = 0; r < 4; ++r) sq[r] = span[qbase + wq * 16 + g * 4 + r];

    float m_old[4] = {-1e30f, -1e30f, -1e30f, -1e30f};
    float lsum[4] = {0.f, 0.f, 0.f, 0.f};
    f32x4 acc[4] = {};

    for (int kt = 0; kt < SEQ / 64; ++kt) {
        const int kb0 = kt * 64;
        if (kb0 > qbase && (qmask & tmask[kt]) == 0) continue;   // block-uniform skip
        __syncthreads();
        {
            const int r = tid >> 2, c0 = (tid & 3) * 16;
            const u16* src = kb + (size_t)(kb0 + r) * DM + head * HDIM + c0;
            *(u16x8*)&sK[r][c0]     = *(const u16x8*)(src);
            *(u16x8*)&sK[r][c0 + 8] = *(const u16x8*)(src + 8);
        }
        {
            const int k = tid & 63, d0 = (tid >> 6) * 16;
            const u16* src = vb + (size_t)(kb0 + k) * DM + head * HDIM + d0;
            const u16x8 v0 = *(const u16x8*)(src);
            const u16x8 v1 = *(const u16x8*)(src + 8);
#pragma unroll
            for (int j = 0; j < 8; ++j) {
                sVT[d0 + j][k]     = v0[j];
                sVT[d0 + 8 + j][k] = v1[j];
            }
        }
        __syncthreads();

        f32x4 accs[4] = {};
        __builtin_amdgcn_s_setprio(1);
#pragma unroll
        for (int nf = 0; nf < 4; ++nf)
#pragma unroll
            for (int kf = 0; kf < 2; ++kf) {
                const bf16x8 kfv = *(const bf16x8*)&sK[nf * 16 + fr][g * 8 + kf * 32];
                accs[nf] = __builtin_amdgcn_mfma_f32_16x16x32_bf16(qfr[kf], kfv, accs[nf], 0, 0, 0);
            }
        __builtin_amdgcn_s_setprio(0);

        float sv[4][4]; bool al[4][4];
        if (kb0 + 63 <= qbase) {             // fully-causal tile: all allowed
#pragma unroll
            for (int nf = 0; nf < 4; ++nf)
#pragma unroll
                for (int r = 0; r < 4; ++r) {
                    al[nf][r] = true;
                    sv[nf][r] = accs[nf][r] * 0.125f;
                }
        } else {
            int spk[4];
#pragma unroll
            for (int nf = 0; nf < 4; ++nf) spk[nf] = span[kb0 + nf * 16 + fr];
#pragma unroll
            for (int nf = 0; nf < 4; ++nf) {
                const int key = kb0 + nf * 16 + fr;
#pragma unroll
                for (int r = 0; r < 4; ++r) {
                    const int q = qbase + wq * 16 + g * 4 + r;
                    al[nf][r] = (key <= q) || (sq[r] > 0 && spk[nf] == sq[r]);
                    sv[nf][r] = al[nf][r] ? accs[nf][r] * 0.125f : -1e30f;
                }
            }
        }
        float alpha[4], ls[4];
#pragma unroll
        for (int r = 0; r < 4; ++r) {
            float mn = fmaxf(fmaxf(sv[0][r], sv[1][r]), fmaxf(sv[2][r], sv[3][r]));
            mn = grpmax16(mn);
            const float mnew = fmaxf(m_old[r], mn);
            alpha[r] = __expf(m_old[r] - mnew);
            m_old[r] = mnew;
            ls[r] = 0.f;
        }
        u16 pb[4][4];
#pragma unroll
        for (int nf = 0; nf < 4; ++nf)
#pragma unroll
            for (int r = 0; r < 4; ++r) {
                const float p = al[nf][r] ? __expf(sv[nf][r] - m_old[r]) : 0.f;
                ls[r] += p;
                pb[nf][r] = f2b(p);
            }
#pragma unroll
        for (int r = 0; r < 4; ++r) {
            lsum[r] = lsum[r] * alpha[r] + grpsum16(ls[r]);
#pragma unroll
            for (int nf = 0; nf < 4; ++nf) acc[nf][r] *= alpha[r];
        }
#pragma unroll
        for (int nf = 0; nf < 4; ++nf)
#pragma unroll
            for (int r = 0; r < 4; ++r)
                sP[wq][g * 4 + r][nf * 16 + fr] = pb[nf][r];

        __builtin_amdgcn_s_setprio(1);
#pragma unroll
        for (int nf = 0; nf < 4; ++nf)
#pragma unroll
            for (int kf = 0; kf < 2; ++kf) {
                const bf16x8 pa  = *(const bf16x8*)&sP[wq][fr][g * 8 + kf * 32];
                const bf16x8 vtb = *(const bf16x8*)&sVT[nf * 16 + fr][g * 8 + kf * 32];
                acc[nf] = __builtin_amdgcn_mfma_f32_16x16x32_bf16(pa, vtb, acc[nf], 0, 0, 0);
            }
        __builtin_amdgcn_s_setprio(0);
    }

#pragma unroll
    for (int nf = 0; nf < 4; ++nf)
#pragma unroll
        for (int r = 0; r < 4; ++r) {
            const int q = qbase + wq * 16 + g * 4 + r;
            const int d = nf * 16 + fr;
            ob[(size_t)q * DM + head * HDIM + d] = f2b(acc[nf][r] / lsum[r]);
        }
}

extern "C" void kernel_launch(void* const* d_in, const int* in_sizes, int n_in,
                              void* d_out, int out_size, void* d_ws, size_t ws_size,
                              hipStream_t stream) {
    (void)in_sizes; (void)n_in; (void)out_size; (void)ws_size;
    const int*   tokens   = (const int*)d_in[0];
    const float* tok_emb  = (const float*)d_in[1];
    const float* wq       = (const float*)d_in[2];
    const float* wk       = (const float*)d_in[3];
    const float* wvw      = (const float*)d_in[4];
    const float* wo       = (const float*)d_in[5];
    const float* w1       = (const float*)d_in[6];
    const float* w2       = (const float*)d_in[7];
    const float* w3       = (const float*)d_in[8];
    const float* attn_nw  = (const float*)d_in[9];
    const float* ffn_nw   = (const float*)d_in[10];
    const float* final_nw = (const float*)d_in[11];
    const float* w_out    = (const float*)d_in[12];
    float* logits = (float*)d_out;

    char* ws = (char*)d_ws;
    size_t off = 0;
    auto alloc = [&](size_t b) { size_t o = off; off += (b + 255) & ~(size_t)255; return o; };
    float* h    = (float*)(ws + alloc((size_t)SEQ * DM * 4));
    u16*   xn   = (u16*)  (ws + alloc((size_t)SEQ * DM * 2));
    u16*   qb   = (u16*)  (ws + alloc((size_t)SEQ * DM * 2));
    u16*   kb   = (u16*)  (ws + alloc((size_t)SEQ * DM * 2));
    u16*   vb   = (u16*)  (ws + alloc((size_t)SEQ * DM * 2));
    u16*   ab   = (u16*)  (ws + alloc((size_t)SEQ * DM * 2));
    u16*   zb   = (u16*)  (ws + alloc((size_t)SEQ * FFD * 2));
    float* cosb = (float*)(ws + alloc((size_t)SEQ * 32 * 4));
    float* sinb = (float*)(ws + alloc((size_t)SEQ * 32 * 4));
    int*   span = (int*)  (ws + alloc((size_t)SEQ * 4));
    int*   tmask= (int*)  (ws + alloc((size_t)(SEQ / 64) * 4));
    // bf16 weight copies
    const size_t nQ = (size_t)NLAY * DM * DM;     // wq/wk/wv/wo each
    const size_t nF = (size_t)NLAY * FFD * DM;    // w1/w2/w3 each
    const size_t nO = (size_t)VOC * DM;           // w_out
    u16* wqb = (u16*)(ws + alloc(nQ * 2));
    u16* wkb = (u16*)(ws + alloc(nQ * 2));
    u16* wvb = (u16*)(ws + alloc(nQ * 2));
    u16* wob = (u16*)(ws + alloc(nQ * 2));
    u16* w1b = (u16*)(ws + alloc(nF * 2));
    u16* w2b = (u16*)(ws + alloc(nF * 2));
    u16* w3b = (u16*)(ws + alloc(nF * 2));
    u16* woub = (u16*)(ws + alloc(nO * 2));

    CvtArgs ca;
    const float* srcs[8] = {wq, wk, wvw, wo, w1, w2, w3, w_out};
    u16* dsts[8] = {wqb, wkb, wvb, wob, w1b, w2b, w3b, woub};
    const size_t cnts[8] = {nQ, nQ, nQ, nQ, nF, nF, nF, nO};
    int cum = 0;
    for (int i = 0; i < 8; ++i) {
        ca.s[i] = srcs[i]; ca.d[i] = dsts[i]; ca.cum[i] = cum;
        cum += (int)(cnts[i] / 16);
    }
    ca.cum[8] = cum;
    cvt_all_kernel<<<2048, 256, 0, stream>>>(ca);

    embed_kernel<<<SEQ, 256, 0, stream>>>(tokens, tok_emb, h);
    ropetab_kernel<<<(SEQ * 32) / 256, 256, 0, stream>>>(cosb, sinb);
    span_kernel<<<1, SEQ, 0, stream>>>(tokens, span, tmask);

    for (int l = 0; l < NLAY; ++l) {
        rmsnorm_kernel<<<SEQ, 256, 0, stream>>>(h, attn_nw + (size_t)l * DM, xn);
        qkv_kernel<<<dim3(8, 24), 256, 0, stream>>>(
            xn, wqb + (size_t)l * DM * DM, wkb + (size_t)l * DM * DM, wvb + (size_t)l * DM * DM,
            cosb, sinb, qb, kb, vb);
        fattn_kernel<<<dim3(SEQ / 64, NHEADS), 256, 0, stream>>>(qb, kb, vb, span, tmask, ab);
        gemm_p_kernel<1, 64, 64><<<dim3(16, 16), 256, 0, stream>>>(
            ab, wob + (size_t)l * DM * DM, h, h, DM, DM);

        rmsnorm_kernel<<<SEQ, 256, 0, stream>>>(h, ffn_nw + (size_t)l * DM, xn);
        ffn13_kernel<<<dim3(16, 22), 256, 0, stream>>>(
            xn, w1b + (size_t)l * FFD * DM, w3b + (size_t)l * FFD * DM, zb);
        gemm_p_kernel<1, 64, 64><<<dim3(16, 16), 256, 0, stream>>>(
            zb, w2b + (size_t)l * DM * FFD, h, h, DM, FFD);
    }

    rmsnorm_kernel<<<SEQ, 256, 0, stream>>>(h, final_nw, xn);
    gemm_big_kernel<0><<<dim3(SEQ / 256, VOC / 256), 512, 0, stream>>>(
        xn, woub, logits, nullptr, VOC, DM);
}